// Round 1
// 1794.643 us; speedup vs baseline: 1.0321x; 1.0321x over previous
//
#include <hip/hip_runtime.h>
#include <hip/hip_bf16.h>

// Problem constants (RWKV-7 Tmix: B=2, T=1024, C=2048, H=32, N=64)
#define BB 2
#define TT 1024
#define CC 2048
#define HH 32
#define BT 2048          // BB*TT tokens
#define GN_EPS 6.4e-4f   // 1e-5 * 8^2

typedef __attribute__((ext_vector_type(8))) __bf16 bf16x8;
typedef __attribute__((ext_vector_type(4))) float f32x4;

__device__ __forceinline__ float sigf(float x) { return 1.0f / (1.0f + expf(-x)); }

__device__ __forceinline__ void split_bf16(float x, __hip_bfloat16& hi, __hip_bfloat16& lo) {
  __hip_bfloat16 h = __float2bfloat16(x);
  hi = h;
  lo = __float2bfloat16(x - __bfloat162float(h));
}

// DPP sum over each aligned 8-lane group (replaces 3x ds_swizzle shfl_xor):
// quad_perm xor1, quad_perm xor2 (each lane -> quad sum, bitwise-equal within
// a quad), then row_half_mirror adds the other quad's sum (equivalent to the
// original xor4 round, bit-identical pairing). 6 VALU ops, no LDS pipe.
__device__ __forceinline__ float red8(float x) {
  x += __int_as_float(__builtin_amdgcn_update_dpp(
      0, __float_as_int(x), 0xB1 /*quad_perm [1,0,3,2]*/, 0xF, 0xF, true));
  x += __int_as_float(__builtin_amdgcn_update_dpp(
      0, __float_as_int(x), 0x4E /*quad_perm [2,3,0,1]*/, 0xF, 0xF, true));
  x += __int_as_float(__builtin_amdgcn_update_dpp(
      0, __float_as_int(x), 0x141 /*row_half_mirror*/, 0xF, 0xF, true));
  return x;
}

// ---------------------------------------------------------------------------
// K1: token shift + six lerped projections. r/k/v hi+lo split (all scan
// inputs are error-critical — round-4 lesson); w/a/g plain bf16.
// ---------------------------------------------------------------------------
__global__ __launch_bounds__(256) void k_prepx(
    const float* __restrict__ hid, const float* __restrict__ shift,
    const float* __restrict__ xrc, const float* __restrict__ xwc,
    const float* __restrict__ xkc, const float* __restrict__ xvc,
    const float* __restrict__ xac, const float* __restrict__ xgc,
    __hip_bfloat16* __restrict__ xrh, __hip_bfloat16* __restrict__ xrl,
    __hip_bfloat16* __restrict__ xw,
    __hip_bfloat16* __restrict__ xkh, __hip_bfloat16* __restrict__ xkl,
    __hip_bfloat16* __restrict__ xvh, __hip_bfloat16* __restrict__ xvl,
    __hip_bfloat16* __restrict__ xa, __hip_bfloat16* __restrict__ xg) {
  int idx = blockIdx.x * 256 + threadIdx.x;   // < BT*CC
  int c  = idx & (CC - 1);
  int bt = idx >> 11;
  int t  = bt & (TT - 1);
  int b  = bt >> 10;
  float hcur  = hid[idx];
  float hprev = (t == 0) ? shift[b * CC + c] : hid[idx - CC];
  float xx = hprev - hcur;
  split_bf16(fmaf(xx, xrc[c], hcur), xrh[idx], xrl[idx]);
  split_bf16(fmaf(xx, xkc[c], hcur), xkh[idx], xkl[idx]);
  split_bf16(fmaf(xx, xvc[c], hcur), xvh[idx], xvl[idx]);
  xw[idx] = __float2bfloat16(fmaf(xx, xwc[c], hcur));
  xa[idx] = __float2bfloat16(fmaf(xx, xac[c], hcur));
  xg[idx] = __float2bfloat16(fmaf(xx, xgc[c], hcur));
}

// ---------------------------------------------------------------------------
// K2: f32 -> hi+lo bf16 split (for Wr/Wk/Wv/Wo)
// ---------------------------------------------------------------------------
__global__ __launch_bounds__(256) void k_cvt2(const float* __restrict__ in,
                                              __hip_bfloat16* __restrict__ oh,
                                              __hip_bfloat16* __restrict__ ol) {
  int i = blockIdx.x * 256 + threadIdx.x;
  split_bf16(in[i], oh[i], ol[i]);
}

// ---------------------------------------------------------------------------
// K3: transpose-convert small LoRA "up" weights: in [2048][N0] f32 ->
//     out [NP][2048] bf16 (rows >= N0 zero-padded).
// ---------------------------------------------------------------------------
__global__ __launch_bounds__(256) void k_tr(const float* __restrict__ in,
                                            __hip_bfloat16* __restrict__ out,
                                            int N0) {
  int i = blockIdx.x * 256 + threadIdx.x;   // over NP*2048, grid exact
  int n = i >> 11;
  int k = i & 2047;
  float v = (n < N0) ? in[k * N0 + n] : 0.0f;
  out[i] = __float2bfloat16(v);
}

// ---------------------------------------------------------------------------
// K4: plain bf16 MFMA GEMM, C[M,N] f32 = A[M,K] @ B[N,K]^T
// (LoRA stage-1 only: error-damped through gates)
// ---------------------------------------------------------------------------
__global__ __launch_bounds__(256) void k_gemm_bt(
    const __hip_bfloat16* __restrict__ A, const __hip_bfloat16* __restrict__ Bm,
    float* __restrict__ Cm, int M, int Nn, int K) {
  int tid  = threadIdx.x;
  int lane = tid & 63;
  int wv   = tid >> 6;
  int l15  = lane & 15;
  int quad = lane >> 4;
  int m0 = blockIdx.x * 128 + wv * 32;
  int n0 = blockIdx.y * 64;
  const __hip_bfloat16* ap0 = A + (m0 + l15) * K + quad * 8;
  const __hip_bfloat16* ap1 = ap0 + 16 * K;
  const __hip_bfloat16* bp  = Bm + (n0 + l15) * K + quad * 8;
  f32x4 z = {0.f, 0.f, 0.f, 0.f};
  f32x4 c00 = z, c01 = z, c02 = z, c03 = z;
  f32x4 c10 = z, c11 = z, c12 = z, c13 = z;
  for (int k0 = 0; k0 < K; k0 += 32) {
    bf16x8 a0v = *(const bf16x8*)(ap0 + k0);
    bf16x8 a1v = *(const bf16x8*)(ap1 + k0);
    bf16x8 b0v = *(const bf16x8*)(bp + k0);
    bf16x8 b1v = *(const bf16x8*)(bp + 16 * K + k0);
    bf16x8 b2v = *(const bf16x8*)(bp + 32 * K + k0);
    bf16x8 b3v = *(const bf16x8*)(bp + 48 * K + k0);
    c00 = __builtin_amdgcn_mfma_f32_16x16x32_bf16(a0v, b0v, c00, 0, 0, 0);
    c01 = __builtin_amdgcn_mfma_f32_16x16x32_bf16(a0v, b1v, c01, 0, 0, 0);
    c02 = __builtin_amdgcn_mfma_f32_16x16x32_bf16(a0v, b2v, c02, 0, 0, 0);
    c03 = __builtin_amdgcn_mfma_f32_16x16x32_bf16(a0v, b3v, c03, 0, 0, 0);
    c10 = __builtin_amdgcn_mfma_f32_16x16x32_bf16(a1v, b0v, c10, 0, 0, 0);
    c11 = __builtin_amdgcn_mfma_f32_16x16x32_bf16(a1v, b1v, c11, 0, 0, 0);
    c12 = __builtin_amdgcn_mfma_f32_16x16x32_bf16(a1v, b2v, c12, 0, 0, 0);
    c13 = __builtin_amdgcn_mfma_f32_16x16x32_bf16(a1v, b3v, c13, 0, 0, 0);
  }
  int colb = n0 + l15;
  int row0 = m0 + quad * 4;
#pragma unroll
  for (int r = 0; r < 4; ++r) {
    Cm[(row0 + r) * Nn + colb +  0] = c00[r];
    Cm[(row0 + r) * Nn + colb + 16] = c01[r];
    Cm[(row0 + r) * Nn + colb + 32] = c02[r];
    Cm[(row0 + r) * Nn + colb + 48] = c03[r];
    Cm[(row0 + 16 + r) * Nn + colb +  0] = c10[r];
    Cm[(row0 + 16 + r) * Nn + colb + 16] = c11[r];
    Cm[(row0 + 16 + r) * Nn + colb + 32] = c12[r];
    Cm[(row0 + 16 + r) * Nn + colb + 48] = c13[r];
  }
}

// ---------------------------------------------------------------------------
// K4b: split-precision GEMM: C = (Ah+Al)@(Bh+Bl)^T ~= Ah Bh + Ah Bl + Al Bh.
// ---------------------------------------------------------------------------
__global__ __launch_bounds__(256) void k_gemm_bt3(
    const __hip_bfloat16* __restrict__ Ah, const __hip_bfloat16* __restrict__ Al,
    const __hip_bfloat16* __restrict__ Bh, const __hip_bfloat16* __restrict__ Bl,
    float* __restrict__ Cm, int M, int Nn, int K) {
  int tid  = threadIdx.x;
  int lane = tid & 63;
  int wv   = tid >> 6;
  int l15  = lane & 15;
  int quad = lane >> 4;
  int m0 = blockIdx.x * 128 + wv * 32;
  int n0 = blockIdx.y * 64;
  size_t aoff0 = (size_t)(m0 + l15) * K + quad * 8;
  size_t aoff1 = aoff0 + (size_t)16 * K;
  size_t boff  = (size_t)(n0 + l15) * K + quad * 8;
  f32x4 z = {0.f, 0.f, 0.f, 0.f};
  f32x4 c00 = z, c01 = z, c02 = z, c03 = z;
  f32x4 c10 = z, c11 = z, c12 = z, c13 = z;
  for (int k0 = 0; k0 < K; k0 += 32) {
    bf16x8 a0h = *(const bf16x8*)(Ah + aoff0 + k0);
    bf16x8 a1h = *(const bf16x8*)(Ah + aoff1 + k0);
    bf16x8 a0l = *(const bf16x8*)(Al + aoff0 + k0);
    bf16x8 a1l = *(const bf16x8*)(Al + aoff1 + k0);
    bf16x8 bh0 = *(const bf16x8*)(Bh + boff + k0);
    bf16x8 bh1 = *(const bf16x8*)(Bh + boff + (size_t)16 * K + k0);
    bf16x8 bh2 = *(const bf16x8*)(Bh + boff + (size_t)32 * K + k0);
    bf16x8 bh3 = *(const bf16x8*)(Bh + boff + (size_t)48 * K + k0);
    bf16x8 bl0 = *(const bf16x8*)(Bl + boff + k0);
    bf16x8 bl1 = *(const bf16x8*)(Bl + boff + (size_t)16 * K + k0);
    bf16x8 bl2 = *(const bf16x8*)(Bl + boff + (size_t)32 * K + k0);
    bf16x8 bl3 = *(const bf16x8*)(Bl + boff + (size_t)48 * K + k0);
    c00 = __builtin_amdgcn_mfma_f32_16x16x32_bf16(a0h, bh0, c00, 0, 0, 0);
    c01 = __builtin_amdgcn_mfma_f32_16x16x32_bf16(a0h, bh1, c01, 0, 0, 0);
    c02 = __builtin_amdgcn_mfma_f32_16x16x32_bf16(a0h, bh2, c02, 0, 0, 0);
    c03 = __builtin_amdgcn_mfma_f32_16x16x32_bf16(a0h, bh3, c03, 0, 0, 0);
    c10 = __builtin_amdgcn_mfma_f32_16x16x32_bf16(a1h, bh0, c10, 0, 0, 0);
    c11 = __builtin_amdgcn_mfma_f32_16x16x32_bf16(a1h, bh1, c11, 0, 0, 0);
    c12 = __builtin_amdgcn_mfma_f32_16x16x32_bf16(a1h, bh2, c12, 0, 0, 0);
    c13 = __builtin_amdgcn_mfma_f32_16x16x32_bf16(a1h, bh3, c13, 0, 0, 0);
    c00 = __builtin_amdgcn_mfma_f32_16x16x32_bf16(a0h, bl0, c00, 0, 0, 0);
    c01 = __builtin_amdgcn_mfma_f32_16x16x32_bf16(a0h, bl1, c01, 0, 0, 0);
    c02 = __builtin_amdgcn_mfma_f32_16x16x32_bf16(a0h, bl2, c02, 0, 0, 0);
    c03 = __builtin_amdgcn_mfma_f32_16x16x32_bf16(a0h, bl3, c03, 0, 0, 0);
    c10 = __builtin_amdgcn_mfma_f32_16x16x32_bf16(a1h, bl0, c10, 0, 0, 0);
    c11 = __builtin_amdgcn_mfma_f32_16x16x32_bf16(a1h, bl1, c11, 0, 0, 0);
    c12 = __builtin_amdgcn_mfma_f32_16x16x32_bf16(a1h, bl2, c12, 0, 0, 0);
    c13 = __builtin_amdgcn_mfma_f32_16x16x32_bf16(a1h, bl3, c13, 0, 0, 0);
    c00 = __builtin_amdgcn_mfma_f32_16x16x32_bf16(a0l, bh0, c00, 0, 0, 0);
    c01 = __builtin_amdgcn_mfma_f32_16x16x32_bf16(a0l, bh1, c01, 0, 0, 0);
    c02 = __builtin_amdgcn_mfma_f32_16x16x32_bf16(a0l, bh2, c02, 0, 0, 0);
    c03 = __builtin_amdgcn_mfma_f32_16x16x32_bf16(a0l, bh3, c03, 0, 0, 0);
    c10 = __builtin_amdgcn_mfma_f32_16x16x32_bf16(a1l, bh0, c10, 0, 0, 0);
    c11 = __builtin_amdgcn_mfma_f32_16x16x32_bf16(a1l, bh1, c11, 0, 0, 0);
    c12 = __builtin_amdgcn_mfma_f32_16x16x32_bf16(a1l, bh2, c12, 0, 0, 0);
    c13 = __builtin_amdgcn_mfma_f32_16x16x32_bf16(a1l, bh3, c13, 0, 0, 0);
  }
  int colb = n0 + l15;
  int row0 = m0 + quad * 4;
#pragma unroll
  for (int r = 0; r < 4; ++r) {
    Cm[(row0 + r) * Nn + colb +  0] = c00[r];
    Cm[(row0 + r) * Nn + colb + 16] = c01[r];
    Cm[(row0 + r) * Nn + colb + 32] = c02[r];
    Cm[(row0 + r) * Nn + colb + 48] = c03[r];
    Cm[(row0 + 16 + r) * Nn + colb +  0] = c10[r];
    Cm[(row0 + 16 + r) * Nn + colb + 16] = c11[r];
    Cm[(row0 + 16 + r) * Nn + colb + 32] = c12[r];
    Cm[(row0 + 16 + r) * Nn + colb + 48] = c13[r];
  }
}

// ---------------------------------------------------------------------------
// K5: activations on stage-1 LoRA outputs: tanh(h1w), sigmoid(h1g), in place
// ---------------------------------------------------------------------------
__global__ __launch_bounds__(256) void k_act(float* __restrict__ h1w,
                                             float* __restrict__ h1g) {
  int i = blockIdx.x * 256 + threadIdx.x;   // grid covers BT*128
  if (i < BT * 64)  h1w[i] = tanhf(h1w[i]);
  if (i < BT * 128) h1g[i] = sigf(h1g[i]);
}

// ---------------------------------------------------------------------------
// K6: fused stage-2 LoRA dots (f32) + gates + kk-normalize + per-head bonus
// (sum r*k_final*r_k — S-independent, so computed here not in the scan).
// ---------------------------------------------------------------------------
__global__ __launch_bounds__(256) void k_prep2(
    const float* __restrict__ h1w, const float* __restrict__ h1a,
    const float* __restrict__ h1v, const float* __restrict__ h1g,
    const float* __restrict__ w2, const float* __restrict__ a2,
    const float* __restrict__ v2, const float* __restrict__ g2,
    const float* __restrict__ w0, const float* __restrict__ a0,
    const float* __restrict__ v0, const float* __restrict__ kkc,
    const float* __restrict__ kac, float* __restrict__ kbuf,
    float* __restrict__ vbuf, const float* __restrict__ vfirst,
    const float* __restrict__ rbuf, const float* __restrict__ rk,
    float* __restrict__ dec, float* __restrict__ aw,
    float* __restrict__ bw, float* __restrict__ gval,
    float* __restrict__ bonb) {
  __shared__ float hs[288][8];   // w:0-63  a:64-127  v:128-159  g:160-287
  int tid = threadIdx.x;
  int c   = blockIdx.x * 256 + tid;
  int t0  = blockIdx.y * 8;
  for (int e = tid; e < 64 * 8;  e += 256) { int d = e >> 3, q = e & 7; hs[d][q]       = h1w[(t0 + q) * 64  + d]; }
  for (int e = tid; e < 64 * 8;  e += 256) { int d = e >> 3, q = e & 7; hs[64 + d][q]  = h1a[(t0 + q) * 64  + d]; }
  for (int e = tid; e < 32 * 8;  e += 256) { int d = e >> 3, q = e & 7; hs[128 + d][q] = h1v[(t0 + q) * 64  + d]; }
  for (int e = tid; e < 128 * 8; e += 256) { int d = e >> 3, q = e & 7; hs[160 + d][q] = h1g[(t0 + q) * 128 + d]; }
  __syncthreads();
  float wacc[8], aacc[8], vacc[8], gacc[8];
#pragma unroll
  for (int q = 0; q < 8; ++q) { wacc[q] = 0.f; aacc[q] = 0.f; vacc[q] = 0.f; gacc[q] = 0.f; }
  for (int d = 0; d < 64; ++d) {
    float wt = w2[d * CC + c];
    float4 h0 = *(const float4*)&hs[d][0];
    float4 h1 = *(const float4*)&hs[d][4];
    wacc[0] = fmaf(h0.x, wt, wacc[0]); wacc[1] = fmaf(h0.y, wt, wacc[1]);
    wacc[2] = fmaf(h0.z, wt, wacc[2]); wacc[3] = fmaf(h0.w, wt, wacc[3]);
    wacc[4] = fmaf(h1.x, wt, wacc[4]); wacc[5] = fmaf(h1.y, wt, wacc[5]);
    wacc[6] = fmaf(h1.z, wt, wacc[6]); wacc[7] = fmaf(h1.w, wt, wacc[7]);
  }
  for (int d = 0; d < 64; ++d) {
    float at = a2[d * CC + c];
    float4 h0 = *(const float4*)&hs[64 + d][0];
    float4 h1 = *(const float4*)&hs[64 + d][4];
    aacc[0] = fmaf(h0.x, at, aacc[0]); aacc[1] = fmaf(h0.y, at, aacc[1]);
    aacc[2] = fmaf(h0.z, at, aacc[2]); aacc[3] = fmaf(h0.w, at, aacc[3]);
    aacc[4] = fmaf(h1.x, at, aacc[4]); aacc[5] = fmaf(h1.y, at, aacc[5]);
    aacc[6] = fmaf(h1.z, at, aacc[6]); aacc[7] = fmaf(h1.w, at, aacc[7]);
  }
  for (int d = 0; d < 32; ++d) {
    float vt = v2[d * CC + c];
    float4 h0 = *(const float4*)&hs[128 + d][0];
    float4 h1 = *(const float4*)&hs[128 + d][4];
    vacc[0] = fmaf(h0.x, vt, vacc[0]); vacc[1] = fmaf(h0.y, vt, vacc[1]);
    vacc[2] = fmaf(h0.z, vt, vacc[2]); vacc[3] = fmaf(h0.w, vt, vacc[3]);
    vacc[4] = fmaf(h1.x, vt, vacc[4]); vacc[5] = fmaf(h1.y, vt, vacc[5]);
    vacc[6] = fmaf(h1.z, vt, vacc[6]); vacc[7] = fmaf(h1.w, vt, vacc[7]);
  }
  for (int d = 0; d < 128; ++d) {
    float gt = g2[d * CC + c];
    float4 h0 = *(const float4*)&hs[160 + d][0];
    float4 h1 = *(const float4*)&hs[160 + d][4];
    gacc[0] = fmaf(h0.x, gt, gacc[0]); gacc[1] = fmaf(h0.y, gt, gacc[1]);
    gacc[2] = fmaf(h0.z, gt, gacc[2]); gacc[3] = fmaf(h0.w, gt, gacc[3]);
    gacc[4] = fmaf(h1.x, gt, gacc[4]); gacc[5] = fmaf(h1.y, gt, gacc[5]);
    gacc[6] = fmaf(h1.z, gt, gacc[6]); gacc[7] = fmaf(h1.w, gt, gacc[7]);
  }
  float w0v = w0[c], a0v = a0[c], v0v = v0[c], kkv = kkc[c], kav = kac[c];
  float rkc = rk[c];
  for (int q = 0; q < 8; ++q) {
    int idx = (t0 + q) * CC + c;
    float kv = kbuf[idx], vv = vbuf[idx], vf = vfirst[idx];
    float d_ = 0.60653065971f * sigf(w0v + wacc[q]);   // sigmoid * e^-0.5
    float as = sigf(a0v + aacc[q]);
    float vs = sigf(v0v + vacc[q]);
    float vm = vv + (vf - vv) * vs;
    float kfv = kv * (1.0f + kav * (as - 1.0f));
    float kku = kv * kkv;
    float s = kku * kku;     // per-head L2 over 64 lanes (wave == head)
    s += __shfl_xor(s, 1);  s += __shfl_xor(s, 2);  s += __shfl_xor(s, 4);
    s += __shfl_xor(s, 8);  s += __shfl_xor(s, 16); s += __shfl_xor(s, 32);
    float nrm = fmaxf(sqrtf(s), 1e-12f);
    float kkn = kku / nrm;
    // per-head bonus: sum_c r*k_final*r_k  (wave == head)
    float bon = rbuf[idx] * kfv * rkc;
    bon += __shfl_xor(bon, 1);  bon += __shfl_xor(bon, 2);
    bon += __shfl_xor(bon, 4);  bon += __shfl_xor(bon, 8);
    bon += __shfl_xor(bon, 16); bon += __shfl_xor(bon, 32);
    if ((tid & 63) == 0) bonb[(t0 + q) * HH + (c >> 6)] = bon;
    dec[idx] = d_;
    aw[idx]  = -kkn; bw[idx] = kkn * as;
    kbuf[idx] = kfv; vbuf[idx] = vm; gval[idx] = gacc[q];
  }
}

// ---------------------------------------------------------------------------
// K7: WKV7 scan, ROW-split, barrier-free, 4-DEEP explicit prefetch ring.
// Grid = 512 blocks x 64 thr; block = one wave = (bh, row-group of 8).
// lane L: row = rg*8+(L>>3), cols = (L&7)*8..+8.
// ROUND-8 change: (a) sa/y 8-lane reduces now via DPP (red8: quad_perm xor1,
// xor2, row_half_mirror) — no LDS-pipe ds_swizzle on the critical path
// (was ~6x120cy/step); (b) ring restructured into NAMED float4 registers
// (no arrays, no pointer passing) so the 4-deep prefetch cannot be demoted
// to scratch / collapsed (prev build: VGPR=112 < the ~190 a real ring needs).
// The asm memory fence after each step+reload still pins load issue order.
// ---------------------------------------------------------------------------
__global__ __launch_bounds__(64) void k_scan(
    const float* __restrict__ rbuf, const float* __restrict__ kf,
    const float* __restrict__ dec, const float* __restrict__ aw,
    const float* __restrict__ bw, const float* __restrict__ vbuf,
    const float* __restrict__ st0, float* __restrict__ ybuf) {
  int blk = blockIdx.x;                // 0..511
  int bh = blk >> 3, rg = blk & 7;
  int b = bh >> 5, h = bh & 31;
  int lane = threadIdx.x;
  int row = rg * 8 + (lane >> 3);
  int c0  = (lane & 7) * 8;
  size_t tokbase = (size_t)b * TT * CC + h * 64;

  float St[8];
  {
    const float* sp = st0 + ((size_t)bh * 64 + row) * 64 + c0;
#pragma unroll
    for (int i = 0; i < 8; ++i) St[i] = sp[i];
  }

  bool writer = ((lane & 7) == 0);
  float* yout = ybuf + tokbase + row;

  // 4 named prefetch slots, each: r0,r1,k0,k1,d0,d1,a0,a1,b0,b1 + vv
#define DECL_SLOT(P) \
  float4 P##r0, P##r1, P##k0, P##k1, P##d0, P##d1, P##a0, P##a1, P##b0, P##b1; \
  float P##vv;
  DECL_SLOT(p0) DECL_SLOT(p1) DECL_SLOT(p2) DECL_SLOT(p3)
#undef DECL_SLOT

#define LOADT(P, T)                                                          \
  { size_t o = tokbase + (size_t)(T) * CC;                                   \
    const float* pc = rbuf + o + c0;                                         \
    P##r0 = *(const float4*)pc; P##r1 = *(const float4*)(pc + 4);            \
    pc = kf + o + c0;                                                        \
    P##k0 = *(const float4*)pc; P##k1 = *(const float4*)(pc + 4);            \
    pc = dec + o + c0;                                                       \
    P##d0 = *(const float4*)pc; P##d1 = *(const float4*)(pc + 4);            \
    pc = aw + o + c0;                                                        \
    P##a0 = *(const float4*)pc; P##a1 = *(const float4*)(pc + 4);            \
    pc = bw + o + c0;                                                        \
    P##b0 = *(const float4*)pc; P##b1 = *(const float4*)(pc + 4);            \
    P##vv = vbuf[o + row]; }

#define STEP(P, T)                                                            \
  { float sa =                                                                \
      fmaf(St[0], P##a0.x, fmaf(St[1], P##a0.y,                               \
           fmaf(St[2], P##a0.z, St[3] * P##a0.w)))                            \
    + fmaf(St[4], P##a1.x, fmaf(St[5], P##a1.y,                               \
           fmaf(St[6], P##a1.z, St[7] * P##a1.w)));                           \
    sa = red8(sa);                                                            \
    float y0, y1;                                                             \
    St[0] = fmaf(St[0], P##d0.x, fmaf(sa, P##b0.x, P##vv * P##k0.x));         \
    y0 = St[0] * P##r0.x;                                                     \
    St[1] = fmaf(St[1], P##d0.y, fmaf(sa, P##b0.y, P##vv * P##k0.y));         \
    y0 = fmaf(St[1], P##r0.y, y0);                                            \
    St[2] = fmaf(St[2], P##d0.z, fmaf(sa, P##b0.z, P##vv * P##k0.z));         \
    y0 = fmaf(St[2], P##r0.z, y0);                                            \
    St[3] = fmaf(St[3], P##d0.w, fmaf(sa, P##b0.w, P##vv * P##k0.w));         \
    y0 = fmaf(St[3], P##r0.w, y0);                                            \
    St[4] = fmaf(St[4], P##d1.x, fmaf(sa, P##b1.x, P##vv * P##k1.x));         \
    y1 = St[4] * P##r1.x;                                                     \
    St[5] = fmaf(St[5], P##d1.y, fmaf(sa, P##b1.y, P##vv * P##k1.y));         \
    y1 = fmaf(St[5], P##r1.y, y1);                                            \
    St[6] = fmaf(St[6], P##d1.z, fmaf(sa, P##b1.z, P##vv * P##k1.z));         \
    y1 = fmaf(St[6], P##r1.z, y1);                                            \
    St[7] = fmaf(St[7], P##d1.w, fmaf(sa, P##b1.w, P##vv * P##k1.w));         \
    y1 = fmaf(St[7], P##r1.w, y1);                                            \
    float y = red8(y0 + y1);                                                  \
    if (writer) yout[(size_t)(T) * CC] = y; }

  LOADT(p0, 0) LOADT(p1, 1) LOADT(p2, 2) LOADT(p3, 3)
  for (int t = 0; t < TT; t += 4) {
    STEP(p0, t + 0); if (t + 4 < TT) LOADT(p0, t + 4);
    asm volatile("" ::: "memory");   // pin: reload issues here, 4 steps early
    STEP(p1, t + 1); if (t + 5 < TT) LOADT(p1, t + 5);
    asm volatile("" ::: "memory");
    STEP(p2, t + 2); if (t + 6 < TT) LOADT(p2, t + 6);
    asm volatile("" ::: "memory");
    STEP(p3, t + 3); if (t + 7 < TT) LOADT(p3, t + 7);
    asm volatile("" ::: "memory");
  }
#undef LOADT
#undef STEP
}

// ---------------------------------------------------------------------------
// K8: post-scan epilogue: GroupNorm + bonus + g-gate, fully parallel.
// Block 256 = 4 waves; wave = one (token, head).
// ---------------------------------------------------------------------------
__global__ __launch_bounds__(256) void k_post(
    const float* __restrict__ ybuf, const float* __restrict__ vb,
    const float* __restrict__ gvb, const float* __restrict__ bonb,
    const float* __restrict__ gnw, const float* __restrict__ gnb,
    __hip_bfloat16* __restrict__ xoh, __hip_bfloat16* __restrict__ xol) {
  int tid = threadIdx.x, wv = tid >> 6, lane = tid & 63;
  int id = blockIdx.x * 4 + wv;        // 0..BT*HH-1
  int bt = id >> 5, h = id & 31;
  size_t base = (size_t)bt * CC + h * 64 + lane;
  float y = ybuf[base];
  float s1 = y, s2 = y * y;
#pragma unroll
  for (int off = 1; off < 64; off <<= 1) {
    s1 += __shfl_xor(s1, off);
    s2 += __shfl_xor(s2, off);
  }
  float mean = s1 * (1.0f / 64.0f);
  float var  = s2 * (1.0f / 64.0f) - mean * mean;
  float inv  = rsqrtf(var + GN_EPS);
  float x = fmaf((y - mean) * inv, gnw[h * 64 + lane], gnb[h * 64 + lane])
          + bonb[bt * HH + h] * vb[base];
  split_bf16(x * gvb[base], xoh[base], xol[base]);
}

// ---------------------------------------------------------------------------
extern "C" void kernel_launch(void* const* d_in, const int* in_sizes, int n_in,
                              void* d_out, int out_size, void* d_ws, size_t ws_size,
                              hipStream_t stream) {
  (void)in_sizes; (void)n_in; (void)out_size; (void)ws_size;
  const float* hid    = (const float*)d_in[0];
  const float* shift  = (const float*)d_in[1];
  const float* st0    = (const float*)d_in[2];
  const float* vfirst = (const float*)d_in[3];
  const float* xrc = (const float*)d_in[4];
  const float* xwc = (const float*)d_in[5];
  const float* xkc = (const float*)d_in[6];
  const float* xvc = (const float*)d_in[7];
  const float* xac = (const float*)d_in[8];
  const float* xgc = (const float*)d_in[9];
  const float* w0  = (const float*)d_in[10];
  const float* w1  = (const float*)d_in[11];
  const float* w2  = (const float*)d_in[12];
  const float* a0  = (const float*)d_in[13];
  const float* a1  = (const float*)d_in[14];
  const float* a2  = (const float*)d_in[15];
  const float* v0  = (const float*)d_in[16];
  const float* v1  = (const float*)d_in[17];
  const float* v2  = (const float*)d_in[18];
  const float* g1  = (const float*)d_in[19];
  const float* g2  = (const float*)d_in[20];
  const float* kkc = (const float*)d_in[21];
  const float* kac = (const float*)d_in[22];
  const float* rk  = (const float*)d_in[23];
  const float* Wr  = (const float*)d_in[24];
  const float* Wk  = (const float*)d_in[25];
  const float* Wv  = (const float*)d_in[26];
  const float* Wo  = (const float*)d_in[27];
  const float* gnw = (const float*)d_in[28];
  const float* gnb = (const float*)d_in[29];
  float* out = (float*)d_out;

  char* p = (char*)d_ws;
  auto alloc = [&](size_t n) { char* q = p; p += (n + 255) & ~(size_t)255; return q; };
  const size_t EL = (size_t)BT * CC;

  // --- alias pool (96 MiB): xrh..xvl + Wrh,Wrl dead by k_prep2 time;
  //     db/awb/bwb/gvb (64 MiB) overlay them.
  char* pool = p;
  __hip_bfloat16* xrh = (__hip_bfloat16*)alloc(EL * 2);
  __hip_bfloat16* xrl = (__hip_bfloat16*)alloc(EL * 2);
  __hip_bfloat16* xkh = (__hip_bfloat16*)alloc(EL * 2);
  __hip_bfloat16* xkl = (__hip_bfloat16*)alloc(EL * 2);
  __hip_bfloat16* xvh = (__hip_bfloat16*)alloc(EL * 2);
  __hip_bfloat16* xvl = (__hip_bfloat16*)alloc(EL * 2);
  __hip_bfloat16* Wrh = (__hip_bfloat16*)alloc((size_t)CC * CC * 2);
  __hip_bfloat16* Wrl = (__hip_bfloat16*)alloc((size_t)CC * CC * 2);
  float* db  = (float*)pool;           // overlays xrh+xrl
  float* awb = db + EL;                // overlays xkh+xkl
  float* bwb = db + 2 * EL;            // overlays xvh+xvl
  float* gvb = db + 3 * EL;            // overlays Wrh+Wrl

  __hip_bfloat16* Wkh = (__hip_bfloat16*)alloc((size_t)CC * CC * 2);
  __hip_bfloat16* Wkl = (__hip_bfloat16*)alloc((size_t)CC * CC * 2);
  float* ybuf = (float*)Wkh;           // overlays Wkh+Wkl (dead after k-GEMM)

  __hip_bfloat16* Wvh = (__hip_bfloat16*)alloc((size_t)CC * CC * 2);
  __hip_bfloat16* Wvl = (__hip_bfloat16*)alloc((size_t)CC * CC * 2);
  __hip_bfloat16* Woh = (__hip_bfloat16*)alloc((size_t)CC * CC * 2);
  __hip_bfloat16* Wol = (__hip_bfloat16*)alloc((size_t)CC * CC * 2);
  __hip_bfloat16* xw  = (__hip_bfloat16*)alloc(EL * 2);
  __hip_bfloat16* xa  = (__hip_bfloat16*)alloc(EL * 2);
  __hip_bfloat16* xg  = (__hip_bfloat16*)alloc(EL * 2);
  __hip_bfloat16* w1t = (__hip_bfloat16*)alloc((size_t)64  * CC * 2);
  __hip_bfloat16* a1t = (__hip_bfloat16*)alloc((size_t)64  * CC * 2);
  __hip_bfloat16* v1t = (__hip_bfloat16*)alloc((size_t)64  * CC * 2);
  __hip_bfloat16* g1t = (__hip_bfloat16*)alloc((size_t)128 * CC * 2);
  float* rb  = (float*)alloc(EL * 4);
  float* kb  = (float*)alloc(EL * 4);  // raw k, then k_final in place
  float* vb  = (float*)alloc(EL * 4);  // raw v, then v_mix in place
  float* h1w = (float*)alloc((size_t)BT * 64  * 4);
  float* h1a = (float*)alloc((size_t)BT * 64  * 4);
  float* h1v = (float*)alloc((size_t)BT * 64  * 4);
  float* h1g = (float*)alloc((size_t)BT * 128 * 4);
  __hip_bfloat16* xoh = (__hip_bfloat16*)alloc(EL * 2);
  __hip_bfloat16* xol = (__hip_bfloat16*)alloc(EL * 2);
  float* bonb = (float*)alloc((size_t)BT * HH * 4);   // per-(token,head) bonus
  // total ~204.5 MiB (fits: 220 MiB known-OK, 268 MiB crashed)

  k_prepx<<<16384, 256, 0, stream>>>(hid, shift, xrc, xwc, xkc, xvc, xac, xgc,
                                     xrh, xrl, xw, xkh, xkl, xvh, xvl, xa, xg);
  k_cvt2<<<16384, 256, 0, stream>>>(Wr, Wrh, Wrl);
  k_cvt2<<<16384, 256, 0, stream>>>(Wk, Wkh, Wkl);
  k_cvt2<<<16384, 256, 0, stream>>>(Wv, Wvh, Wvl);
  k_cvt2<<<16384, 256, 0, stream>>>(Wo, Woh, Wol);
  k_tr<<<512, 256, 0, stream>>>(w1, w1t, 64);
  k_tr<<<512, 256, 0, stream>>>(a1, a1t, 64);
  k_tr<<<512, 256, 0, stream>>>(v1, v1t, 32);
  k_tr<<<1024, 256, 0, stream>>>(g1, g1t, 128);

  k_gemm_bt3<<<dim3(16, 32), 256, 0, stream>>>(xrh, xrl, Wrh, Wrl, rb, BT, CC, CC);
  k_gemm_bt3<<<dim3(16, 32), 256, 0, stream>>>(xkh, xkl, Wkh, Wkl, kb, BT, CC, CC);
  k_gemm_bt3<<<dim3(16, 32), 256, 0, stream>>>(xvh, xvl, Wvh, Wvl, vb, BT, CC, CC);
  k_gemm_bt<<<dim3(16, 1),  256, 0, stream>>>(xw,  w1t, h1w, BT, 64, CC);
  k_gemm_bt<<<dim3(16, 1),  256, 0, stream>>>(xa,  a1t, h1a, BT, 64, CC);
  k_gemm_bt<<<dim3(16, 1),  256, 0, stream>>>(xvh, v1t, h1v, BT, 64, CC);
  k_gemm_bt<<<dim3(16, 2),  256, 0, stream>>>(xg,  g1t, h1g, BT, 128, CC);

  k_act<<<1024, 256, 0, stream>>>(h1w, h1g);
  // from here: xrh..xvl / Wrh,Wrl dead (db/awb/bwb/gvb overlay);
  //            Wkh/Wkl dead (ybuf overlay)
  k_prep2<<<dim3(8, 256), 256, 0, stream>>>(h1w, h1a, h1v, h1g, w2, a2, v2, g2,
                                            w0, a0, v0, kkc, kac, kb, vb, vfirst,
                                            rb, rk, db, awb, bwb, gvb, bonb);
  k_scan<<<512, 64, 0, stream>>>(rb, kb, db, awb, bwb, vb, st0, ybuf);
  k_post<<<16384, 256, 0, stream>>>(ybuf, vb, gvb, bonb, gnw, gnb, xoh, xol);
  k_gemm_bt3<<<dim3(16, 32), 256, 0, stream>>>(xoh, xol, Woh, Wol, out, BT, CC, CC);
}

// Round 2
// 1736.944 us; speedup vs baseline: 1.0664x; 1.0332x over previous
//
#include <hip/hip_runtime.h>
#include <hip/hip_bf16.h>

// Problem constants (RWKV-7 Tmix: B=2, T=1024, C=2048, H=32, N=64)
#define BB 2
#define TT 1024
#define CC 2048
#define HH 32
#define BT 2048          // BB*TT tokens
#define GN_EPS 6.4e-4f   // 1e-5 * 8^2

typedef __attribute__((ext_vector_type(8))) __bf16 bf16x8;
typedef __attribute__((ext_vector_type(4))) float f32x4;

__device__ __forceinline__ float sigf(float x) { return 1.0f / (1.0f + expf(-x)); }

__device__ __forceinline__ void split_bf16(float x, __hip_bfloat16& hi, __hip_bfloat16& lo) {
  __hip_bfloat16 h = __float2bfloat16(x);
  hi = h;
  lo = __float2bfloat16(x - __bfloat162float(h));
}

// Sum over each aligned 32-lane group. Rounds: xor1, xor2 (quad_perm);
// row_half_mirror (valid as "other quad" fetch once quads are uniform);
// row_ror:8 (other 8-group once 8-uniform); ds_swizzle xor16 (32-group).
// 4 DPP VALU ops + 1 ds_swizzle; every lane ends with the group sum.
__device__ __forceinline__ float red32(float x) {
  x += __int_as_float(__builtin_amdgcn_update_dpp(
      0, __float_as_int(x), 0xB1 /*quad_perm [1,0,3,2]*/, 0xF, 0xF, true));
  x += __int_as_float(__builtin_amdgcn_update_dpp(
      0, __float_as_int(x), 0x4E /*quad_perm [2,3,0,1]*/, 0xF, 0xF, true));
  x += __int_as_float(__builtin_amdgcn_update_dpp(
      0, __float_as_int(x), 0x141 /*row_half_mirror*/, 0xF, 0xF, true));
  x += __int_as_float(__builtin_amdgcn_update_dpp(
      0, __float_as_int(x), 0x128 /*row_ror:8*/, 0xF, 0xF, true));
  x += __int_as_float(__builtin_amdgcn_ds_swizzle(
      __float_as_int(x), 0x401F /*BitMode xor16*/));
  return x;
}

// ---------------------------------------------------------------------------
// K1: token shift + six lerped projections. r/k/v hi+lo split (all scan
// inputs are error-critical — round-4 lesson); w/a/g plain bf16.
// ---------------------------------------------------------------------------
__global__ __launch_bounds__(256) void k_prepx(
    const float* __restrict__ hid, const float* __restrict__ shift,
    const float* __restrict__ xrc, const float* __restrict__ xwc,
    const float* __restrict__ xkc, const float* __restrict__ xvc,
    const float* __restrict__ xac, const float* __restrict__ xgc,
    __hip_bfloat16* __restrict__ xrh, __hip_bfloat16* __restrict__ xrl,
    __hip_bfloat16* __restrict__ xw,
    __hip_bfloat16* __restrict__ xkh, __hip_bfloat16* __restrict__ xkl,
    __hip_bfloat16* __restrict__ xvh, __hip_bfloat16* __restrict__ xvl,
    __hip_bfloat16* __restrict__ xa, __hip_bfloat16* __restrict__ xg) {
  int idx = blockIdx.x * 256 + threadIdx.x;   // < BT*CC
  int c  = idx & (CC - 1);
  int bt = idx >> 11;
  int t  = bt & (TT - 1);
  int b  = bt >> 10;
  float hcur  = hid[idx];
  float hprev = (t == 0) ? shift[b * CC + c] : hid[idx - CC];
  float xx = hprev - hcur;
  split_bf16(fmaf(xx, xrc[c], hcur), xrh[idx], xrl[idx]);
  split_bf16(fmaf(xx, xkc[c], hcur), xkh[idx], xkl[idx]);
  split_bf16(fmaf(xx, xvc[c], hcur), xvh[idx], xvl[idx]);
  xw[idx] = __float2bfloat16(fmaf(xx, xwc[c], hcur));
  xa[idx] = __float2bfloat16(fmaf(xx, xac[c], hcur));
  xg[idx] = __float2bfloat16(fmaf(xx, xgc[c], hcur));
}

// ---------------------------------------------------------------------------
// K2: f32 -> hi+lo bf16 split (for Wr/Wk/Wv/Wo)
// ---------------------------------------------------------------------------
__global__ __launch_bounds__(256) void k_cvt2(const float* __restrict__ in,
                                              __hip_bfloat16* __restrict__ oh,
                                              __hip_bfloat16* __restrict__ ol) {
  int i = blockIdx.x * 256 + threadIdx.x;
  split_bf16(in[i], oh[i], ol[i]);
}

// ---------------------------------------------------------------------------
// K3: transpose-convert small LoRA "up" weights: in [2048][N0] f32 ->
//     out [NP][2048] bf16 (rows >= N0 zero-padded).
// ---------------------------------------------------------------------------
__global__ __launch_bounds__(256) void k_tr(const float* __restrict__ in,
                                            __hip_bfloat16* __restrict__ out,
                                            int N0) {
  int i = blockIdx.x * 256 + threadIdx.x;   // over NP*2048, grid exact
  int n = i >> 11;
  int k = i & 2047;
  float v = (n < N0) ? in[k * N0 + n] : 0.0f;
  out[i] = __float2bfloat16(v);
}

// ---------------------------------------------------------------------------
// K4: plain bf16 MFMA GEMM, C[M,N] f32 = A[M,K] @ B[N,K]^T
// (LoRA stage-1 only: error-damped through gates)
// ---------------------------------------------------------------------------
__global__ __launch_bounds__(256) void k_gemm_bt(
    const __hip_bfloat16* __restrict__ A, const __hip_bfloat16* __restrict__ Bm,
    float* __restrict__ Cm, int M, int Nn, int K) {
  int tid  = threadIdx.x;
  int lane = tid & 63;
  int wv   = tid >> 6;
  int l15  = lane & 15;
  int quad = lane >> 4;
  int m0 = blockIdx.x * 128 + wv * 32;
  int n0 = blockIdx.y * 64;
  const __hip_bfloat16* ap0 = A + (m0 + l15) * K + quad * 8;
  const __hip_bfloat16* ap1 = ap0 + 16 * K;
  const __hip_bfloat16* bp  = Bm + (n0 + l15) * K + quad * 8;
  f32x4 z = {0.f, 0.f, 0.f, 0.f};
  f32x4 c00 = z, c01 = z, c02 = z, c03 = z;
  f32x4 c10 = z, c11 = z, c12 = z, c13 = z;
  for (int k0 = 0; k0 < K; k0 += 32) {
    bf16x8 a0v = *(const bf16x8*)(ap0 + k0);
    bf16x8 a1v = *(const bf16x8*)(ap1 + k0);
    bf16x8 b0v = *(const bf16x8*)(bp + k0);
    bf16x8 b1v = *(const bf16x8*)(bp + 16 * K + k0);
    bf16x8 b2v = *(const bf16x8*)(bp + 32 * K + k0);
    bf16x8 b3v = *(const bf16x8*)(bp + 48 * K + k0);
    c00 = __builtin_amdgcn_mfma_f32_16x16x32_bf16(a0v, b0v, c00, 0, 0, 0);
    c01 = __builtin_amdgcn_mfma_f32_16x16x32_bf16(a0v, b1v, c01, 0, 0, 0);
    c02 = __builtin_amdgcn_mfma_f32_16x16x32_bf16(a0v, b2v, c02, 0, 0, 0);
    c03 = __builtin_amdgcn_mfma_f32_16x16x32_bf16(a0v, b3v, c03, 0, 0, 0);
    c10 = __builtin_amdgcn_mfma_f32_16x16x32_bf16(a1v, b0v, c10, 0, 0, 0);
    c11 = __builtin_amdgcn_mfma_f32_16x16x32_bf16(a1v, b1v, c11, 0, 0, 0);
    c12 = __builtin_amdgcn_mfma_f32_16x16x32_bf16(a1v, b2v, c12, 0, 0, 0);
    c13 = __builtin_amdgcn_mfma_f32_16x16x32_bf16(a1v, b3v, c13, 0, 0, 0);
  }
  int colb = n0 + l15;
  int row0 = m0 + quad * 4;
#pragma unroll
  for (int r = 0; r < 4; ++r) {
    Cm[(row0 + r) * Nn + colb +  0] = c00[r];
    Cm[(row0 + r) * Nn + colb + 16] = c01[r];
    Cm[(row0 + r) * Nn + colb + 32] = c02[r];
    Cm[(row0 + r) * Nn + colb + 48] = c03[r];
    Cm[(row0 + 16 + r) * Nn + colb +  0] = c10[r];
    Cm[(row0 + 16 + r) * Nn + colb + 16] = c11[r];
    Cm[(row0 + 16 + r) * Nn + colb + 32] = c12[r];
    Cm[(row0 + 16 + r) * Nn + colb + 48] = c13[r];
  }
}

// ---------------------------------------------------------------------------
// K4b: split-precision GEMM: C = (Ah+Al)@(Bh+Bl)^T ~= Ah Bh + Ah Bl + Al Bh.
// ---------------------------------------------------------------------------
__global__ __launch_bounds__(256) void k_gemm_bt3(
    const __hip_bfloat16* __restrict__ Ah, const __hip_bfloat16* __restrict__ Al,
    const __hip_bfloat16* __restrict__ Bh, const __hip_bfloat16* __restrict__ Bl,
    float* __restrict__ Cm, int M, int Nn, int K) {
  int tid  = threadIdx.x;
  int lane = tid & 63;
  int wv   = tid >> 6;
  int l15  = lane & 15;
  int quad = lane >> 4;
  int m0 = blockIdx.x * 128 + wv * 32;
  int n0 = blockIdx.y * 64;
  size_t aoff0 = (size_t)(m0 + l15) * K + quad * 8;
  size_t aoff1 = aoff0 + (size_t)16 * K;
  size_t boff  = (size_t)(n0 + l15) * K + quad * 8;
  f32x4 z = {0.f, 0.f, 0.f, 0.f};
  f32x4 c00 = z, c01 = z, c02 = z, c03 = z;
  f32x4 c10 = z, c11 = z, c12 = z, c13 = z;
  for (int k0 = 0; k0 < K; k0 += 32) {
    bf16x8 a0h = *(const bf16x8*)(Ah + aoff0 + k0);
    bf16x8 a1h = *(const bf16x8*)(Ah + aoff1 + k0);
    bf16x8 a0l = *(const bf16x8*)(Al + aoff0 + k0);
    bf16x8 a1l = *(const bf16x8*)(Al + aoff1 + k0);
    bf16x8 bh0 = *(const bf16x8*)(Bh + boff + k0);
    bf16x8 bh1 = *(const bf16x8*)(Bh + boff + (size_t)16 * K + k0);
    bf16x8 bh2 = *(const bf16x8*)(Bh + boff + (size_t)32 * K + k0);
    bf16x8 bh3 = *(const bf16x8*)(Bh + boff + (size_t)48 * K + k0);
    bf16x8 bl0 = *(const bf16x8*)(Bl + boff + k0);
    bf16x8 bl1 = *(const bf16x8*)(Bl + boff + (size_t)16 * K + k0);
    bf16x8 bl2 = *(const bf16x8*)(Bl + boff + (size_t)32 * K + k0);
    bf16x8 bl3 = *(const bf16x8*)(Bl + boff + (size_t)48 * K + k0);
    c00 = __builtin_amdgcn_mfma_f32_16x16x32_bf16(a0h, bh0, c00, 0, 0, 0);
    c01 = __builtin_amdgcn_mfma_f32_16x16x32_bf16(a0h, bh1, c01, 0, 0, 0);
    c02 = __builtin_amdgcn_mfma_f32_16x16x32_bf16(a0h, bh2, c02, 0, 0, 0);
    c03 = __builtin_amdgcn_mfma_f32_16x16x32_bf16(a0h, bh3, c03, 0, 0, 0);
    c10 = __builtin_amdgcn_mfma_f32_16x16x32_bf16(a1h, bh0, c10, 0, 0, 0);
    c11 = __builtin_amdgcn_mfma_f32_16x16x32_bf16(a1h, bh1, c11, 0, 0, 0);
    c12 = __builtin_amdgcn_mfma_f32_16x16x32_bf16(a1h, bh2, c12, 0, 0, 0);
    c13 = __builtin_amdgcn_mfma_f32_16x16x32_bf16(a1h, bh3, c13, 0, 0, 0);
    c00 = __builtin_amdgcn_mfma_f32_16x16x32_bf16(a0h, bl0, c00, 0, 0, 0);
    c01 = __builtin_amdgcn_mfma_f32_16x16x32_bf16(a0h, bl1, c01, 0, 0, 0);
    c02 = __builtin_amdgcn_mfma_f32_16x16x32_bf16(a0h, bl2, c02, 0, 0, 0);
    c03 = __builtin_amdgcn_mfma_f32_16x16x32_bf16(a0h, bl3, c03, 0, 0, 0);
    c10 = __builtin_amdgcn_mfma_f32_16x16x32_bf16(a1h, bl0, c10, 0, 0, 0);
    c11 = __builtin_amdgcn_mfma_f32_16x16x32_bf16(a1h, bl1, c11, 0, 0, 0);
    c12 = __builtin_amdgcn_mfma_f32_16x16x32_bf16(a1h, bl2, c12, 0, 0, 0);
    c13 = __builtin_amdgcn_mfma_f32_16x16x32_bf16(a1h, bl3, c13, 0, 0, 0);
    c00 = __builtin_amdgcn_mfma_f32_16x16x32_bf16(a0l, bh0, c00, 0, 0, 0);
    c01 = __builtin_amdgcn_mfma_f32_16x16x32_bf16(a0l, bh1, c01, 0, 0, 0);
    c02 = __builtin_amdgcn_mfma_f32_16x16x32_bf16(a0l, bh2, c02, 0, 0, 0);
    c03 = __builtin_amdgcn_mfma_f32_16x16x32_bf16(a0l, bh3, c03, 0, 0, 0);
    c10 = __builtin_amdgcn_mfma_f32_16x16x32_bf16(a1l, bh0, c10, 0, 0, 0);
    c11 = __builtin_amdgcn_mfma_f32_16x16x32_bf16(a1l, bh1, c11, 0, 0, 0);
    c12 = __builtin_amdgcn_mfma_f32_16x16x32_bf16(a1l, bh2, c12, 0, 0, 0);
    c13 = __builtin_amdgcn_mfma_f32_16x16x32_bf16(a1l, bh3, c13, 0, 0, 0);
  }
  int colb = n0 + l15;
  int row0 = m0 + quad * 4;
#pragma unroll
  for (int r = 0; r < 4; ++r) {
    Cm[(row0 + r) * Nn + colb +  0] = c00[r];
    Cm[(row0 + r) * Nn + colb + 16] = c01[r];
    Cm[(row0 + r) * Nn + colb + 32] = c02[r];
    Cm[(row0 + r) * Nn + colb + 48] = c03[r];
    Cm[(row0 + 16 + r) * Nn + colb +  0] = c10[r];
    Cm[(row0 + 16 + r) * Nn + colb + 16] = c11[r];
    Cm[(row0 + 16 + r) * Nn + colb + 32] = c12[r];
    Cm[(row0 + 16 + r) * Nn + colb + 48] = c13[r];
  }
}

// ---------------------------------------------------------------------------
// K5: activations on stage-1 LoRA outputs: tanh(h1w), sigmoid(h1g), in place
// ---------------------------------------------------------------------------
__global__ __launch_bounds__(256) void k_act(float* __restrict__ h1w,
                                             float* __restrict__ h1g) {
  int i = blockIdx.x * 256 + threadIdx.x;   // grid covers BT*128
  if (i < BT * 64)  h1w[i] = tanhf(h1w[i]);
  if (i < BT * 128) h1g[i] = sigf(h1g[i]);
}

// ---------------------------------------------------------------------------
// K6: fused stage-2 LoRA dots (f32) + gates + kk-normalize + per-head bonus
// (sum r*k_final*r_k — S-independent, so computed here not in the scan).
// ---------------------------------------------------------------------------
__global__ __launch_bounds__(256) void k_prep2(
    const float* __restrict__ h1w, const float* __restrict__ h1a,
    const float* __restrict__ h1v, const float* __restrict__ h1g,
    const float* __restrict__ w2, const float* __restrict__ a2,
    const float* __restrict__ v2, const float* __restrict__ g2,
    const float* __restrict__ w0, const float* __restrict__ a0,
    const float* __restrict__ v0, const float* __restrict__ kkc,
    const float* __restrict__ kac, float* __restrict__ kbuf,
    float* __restrict__ vbuf, const float* __restrict__ vfirst,
    const float* __restrict__ rbuf, const float* __restrict__ rk,
    float* __restrict__ dec, float* __restrict__ aw,
    float* __restrict__ bw, float* __restrict__ gval,
    float* __restrict__ bonb) {
  __shared__ float hs[288][8];   // w:0-63  a:64-127  v:128-159  g:160-287
  int tid = threadIdx.x;
  int c   = blockIdx.x * 256 + tid;
  int t0  = blockIdx.y * 8;
  for (int e = tid; e < 64 * 8;  e += 256) { int d = e >> 3, q = e & 7; hs[d][q]       = h1w[(t0 + q) * 64  + d]; }
  for (int e = tid; e < 64 * 8;  e += 256) { int d = e >> 3, q = e & 7; hs[64 + d][q]  = h1a[(t0 + q) * 64  + d]; }
  for (int e = tid; e < 32 * 8;  e += 256) { int d = e >> 3, q = e & 7; hs[128 + d][q] = h1v[(t0 + q) * 64  + d]; }
  for (int e = tid; e < 128 * 8; e += 256) { int d = e >> 3, q = e & 7; hs[160 + d][q] = h1g[(t0 + q) * 128 + d]; }
  __syncthreads();
  float wacc[8], aacc[8], vacc[8], gacc[8];
#pragma unroll
  for (int q = 0; q < 8; ++q) { wacc[q] = 0.f; aacc[q] = 0.f; vacc[q] = 0.f; gacc[q] = 0.f; }
  for (int d = 0; d < 64; ++d) {
    float wt = w2[d * CC + c];
    float4 h0 = *(const float4*)&hs[d][0];
    float4 h1 = *(const float4*)&hs[d][4];
    wacc[0] = fmaf(h0.x, wt, wacc[0]); wacc[1] = fmaf(h0.y, wt, wacc[1]);
    wacc[2] = fmaf(h0.z, wt, wacc[2]); wacc[3] = fmaf(h0.w, wt, wacc[3]);
    wacc[4] = fmaf(h1.x, wt, wacc[4]); wacc[5] = fmaf(h1.y, wt, wacc[5]);
    wacc[6] = fmaf(h1.z, wt, wacc[6]); wacc[7] = fmaf(h1.w, wt, wacc[7]);
  }
  for (int d = 0; d < 64; ++d) {
    float at = a2[d * CC + c];
    float4 h0 = *(const float4*)&hs[64 + d][0];
    float4 h1 = *(const float4*)&hs[64 + d][4];
    aacc[0] = fmaf(h0.x, at, aacc[0]); aacc[1] = fmaf(h0.y, at, aacc[1]);
    aacc[2] = fmaf(h0.z, at, aacc[2]); aacc[3] = fmaf(h0.w, at, aacc[3]);
    aacc[4] = fmaf(h1.x, at, aacc[4]); aacc[5] = fmaf(h1.y, at, aacc[5]);
    aacc[6] = fmaf(h1.z, at, aacc[6]); aacc[7] = fmaf(h1.w, at, aacc[7]);
  }
  for (int d = 0; d < 32; ++d) {
    float vt = v2[d * CC + c];
    float4 h0 = *(const float4*)&hs[128 + d][0];
    float4 h1 = *(const float4*)&hs[128 + d][4];
    vacc[0] = fmaf(h0.x, vt, vacc[0]); vacc[1] = fmaf(h0.y, vt, vacc[1]);
    vacc[2] = fmaf(h0.z, vt, vacc[2]); vacc[3] = fmaf(h0.w, vt, vacc[3]);
    vacc[4] = fmaf(h1.x, vt, vacc[4]); vacc[5] = fmaf(h1.y, vt, vacc[5]);
    vacc[6] = fmaf(h1.z, vt, vacc[6]); vacc[7] = fmaf(h1.w, vt, vacc[7]);
  }
  for (int d = 0; d < 128; ++d) {
    float gt = g2[d * CC + c];
    float4 h0 = *(const float4*)&hs[160 + d][0];
    float4 h1 = *(const float4*)&hs[160 + d][4];
    gacc[0] = fmaf(h0.x, gt, gacc[0]); gacc[1] = fmaf(h0.y, gt, gacc[1]);
    gacc[2] = fmaf(h0.z, gt, gacc[2]); gacc[3] = fmaf(h0.w, gt, gacc[3]);
    gacc[4] = fmaf(h1.x, gt, gacc[4]); gacc[5] = fmaf(h1.y, gt, gacc[5]);
    gacc[6] = fmaf(h1.z, gt, gacc[6]); gacc[7] = fmaf(h1.w, gt, gacc[7]);
  }
  float w0v = w0[c], a0v = a0[c], v0v = v0[c], kkv = kkc[c], kav = kac[c];
  float rkc = rk[c];
  for (int q = 0; q < 8; ++q) {
    int idx = (t0 + q) * CC + c;
    float kv = kbuf[idx], vv = vbuf[idx], vf = vfirst[idx];
    float d_ = 0.60653065971f * sigf(w0v + wacc[q]);   // sigmoid * e^-0.5
    float as = sigf(a0v + aacc[q]);
    float vs = sigf(v0v + vacc[q]);
    float vm = vv + (vf - vv) * vs;
    float kfv = kv * (1.0f + kav * (as - 1.0f));
    float kku = kv * kkv;
    float s = kku * kku;     // per-head L2 over 64 lanes (wave == head)
    s += __shfl_xor(s, 1);  s += __shfl_xor(s, 2);  s += __shfl_xor(s, 4);
    s += __shfl_xor(s, 8);  s += __shfl_xor(s, 16); s += __shfl_xor(s, 32);
    float nrm = fmaxf(sqrtf(s), 1e-12f);
    float kkn = kku / nrm;
    // per-head bonus: sum_c r*k_final*r_k  (wave == head)
    float bon = rbuf[idx] * kfv * rkc;
    bon += __shfl_xor(bon, 1);  bon += __shfl_xor(bon, 2);
    bon += __shfl_xor(bon, 4);  bon += __shfl_xor(bon, 8);
    bon += __shfl_xor(bon, 16); bon += __shfl_xor(bon, 32);
    if ((tid & 63) == 0) bonb[(t0 + q) * HH + (c >> 6)] = bon;
    dec[idx] = d_;
    aw[idx]  = -kkn; bw[idx] = kkn * as;
    kbuf[idx] = kfv; vbuf[idx] = vm; gval[idx] = gacc[q];
  }
}

// ---------------------------------------------------------------------------
// K7: WKV7 scan, ROW-PAIR split for TLP + XCD-clustered heads.
// ROUND-9 redesign (evidence: VGPR=108 proved the 8-row 4-deep ring never
// materialized; FETCH 361MB = 3.8x unique input => streams miss per-XCD L2
// and loads are ~900cy HBM-class with only 0.5 waves/SIMD to hide them):
//  - 2048 single-wave blocks (= 8 waves/CU, 2/SIMD): block = (bh, row PAIR).
//    lane L: row = rg*2 + (L>>5), cols c0 = (L&31)*2. S state = 2 floats.
//  - XCD clustering: bh = (blk&7)*8 + (blk>>8) puts all 32 row-pair waves of
//    one head on one XCD (round-robin dispatch) => each head's token stream
//    is HBM-fetched once, siblings hit that XCD's L2 (~200cy not ~900cy).
//  - 8-deep prefetch ring now costs only 8 x 11 = 88 VGPRs, so it actually
//    fits in registers; fences pin issue order.
//  - 32-lane reductions: 4 DPP + 1 ds_swizzle (red32).
// ---------------------------------------------------------------------------
__global__ __launch_bounds__(64) void k_scan(
    const float* __restrict__ rbuf, const float* __restrict__ kf,
    const float* __restrict__ dec, const float* __restrict__ aw,
    const float* __restrict__ bw, const float* __restrict__ vbuf,
    const float* __restrict__ st0, float* __restrict__ ybuf) {
  int blk = blockIdx.x;                     // 0..2047
  int bh  = (blk & 7) * 8 + (blk >> 8);     // all rg of one bh share blk%8 -> one XCD
  int rg  = (blk >> 3) & 31;
  int b = bh >> 5, h = bh & 31;
  int lane = threadIdx.x;
  int row  = rg * 2 + (lane >> 5);
  int c0   = (lane & 31) * 2;
  size_t tokbase = (size_t)b * TT * CC + h * 64;

  float S0, S1;
  {
    const float* sp = st0 + ((size_t)bh * 64 + row) * 64 + c0;
    S0 = sp[0]; S1 = sp[1];
  }

  bool writer = ((lane & 31) == 0);
  float* yout = ybuf + tokbase + row;

  // 8-deep prefetch ring; all indices compile-time constant after unroll.
  float2 Rr[8], Rk[8], Rd[8], Ra[8], Rb[8];
  float  Rv[8];

#define LOADT(SL, T)                                                         \
  { size_t o = tokbase + (size_t)(T) * CC;                                   \
    Rr[SL] = *(const float2*)(rbuf + o + c0);                                \
    Rk[SL] = *(const float2*)(kf   + o + c0);                                \
    Rd[SL] = *(const float2*)(dec  + o + c0);                                \
    Ra[SL] = *(const float2*)(aw   + o + c0);                                \
    Rb[SL] = *(const float2*)(bw   + o + c0);                                \
    Rv[SL] = vbuf[o + row]; }

#define STEP(SL, T)                                                          \
  { float sa = red32(fmaf(S1, Ra[SL].y, S0 * Ra[SL].x));                     \
    float vk0 = Rv[SL] * Rk[SL].x, vk1 = Rv[SL] * Rk[SL].y;                  \
    S0 = fmaf(S0, Rd[SL].x, fmaf(sa, Rb[SL].x, vk0));                        \
    S1 = fmaf(S1, Rd[SL].y, fmaf(sa, Rb[SL].y, vk1));                        \
    float y = red32(fmaf(S1, Rr[SL].y, S0 * Rr[SL].x));                      \
    if (writer) yout[(size_t)(T) * CC] = y; }

#pragma unroll
  for (int s = 0; s < 8; ++s) LOADT(s, s)
  for (int t = 0; t < TT; t += 8) {
#pragma unroll
    for (int s = 0; s < 8; ++s) {
      STEP(s, t + s)
      if (t + 8 + s < TT) LOADT(s, t + 8 + s)
      asm volatile("" ::: "memory");   // pin: reload issues here, 8 steps early
    }
  }
#undef LOADT
#undef STEP
}

// ---------------------------------------------------------------------------
// K8: post-scan epilogue: GroupNorm + bonus + g-gate, fully parallel.
// Block 256 = 4 waves; wave = one (token, head).
// ---------------------------------------------------------------------------
__global__ __launch_bounds__(256) void k_post(
    const float* __restrict__ ybuf, const float* __restrict__ vb,
    const float* __restrict__ gvb, const float* __restrict__ bonb,
    const float* __restrict__ gnw, const float* __restrict__ gnb,
    __hip_bfloat16* __restrict__ xoh, __hip_bfloat16* __restrict__ xol) {
  int tid = threadIdx.x, wv = tid >> 6, lane = tid & 63;
  int id = blockIdx.x * 4 + wv;        // 0..BT*HH-1
  int bt = id >> 5, h = id & 31;
  size_t base = (size_t)bt * CC + h * 64 + lane;
  float y = ybuf[base];
  float s1 = y, s2 = y * y;
#pragma unroll
  for (int off = 1; off < 64; off <<= 1) {
    s1 += __shfl_xor(s1, off);
    s2 += __shfl_xor(s2, off);
  }
  float mean = s1 * (1.0f / 64.0f);
  float var  = s2 * (1.0f / 64.0f) - mean * mean;
  float inv  = rsqrtf(var + GN_EPS);
  float x = fmaf((y - mean) * inv, gnw[h * 64 + lane], gnb[h * 64 + lane])
          + bonb[bt * HH + h] * vb[base];
  split_bf16(x * gvb[base], xoh[base], xol[base]);
}

// ---------------------------------------------------------------------------
extern "C" void kernel_launch(void* const* d_in, const int* in_sizes, int n_in,
                              void* d_out, int out_size, void* d_ws, size_t ws_size,
                              hipStream_t stream) {
  (void)in_sizes; (void)n_in; (void)out_size; (void)ws_size;
  const float* hid    = (const float*)d_in[0];
  const float* shift  = (const float*)d_in[1];
  const float* st0    = (const float*)d_in[2];
  const float* vfirst = (const float*)d_in[3];
  const float* xrc = (const float*)d_in[4];
  const float* xwc = (const float*)d_in[5];
  const float* xkc = (const float*)d_in[6];
  const float* xvc = (const float*)d_in[7];
  const float* xac = (const float*)d_in[8];
  const float* xgc = (const float*)d_in[9];
  const float* w0  = (const float*)d_in[10];
  const float* w1  = (const float*)d_in[11];
  const float* w2  = (const float*)d_in[12];
  const float* a0  = (const float*)d_in[13];
  const float* a1  = (const float*)d_in[14];
  const float* a2  = (const float*)d_in[15];
  const float* v0  = (const float*)d_in[16];
  const float* v1  = (const float*)d_in[17];
  const float* v2  = (const float*)d_in[18];
  const float* g1  = (const float*)d_in[19];
  const float* g2  = (const float*)d_in[20];
  const float* kkc = (const float*)d_in[21];
  const float* kac = (const float*)d_in[22];
  const float* rk  = (const float*)d_in[23];
  const float* Wr  = (const float*)d_in[24];
  const float* Wk  = (const float*)d_in[25];
  const float* Wv  = (const float*)d_in[26];
  const float* Wo  = (const float*)d_in[27];
  const float* gnw = (const float*)d_in[28];
  const float* gnb = (const float*)d_in[29];
  float* out = (float*)d_out;

  char* p = (char*)d_ws;
  auto alloc = [&](size_t n) { char* q = p; p += (n + 255) & ~(size_t)255; return q; };
  const size_t EL = (size_t)BT * CC;

  // --- alias pool (96 MiB): xrh..xvl + Wrh,Wrl dead by k_prep2 time;
  //     db/awb/bwb/gvb (64 MiB) overlay them.
  char* pool = p;
  __hip_bfloat16* xrh = (__hip_bfloat16*)alloc(EL * 2);
  __hip_bfloat16* xrl = (__hip_bfloat16*)alloc(EL * 2);
  __hip_bfloat16* xkh = (__hip_bfloat16*)alloc(EL * 2);
  __hip_bfloat16* xkl = (__hip_bfloat16*)alloc(EL * 2);
  __hip_bfloat16* xvh = (__hip_bfloat16*)alloc(EL * 2);
  __hip_bfloat16* xvl = (__hip_bfloat16*)alloc(EL * 2);
  __hip_bfloat16* Wrh = (__hip_bfloat16*)alloc((size_t)CC * CC * 2);
  __hip_bfloat16* Wrl = (__hip_bfloat16*)alloc((size_t)CC * CC * 2);
  float* db  = (float*)pool;           // overlays xrh+xrl
  float* awb = db + EL;                // overlays xkh+xkl
  float* bwb = db + 2 * EL;            // overlays xvh+xvl
  float* gvb = db + 3 * EL;            // overlays Wrh+Wrl

  __hip_bfloat16* Wkh = (__hip_bfloat16*)alloc((size_t)CC * CC * 2);
  __hip_bfloat16* Wkl = (__hip_bfloat16*)alloc((size_t)CC * CC * 2);
  float* ybuf = (float*)Wkh;           // overlays Wkh+Wkl (dead after k-GEMM)

  __hip_bfloat16* Wvh = (__hip_bfloat16*)alloc((size_t)CC * CC * 2);
  __hip_bfloat16* Wvl = (__hip_bfloat16*)alloc((size_t)CC * CC * 2);
  __hip_bfloat16* Woh = (__hip_bfloat16*)alloc((size_t)CC * CC * 2);
  __hip_bfloat16* Wol = (__hip_bfloat16*)alloc((size_t)CC * CC * 2);
  __hip_bfloat16* xw  = (__hip_bfloat16*)alloc(EL * 2);
  __hip_bfloat16* xa  = (__hip_bfloat16*)alloc(EL * 2);
  __hip_bfloat16* xg  = (__hip_bfloat16*)alloc(EL * 2);
  __hip_bfloat16* w1t = (__hip_bfloat16*)alloc((size_t)64  * CC * 2);
  __hip_bfloat16* a1t = (__hip_bfloat16*)alloc((size_t)64  * CC * 2);
  __hip_bfloat16* v1t = (__hip_bfloat16*)alloc((size_t)64  * CC * 2);
  __hip_bfloat16* g1t = (__hip_bfloat16*)alloc((size_t)128 * CC * 2);
  float* rb  = (float*)alloc(EL * 4);
  float* kb  = (float*)alloc(EL * 4);  // raw k, then k_final in place
  float* vb  = (float*)alloc(EL * 4);  // raw v, then v_mix in place
  float* h1w = (float*)alloc((size_t)BT * 64  * 4);
  float* h1a = (float*)alloc((size_t)BT * 64  * 4);
  float* h1v = (float*)alloc((size_t)BT * 64  * 4);
  float* h1g = (float*)alloc((size_t)BT * 128 * 4);
  __hip_bfloat16* xoh = (__hip_bfloat16*)alloc(EL * 2);
  __hip_bfloat16* xol = (__hip_bfloat16*)alloc(EL * 2);
  float* bonb = (float*)alloc((size_t)BT * HH * 4);   // per-(token,head) bonus
  // total ~204.5 MiB (fits: 220 MiB known-OK, 268 MiB crashed)

  k_prepx<<<16384, 256, 0, stream>>>(hid, shift, xrc, xwc, xkc, xvc, xac, xgc,
                                     xrh, xrl, xw, xkh, xkl, xvh, xvl, xa, xg);
  k_cvt2<<<16384, 256, 0, stream>>>(Wr, Wrh, Wrl);
  k_cvt2<<<16384, 256, 0, stream>>>(Wk, Wkh, Wkl);
  k_cvt2<<<16384, 256, 0, stream>>>(Wv, Wvh, Wvl);
  k_cvt2<<<16384, 256, 0, stream>>>(Wo, Woh, Wol);
  k_tr<<<512, 256, 0, stream>>>(w1, w1t, 64);
  k_tr<<<512, 256, 0, stream>>>(a1, a1t, 64);
  k_tr<<<512, 256, 0, stream>>>(v1, v1t, 32);
  k_tr<<<1024, 256, 0, stream>>>(g1, g1t, 128);

  k_gemm_bt3<<<dim3(16, 32), 256, 0, stream>>>(xrh, xrl, Wrh, Wrl, rb, BT, CC, CC);
  k_gemm_bt3<<<dim3(16, 32), 256, 0, stream>>>(xkh, xkl, Wkh, Wkl, kb, BT, CC, CC);
  k_gemm_bt3<<<dim3(16, 32), 256, 0, stream>>>(xvh, xvl, Wvh, Wvl, vb, BT, CC, CC);
  k_gemm_bt<<<dim3(16, 1),  256, 0, stream>>>(xw,  w1t, h1w, BT, 64, CC);
  k_gemm_bt<<<dim3(16, 1),  256, 0, stream>>>(xa,  a1t, h1a, BT, 64, CC);
  k_gemm_bt<<<dim3(16, 1),  256, 0, stream>>>(xvh, v1t, h1v, BT, 64, CC);
  k_gemm_bt<<<dim3(16, 2),  256, 0, stream>>>(xg,  g1t, h1g, BT, 128, CC);

  k_act<<<1024, 256, 0, stream>>>(h1w, h1g);
  // from here: xrh..xvl / Wrh,Wrl dead (db/awb/bwb/gvb overlay);
  //            Wkh/Wkl dead (ybuf overlay)
  k_prep2<<<dim3(8, 256), 256, 0, stream>>>(h1w, h1a, h1v, h1g, w2, a2, v2, g2,
                                            w0, a0, v0, kkc, kac, kb, vb, vfirst,
                                            rb, rk, db, awb, bwb, gvb, bonb);
  k_scan<<<2048, 64, 0, stream>>>(rb, kb, db, awb, bwb, vb, st0, ybuf);
  k_post<<<16384, 256, 0, stream>>>(ybuf, vb, gvb, bonb, gnw, gnb, xoh, xol);
  k_gemm_bt3<<<dim3(16, 32), 256, 0, stream>>>(xoh, xol, Woh, Wol, out, BT, CC, CC);
}

// Round 4
// 1624.611 us; speedup vs baseline: 1.1401x; 1.0691x over previous
//
#include <hip/hip_runtime.h>
#include <hip/hip_bf16.h>

// Problem constants (RWKV-7 Tmix: B=2, T=1024, C=2048, H=32, N=64)
#define BB 2
#define TT 1024
#define CC 2048
#define HH 32
#define BT 2048          // BB*TT tokens
#define GN_EPS 6.4e-4f   // 1e-5 * 8^2

typedef __attribute__((ext_vector_type(8))) __bf16 bf16x8;
typedef __attribute__((ext_vector_type(4))) float f32x4;

__device__ __forceinline__ float sigf(float x) { return 1.0f / (1.0f + expf(-x)); }

__device__ __forceinline__ void split_bf16(float x, __hip_bfloat16& hi, __hip_bfloat16& lo) {
  __hip_bfloat16 h = __float2bfloat16(x);
  hi = h;
  lo = __float2bfloat16(x - __bfloat162float(h));
}

// Sum over each aligned 16-lane group, pure DPP (no LDS pipe on the chain):
// quad_perm xor1, quad_perm xor2 -> quads uniform; row_half_mirror adds the
// other quad of the 8-half (xor4-equivalent given quad uniformity);
// row_mirror adds the other 8-half of the 16-row (xor8-equivalent).
// DPP row ops never cross 16-lane rows, and our groups are aligned 16-rows.
__device__ __forceinline__ float red16(float x) {
  x += __int_as_float(__builtin_amdgcn_update_dpp(
      0, __float_as_int(x), 0xB1 /*quad_perm [1,0,3,2]*/, 0xF, 0xF, true));
  x += __int_as_float(__builtin_amdgcn_update_dpp(
      0, __float_as_int(x), 0x4E /*quad_perm [2,3,0,1]*/, 0xF, 0xF, true));
  x += __int_as_float(__builtin_amdgcn_update_dpp(
      0, __float_as_int(x), 0x141 /*row_half_mirror*/, 0xF, 0xF, true));
  x += __int_as_float(__builtin_amdgcn_update_dpp(
      0, __float_as_int(x), 0x140 /*row_mirror*/, 0xF, 0xF, true));
  return x;
}

// ---------------------------------------------------------------------------
// K1: token shift + six lerped projections. r/k/v hi+lo split (all scan
// inputs are error-critical — round-4 lesson); w/a/g plain bf16.
// ---------------------------------------------------------------------------
__global__ __launch_bounds__(256) void k_prepx(
    const float* __restrict__ hid, const float* __restrict__ shift,
    const float* __restrict__ xrc, const float* __restrict__ xwc,
    const float* __restrict__ xkc, const float* __restrict__ xvc,
    const float* __restrict__ xac, const float* __restrict__ xgc,
    __hip_bfloat16* __restrict__ xrh, __hip_bfloat16* __restrict__ xrl,
    __hip_bfloat16* __restrict__ xw,
    __hip_bfloat16* __restrict__ xkh, __hip_bfloat16* __restrict__ xkl,
    __hip_bfloat16* __restrict__ xvh, __hip_bfloat16* __restrict__ xvl,
    __hip_bfloat16* __restrict__ xa, __hip_bfloat16* __restrict__ xg) {
  int idx = blockIdx.x * 256 + threadIdx.x;   // < BT*CC
  int c  = idx & (CC - 1);
  int bt = idx >> 11;
  int t  = bt & (TT - 1);
  int b  = bt >> 10;
  float hcur  = hid[idx];
  float hprev = (t == 0) ? shift[b * CC + c] : hid[idx - CC];
  float xx = hprev - hcur;
  split_bf16(fmaf(xx, xrc[c], hcur), xrh[idx], xrl[idx]);
  split_bf16(fmaf(xx, xkc[c], hcur), xkh[idx], xkl[idx]);
  split_bf16(fmaf(xx, xvc[c], hcur), xvh[idx], xvl[idx]);
  xw[idx] = __float2bfloat16(fmaf(xx, xwc[c], hcur));
  xa[idx] = __float2bfloat16(fmaf(xx, xac[c], hcur));
  xg[idx] = __float2bfloat16(fmaf(xx, xgc[c], hcur));
}

// ---------------------------------------------------------------------------
// K2: f32 -> hi+lo bf16 split (for Wr/Wk/Wv/Wo)
// ---------------------------------------------------------------------------
__global__ __launch_bounds__(256) void k_cvt2(const float* __restrict__ in,
                                              __hip_bfloat16* __restrict__ oh,
                                              __hip_bfloat16* __restrict__ ol) {
  int i = blockIdx.x * 256 + threadIdx.x;
  split_bf16(in[i], oh[i], ol[i]);
}

// ---------------------------------------------------------------------------
// K3: transpose-convert small LoRA "up" weights: in [2048][N0] f32 ->
//     out [NP][2048] bf16 (rows >= N0 zero-padded).
// ---------------------------------------------------------------------------
__global__ __launch_bounds__(256) void k_tr(const float* __restrict__ in,
                                            __hip_bfloat16* __restrict__ out,
                                            int N0) {
  int i = blockIdx.x * 256 + threadIdx.x;   // over NP*2048, grid exact
  int n = i >> 11;
  int k = i & 2047;
  float v = (n < N0) ? in[k * N0 + n] : 0.0f;
  out[i] = __float2bfloat16(v);
}

// ---------------------------------------------------------------------------
// K4: plain bf16 MFMA GEMM, C[M,N] f32 = A[M,K] @ B[N,K]^T
// (LoRA stage-1 only: error-damped through gates)
// ---------------------------------------------------------------------------
__global__ __launch_bounds__(256) void k_gemm_bt(
    const __hip_bfloat16* __restrict__ A, const __hip_bfloat16* __restrict__ Bm,
    float* __restrict__ Cm, int M, int Nn, int K) {
  int tid  = threadIdx.x;
  int lane = tid & 63;
  int wv   = tid >> 6;
  int l15  = lane & 15;
  int quad = lane >> 4;
  int m0 = blockIdx.x * 128 + wv * 32;
  int n0 = blockIdx.y * 64;
  const __hip_bfloat16* ap0 = A + (m0 + l15) * K + quad * 8;
  const __hip_bfloat16* ap1 = ap0 + 16 * K;
  const __hip_bfloat16* bp  = Bm + (n0 + l15) * K + quad * 8;
  f32x4 z = {0.f, 0.f, 0.f, 0.f};
  f32x4 c00 = z, c01 = z, c02 = z, c03 = z;
  f32x4 c10 = z, c11 = z, c12 = z, c13 = z;
  for (int k0 = 0; k0 < K; k0 += 32) {
    bf16x8 a0v = *(const bf16x8*)(ap0 + k0);
    bf16x8 a1v = *(const bf16x8*)(ap1 + k0);
    bf16x8 b0v = *(const bf16x8*)(bp + k0);
    bf16x8 b1v = *(const bf16x8*)(bp + 16 * K + k0);
    bf16x8 b2v = *(const bf16x8*)(bp + 32 * K + k0);
    bf16x8 b3v = *(const bf16x8*)(bp + 48 * K + k0);
    c00 = __builtin_amdgcn_mfma_f32_16x16x32_bf16(a0v, b0v, c00, 0, 0, 0);
    c01 = __builtin_amdgcn_mfma_f32_16x16x32_bf16(a0v, b1v, c01, 0, 0, 0);
    c02 = __builtin_amdgcn_mfma_f32_16x16x32_bf16(a0v, b2v, c02, 0, 0, 0);
    c03 = __builtin_amdgcn_mfma_f32_16x16x32_bf16(a0v, b3v, c03, 0, 0, 0);
    c10 = __builtin_amdgcn_mfma_f32_16x16x32_bf16(a1v, b0v, c10, 0, 0, 0);
    c11 = __builtin_amdgcn_mfma_f32_16x16x32_bf16(a1v, b1v, c11, 0, 0, 0);
    c12 = __builtin_amdgcn_mfma_f32_16x16x32_bf16(a1v, b2v, c12, 0, 0, 0);
    c13 = __builtin_amdgcn_mfma_f32_16x16x32_bf16(a1v, b3v, c13, 0, 0, 0);
  }
  int colb = n0 + l15;
  int row0 = m0 + quad * 4;
#pragma unroll
  for (int r = 0; r < 4; ++r) {
    Cm[(row0 + r) * Nn + colb +  0] = c00[r];
    Cm[(row0 + r) * Nn + colb + 16] = c01[r];
    Cm[(row0 + r) * Nn + colb + 32] = c02[r];
    Cm[(row0 + r) * Nn + colb + 48] = c03[r];
    Cm[(row0 + 16 + r) * Nn + colb +  0] = c10[r];
    Cm[(row0 + 16 + r) * Nn + colb + 16] = c11[r];
    Cm[(row0 + 16 + r) * Nn + colb + 32] = c12[r];
    Cm[(row0 + 16 + r) * Nn + colb + 48] = c13[r];
  }
}

// ---------------------------------------------------------------------------
// K4b: split-precision GEMM: C = (Ah+Al)@(Bh+Bl)^T ~= Ah Bh + Ah Bl + Al Bh.
// ---------------------------------------------------------------------------
__global__ __launch_bounds__(256) void k_gemm_bt3(
    const __hip_bfloat16* __restrict__ Ah, const __hip_bfloat16* __restrict__ Al,
    const __hip_bfloat16* __restrict__ Bh, const __hip_bfloat16* __restrict__ Bl,
    float* __restrict__ Cm, int M, int Nn, int K) {
  int tid  = threadIdx.x;
  int lane = tid & 63;
  int wv   = tid >> 6;
  int l15  = lane & 15;
  int quad = lane >> 4;
  int m0 = blockIdx.x * 128 + wv * 32;
  int n0 = blockIdx.y * 64;
  size_t aoff0 = (size_t)(m0 + l15) * K + quad * 8;
  size_t aoff1 = aoff0 + (size_t)16 * K;
  size_t boff  = (size_t)(n0 + l15) * K + quad * 8;
  f32x4 z = {0.f, 0.f, 0.f, 0.f};
  f32x4 c00 = z, c01 = z, c02 = z, c03 = z;
  f32x4 c10 = z, c11 = z, c12 = z, c13 = z;
  for (int k0 = 0; k0 < K; k0 += 32) {
    bf16x8 a0h = *(const bf16x8*)(Ah + aoff0 + k0);
    bf16x8 a1h = *(const bf16x8*)(Ah + aoff1 + k0);
    bf16x8 a0l = *(const bf16x8*)(Al + aoff0 + k0);
    bf16x8 a1l = *(const bf16x8*)(Al + aoff1 + k0);
    bf16x8 bh0 = *(const bf16x8*)(Bh + boff + k0);
    bf16x8 bh1 = *(const bf16x8*)(Bh + boff + (size_t)16 * K + k0);
    bf16x8 bh2 = *(const bf16x8*)(Bh + boff + (size_t)32 * K + k0);
    bf16x8 bh3 = *(const bf16x8*)(Bh + boff + (size_t)48 * K + k0);
    bf16x8 bl0 = *(const bf16x8*)(Bl + boff + k0);
    bf16x8 bl1 = *(const bf16x8*)(Bl + boff + (size_t)16 * K + k0);
    bf16x8 bl2 = *(const bf16x8*)(Bl + boff + (size_t)32 * K + k0);
    bf16x8 bl3 = *(const bf16x8*)(Bl + boff + (size_t)48 * K + k0);
    c00 = __builtin_amdgcn_mfma_f32_16x16x32_bf16(a0h, bh0, c00, 0, 0, 0);
    c01 = __builtin_amdgcn_mfma_f32_16x16x32_bf16(a0h, bh1, c01, 0, 0, 0);
    c02 = __builtin_amdgcn_mfma_f32_16x16x32_bf16(a0h, bh2, c02, 0, 0, 0);
    c03 = __builtin_amdgcn_mfma_f32_16x16x32_bf16(a0h, bh3, c03, 0, 0, 0);
    c10 = __builtin_amdgcn_mfma_f32_16x16x32_bf16(a1h, bh0, c10, 0, 0, 0);
    c11 = __builtin_amdgcn_mfma_f32_16x16x32_bf16(a1h, bh1, c11, 0, 0, 0);
    c12 = __builtin_amdgcn_mfma_f32_16x16x32_bf16(a1h, bh2, c12, 0, 0, 0);
    c13 = __builtin_amdgcn_mfma_f32_16x16x32_bf16(a1h, bh3, c13, 0, 0, 0);
    c00 = __builtin_amdgcn_mfma_f32_16x16x32_bf16(a0h, bl0, c00, 0, 0, 0);
    c01 = __builtin_amdgcn_mfma_f32_16x16x32_bf16(a0h, bl1, c01, 0, 0, 0);
    c02 = __builtin_amdgcn_mfma_f32_16x16x32_bf16(a0h, bl2, c02, 0, 0, 0);
    c03 = __builtin_amdgcn_mfma_f32_16x16x32_bf16(a0h, bl3, c03, 0, 0, 0);
    c10 = __builtin_amdgcn_mfma_f32_16x16x32_bf16(a1h, bl0, c10, 0, 0, 0);
    c11 = __builtin_amdgcn_mfma_f32_16x16x32_bf16(a1h, bl1, c11, 0, 0, 0);
    c12 = __builtin_amdgcn_mfma_f32_16x16x32_bf16(a1h, bl2, c12, 0, 0, 0);
    c13 = __builtin_amdgcn_mfma_f32_16x16x32_bf16(a1h, bl3, c13, 0, 0, 0);
    c00 = __builtin_amdgcn_mfma_f32_16x16x32_bf16(a0l, bh0, c00, 0, 0, 0);
    c01 = __builtin_amdgcn_mfma_f32_16x16x32_bf16(a0l, bh1, c01, 0, 0, 0);
    c02 = __builtin_amdgcn_mfma_f32_16x16x32_bf16(a0l, bh2, c02, 0, 0, 0);
    c03 = __builtin_amdgcn_mfma_f32_16x16x32_bf16(a0l, bh3, c03, 0, 0, 0);
    c10 = __builtin_amdgcn_mfma_f32_16x16x32_bf16(a1l, bh0, c10, 0, 0, 0);
    c11 = __builtin_amdgcn_mfma_f32_16x16x32_bf16(a1l, bh1, c11, 0, 0, 0);
    c12 = __builtin_amdgcn_mfma_f32_16x16x32_bf16(a1l, bh2, c12, 0, 0, 0);
    c13 = __builtin_amdgcn_mfma_f32_16x16x32_bf16(a1l, bh3, c13, 0, 0, 0);
  }
  int colb = n0 + l15;
  int row0 = m0 + quad * 4;
#pragma unroll
  for (int r = 0; r < 4; ++r) {
    Cm[(row0 + r) * Nn + colb +  0] = c00[r];
    Cm[(row0 + r) * Nn + colb + 16] = c01[r];
    Cm[(row0 + r) * Nn + colb + 32] = c02[r];
    Cm[(row0 + r) * Nn + colb + 48] = c03[r];
    Cm[(row0 + 16 + r) * Nn + colb +  0] = c10[r];
    Cm[(row0 + 16 + r) * Nn + colb + 16] = c11[r];
    Cm[(row0 + 16 + r) * Nn + colb + 32] = c12[r];
    Cm[(row0 + 16 + r) * Nn + colb + 48] = c13[r];
  }
}

// ---------------------------------------------------------------------------
// K5: activations on stage-1 LoRA outputs: tanh(h1w), sigmoid(h1g), in place
// ---------------------------------------------------------------------------
__global__ __launch_bounds__(256) void k_act(float* __restrict__ h1w,
                                             float* __restrict__ h1g) {
  int i = blockIdx.x * 256 + threadIdx.x;   // grid covers BT*128
  if (i < BT * 64)  h1w[i] = tanhf(h1w[i]);
  if (i < BT * 128) h1g[i] = sigf(h1g[i]);
}

// ---------------------------------------------------------------------------
// K6: fused stage-2 LoRA dots (f32) + gates + kk-normalize + per-head bonus
// (sum r*k_final*r_k — S-independent, so computed here not in the scan).
// ---------------------------------------------------------------------------
__global__ __launch_bounds__(256) void k_prep2(
    const float* __restrict__ h1w, const float* __restrict__ h1a,
    const float* __restrict__ h1v, const float* __restrict__ h1g,
    const float* __restrict__ w2, const float* __restrict__ a2,
    const float* __restrict__ v2, const float* __restrict__ g2,
    const float* __restrict__ w0, const float* __restrict__ a0,
    const float* __restrict__ v0, const float* __restrict__ kkc,
    const float* __restrict__ kac, float* __restrict__ kbuf,
    float* __restrict__ vbuf, const float* __restrict__ vfirst,
    const float* __restrict__ rbuf, const float* __restrict__ rk,
    float* __restrict__ dec, float* __restrict__ aw,
    float* __restrict__ bw, float* __restrict__ gval,
    float* __restrict__ bonb) {
  __shared__ float hs[288][8];   // w:0-63  a:64-127  v:128-159  g:160-287
  int tid = threadIdx.x;
  int c   = blockIdx.x * 256 + tid;
  int t0  = blockIdx.y * 8;
  for (int e = tid; e < 64 * 8;  e += 256) { int d = e >> 3, q = e & 7; hs[d][q]       = h1w[(t0 + q) * 64  + d]; }
  for (int e = tid; e < 64 * 8;  e += 256) { int d = e >> 3, q = e & 7; hs[64 + d][q]  = h1a[(t0 + q) * 64  + d]; }
  for (int e = tid; e < 32 * 8;  e += 256) { int d = e >> 3, q = e & 7; hs[128 + d][q] = h1v[(t0 + q) * 64  + d]; }
  for (int e = tid; e < 128 * 8; e += 256) { int d = e >> 3, q = e & 7; hs[160 + d][q] = h1g[(t0 + q) * 128 + d]; }
  __syncthreads();
  float wacc[8], aacc[8], vacc[8], gacc[8];
#pragma unroll
  for (int q = 0; q < 8; ++q) { wacc[q] = 0.f; aacc[q] = 0.f; vacc[q] = 0.f; gacc[q] = 0.f; }
  for (int d = 0; d < 64; ++d) {
    float wt = w2[d * CC + c];
    float4 h0 = *(const float4*)&hs[d][0];
    float4 h1 = *(const float4*)&hs[d][4];
    wacc[0] = fmaf(h0.x, wt, wacc[0]); wacc[1] = fmaf(h0.y, wt, wacc[1]);
    wacc[2] = fmaf(h0.z, wt, wacc[2]); wacc[3] = fmaf(h0.w, wt, wacc[3]);
    wacc[4] = fmaf(h1.x, wt, wacc[4]); wacc[5] = fmaf(h1.y, wt, wacc[5]);
    wacc[6] = fmaf(h1.z, wt, wacc[6]); wacc[7] = fmaf(h1.w, wt, wacc[7]);
  }
  for (int d = 0; d < 64; ++d) {
    float at = a2[d * CC + c];
    float4 h0 = *(const float4*)&hs[64 + d][0];
    float4 h1 = *(const float4*)&hs[64 + d][4];
    aacc[0] = fmaf(h0.x, at, aacc[0]); aacc[1] = fmaf(h0.y, at, aacc[1]);
    aacc[2] = fmaf(h0.z, at, aacc[2]); aacc[3] = fmaf(h0.w, at, aacc[3]);
    aacc[4] = fmaf(h1.x, at, aacc[4]); aacc[5] = fmaf(h1.y, at, aacc[5]);
    aacc[6] = fmaf(h1.z, at, aacc[6]); aacc[7] = fmaf(h1.w, at, aacc[7]);
  }
  for (int d = 0; d < 32; ++d) {
    float vt = v2[d * CC + c];
    float4 h0 = *(const float4*)&hs[128 + d][0];
    float4 h1 = *(const float4*)&hs[128 + d][4];
    vacc[0] = fmaf(h0.x, vt, vacc[0]); vacc[1] = fmaf(h0.y, vt, vacc[1]);
    vacc[2] = fmaf(h0.z, vt, vacc[2]); vacc[3] = fmaf(h0.w, vt, vacc[3]);
    vacc[4] = fmaf(h1.x, vt, vacc[4]); vacc[5] = fmaf(h1.y, vt, vacc[5]);
    vacc[6] = fmaf(h1.z, vt, vacc[6]); vacc[7] = fmaf(h1.w, vt, vacc[7]);
  }
  for (int d = 0; d < 128; ++d) {
    float gt = g2[d * CC + c];
    float4 h0 = *(const float4*)&hs[160 + d][0];
    float4 h1 = *(const float4*)&hs[160 + d][4];
    gacc[0] = fmaf(h0.x, gt, gacc[0]); gacc[1] = fmaf(h0.y, gt, gacc[1]);
    gacc[2] = fmaf(h0.z, gt, gacc[2]); gacc[3] = fmaf(h0.w, gt, gacc[3]);
    gacc[4] = fmaf(h1.x, gt, gacc[4]); gacc[5] = fmaf(h1.y, gt, gacc[5]);
    gacc[6] = fmaf(h1.z, gt, gacc[6]); gacc[7] = fmaf(h1.w, gt, gacc[7]);
  }
  float w0v = w0[c], a0v = a0[c], v0v = v0[c], kkv = kkc[c], kav = kac[c];
  float rkc = rk[c];
  for (int q = 0; q < 8; ++q) {
    int idx = (t0 + q) * CC + c;
    float kv = kbuf[idx], vv = vbuf[idx], vf = vfirst[idx];
    float d_ = 0.60653065971f * sigf(w0v + wacc[q]);   // sigmoid * e^-0.5
    float as = sigf(a0v + aacc[q]);
    float vs = sigf(v0v + vacc[q]);
    float vm = vv + (vf - vv) * vs;
    float kfv = kv * (1.0f + kav * (as - 1.0f));
    float kku = kv * kkv;
    float s = kku * kku;     // per-head L2 over 64 lanes (wave == head)
    s += __shfl_xor(s, 1);  s += __shfl_xor(s, 2);  s += __shfl_xor(s, 4);
    s += __shfl_xor(s, 8);  s += __shfl_xor(s, 16); s += __shfl_xor(s, 32);
    float nrm = fmaxf(sqrtf(s), 1e-12f);
    float kkn = kku / nrm;
    // per-head bonus: sum_c r*k_final*r_k  (wave == head)
    float bon = rbuf[idx] * kfv * rkc;
    bon += __shfl_xor(bon, 1);  bon += __shfl_xor(bon, 2);
    bon += __shfl_xor(bon, 4);  bon += __shfl_xor(bon, 8);
    bon += __shfl_xor(bon, 16); bon += __shfl_xor(bon, 32);
    if ((tid & 63) == 0) bonb[(t0 + q) * HH + (c >> 6)] = bon;
    dec[idx] = d_;
    aw[idx]  = -kkn; bw[idx] = kkn * as;
    kbuf[idx] = kfv; vbuf[idx] = vm; gval[idx] = gacc[q];
  }
}

// ---------------------------------------------------------------------------
// K7: WKV7 scan — ROUND-11.
// ROOT CAUSE of rounds 7-10: __launch_bounds__(64) without a min-waves arg
// let the allocator target high occupancy -> VGPR cap 64-112 -> every
// prefetch ring spilled/collapsed (round-2: VGPR=64 vs the 88+ the ring
// needs). FIX: __launch_bounds__(64, 1) (1 wave/EU -> up to 512 VGPRs).
// Round-3's inline-asm loads crashed (asm defs vs. async data arrival is
// UB with regalloc copies) — reverted to plain C++ loads; the compiler
// inserts its own counted vmcnt before uses (known-good, m97).
// Geometry: wave = (bh, row-group of 4); row = rg*4+(lane>>4), cols
// (lane&15)*4..+4 (float4 S). Reductions: red16 = 4 pure-DPP ops — no
// ds_swizzle/lgkmcnt on the serial chain (round-2 red32 had one).
// 8-deep C++ float4 ring (168 regs) + issue-order fences.
// Blocks = 1024: bh = (blk&7)*8 + ((blk>>3)&7), rg = blk>>6 — all 16
// row-waves of a head share blk%8 -> one XCD -> L2-local (round-2: FETCH
// 361->50MB proved this works).
// ---------------------------------------------------------------------------
__global__ __launch_bounds__(64, 1) void k_scan(
    const float* __restrict__ rbuf, const float* __restrict__ kf,
    const float* __restrict__ dec, const float* __restrict__ aw,
    const float* __restrict__ bw, const float* __restrict__ vbuf,
    const float* __restrict__ st0, float* __restrict__ ybuf) {
  int blk = blockIdx.x;                     // 0..1023
  int xcd = blk & 7;
  int q   = blk >> 3;                       // 0..127
  int bh  = xcd * 8 + (q & 7);              // all 16 rg-waves of a head share blk%8
  int rg  = q >> 3;                         // 0..15
  int b = bh >> 5, h = bh & 31;
  int lane = threadIdx.x;
  int row  = rg * 4 + (lane >> 4);
  int c0   = (lane & 15) * 4;
  size_t tokbase = (size_t)b * TT * CC + h * 64;

  float4 S = *(const float4*)(st0 + ((size_t)bh * 64 + row) * 64 + c0);

  bool writer = ((lane & 15) == 0);
  float* yout = ybuf + tokbase + row;

  const float* pr = rbuf + tokbase + c0;
  const float* pk = kf   + tokbase + c0;
  const float* pd = dec  + tokbase + c0;
  const float* pa = aw   + tokbase + c0;
  const float* pb = bw   + tokbase + c0;
  const float* pv = vbuf + tokbase + row;

  // 8-deep prefetch ring; indices compile-time constant after full unroll.
  float4 Rr[8], Rk[8], Rd[8], Ra[8], Rb[8];
  float  Rv[8];

#define LOADT(SL, T)                                                         \
  { size_t oo = (size_t)(T) * CC;                                            \
    Rr[SL] = *(const float4*)(pr + oo);                                      \
    Rk[SL] = *(const float4*)(pk + oo);                                      \
    Rd[SL] = *(const float4*)(pd + oo);                                      \
    Ra[SL] = *(const float4*)(pa + oo);                                      \
    Rb[SL] = *(const float4*)(pb + oo);                                      \
    Rv[SL] = pv[oo]; }

#define STEP(SL, T)                                                          \
  { float sa = fmaf(S.w, Ra[SL].w, fmaf(S.z, Ra[SL].z,                       \
               fmaf(S.y, Ra[SL].y, S.x * Ra[SL].x)));                        \
    sa = red16(sa);                                                          \
    float vv = Rv[SL];                                                       \
    S.x = fmaf(S.x, Rd[SL].x, fmaf(sa, Rb[SL].x, vv * Rk[SL].x));            \
    S.y = fmaf(S.y, Rd[SL].y, fmaf(sa, Rb[SL].y, vv * Rk[SL].y));            \
    S.z = fmaf(S.z, Rd[SL].z, fmaf(sa, Rb[SL].z, vv * Rk[SL].z));            \
    S.w = fmaf(S.w, Rd[SL].w, fmaf(sa, Rb[SL].w, vv * Rk[SL].w));            \
    float y = fmaf(S.w, Rr[SL].w, fmaf(S.z, Rr[SL].z,                        \
              fmaf(S.y, Rr[SL].y, S.x * Rr[SL].x)));                         \
    y = red16(y);                                                            \
    if (writer) yout[(size_t)(T) * CC] = y; }

#pragma unroll
  for (int s = 0; s < 8; ++s) LOADT(s, s)
  for (int t = 0; t < TT; t += 8) {
#pragma unroll
    for (int s = 0; s < 8; ++s) {
      STEP(s, t + s)
      if (t + 8 + s < TT) LOADT(s, t + 8 + s)
      asm volatile("" ::: "memory");   // pin: reload issues here, 8 steps early
    }
  }
#undef LOADT
#undef STEP
}

// ---------------------------------------------------------------------------
// K8: post-scan epilogue: GroupNorm + bonus + g-gate, fully parallel.
// Block 256 = 4 waves; wave = one (token, head).
// ---------------------------------------------------------------------------
__global__ __launch_bounds__(256) void k_post(
    const float* __restrict__ ybuf, const float* __restrict__ vb,
    const float* __restrict__ gvb, const float* __restrict__ bonb,
    const float* __restrict__ gnw, const float* __restrict__ gnb,
    __hip_bfloat16* __restrict__ xoh, __hip_bfloat16* __restrict__ xol) {
  int tid = threadIdx.x, wv = tid >> 6, lane = tid & 63;
  int id = blockIdx.x * 4 + wv;        // 0..BT*HH-1
  int bt = id >> 5, h = id & 31;
  size_t base = (size_t)bt * CC + h * 64 + lane;
  float y = ybuf[base];
  float s1 = y, s2 = y * y;
#pragma unroll
  for (int off = 1; off < 64; off <<= 1) {
    s1 += __shfl_xor(s1, off);
    s2 += __shfl_xor(s2, off);
  }
  float mean = s1 * (1.0f / 64.0f);
  float var  = s2 * (1.0f / 64.0f) - mean * mean;
  float inv  = rsqrtf(var + GN_EPS);
  float x = fmaf((y - mean) * inv, gnw[h * 64 + lane], gnb[h * 64 + lane])
          + bonb[bt * HH + h] * vb[base];
  split_bf16(x * gvb[base], xoh[base], xol[base]);
}

// ---------------------------------------------------------------------------
extern "C" void kernel_launch(void* const* d_in, const int* in_sizes, int n_in,
                              void* d_out, int out_size, void* d_ws, size_t ws_size,
                              hipStream_t stream) {
  (void)in_sizes; (void)n_in; (void)out_size; (void)ws_size;
  const float* hid    = (const float*)d_in[0];
  const float* shift  = (const float*)d_in[1];
  const float* st0    = (const float*)d_in[2];
  const float* vfirst = (const float*)d_in[3];
  const float* xrc = (const float*)d_in[4];
  const float* xwc = (const float*)d_in[5];
  const float* xkc = (const float*)d_in[6];
  const float* xvc = (const float*)d_in[7];
  const float* xac = (const float*)d_in[8];
  const float* xgc = (const float*)d_in[9];
  const float* w0  = (const float*)d_in[10];
  const float* w1  = (const float*)d_in[11];
  const float* w2  = (const float*)d_in[12];
  const float* a0  = (const float*)d_in[13];
  const float* a1  = (const float*)d_in[14];
  const float* a2  = (const float*)d_in[15];
  const float* v0  = (const float*)d_in[16];
  const float* v1  = (const float*)d_in[17];
  const float* v2  = (const float*)d_in[18];
  const float* g1  = (const float*)d_in[19];
  const float* g2  = (const float*)d_in[20];
  const float* kkc = (const float*)d_in[21];
  const float* kac = (const float*)d_in[22];
  const float* rk  = (const float*)d_in[23];
  const float* Wr  = (const float*)d_in[24];
  const float* Wk  = (const float*)d_in[25];
  const float* Wv  = (const float*)d_in[26];
  const float* Wo  = (const float*)d_in[27];
  const float* gnw = (const float*)d_in[28];
  const float* gnb = (const float*)d_in[29];
  float* out = (float*)d_out;

  char* p = (char*)d_ws;
  auto alloc = [&](size_t n) { char* q = p; p += (n + 255) & ~(size_t)255; return q; };
  const size_t EL = (size_t)BT * CC;

  // --- alias pool (96 MiB): xrh..xvl + Wrh,Wrl dead by k_prep2 time;
  //     db/awb/bwb/gvb (64 MiB) overlay them.
  char* pool = p;
  __hip_bfloat16* xrh = (__hip_bfloat16*)alloc(EL * 2);
  __hip_bfloat16* xrl = (__hip_bfloat16*)alloc(EL * 2);
  __hip_bfloat16* xkh = (__hip_bfloat16*)alloc(EL * 2);
  __hip_bfloat16* xkl = (__hip_bfloat16*)alloc(EL * 2);
  __hip_bfloat16* xvh = (__hip_bfloat16*)alloc(EL * 2);
  __hip_bfloat16* xvl = (__hip_bfloat16*)alloc(EL * 2);
  __hip_bfloat16* Wrh = (__hip_bfloat16*)alloc((size_t)CC * CC * 2);
  __hip_bfloat16* Wrl = (__hip_bfloat16*)alloc((size_t)CC * CC * 2);
  float* db  = (float*)pool;           // overlays xrh+xrl
  float* awb = db + EL;                // overlays xkh+xkl
  float* bwb = db + 2 * EL;            // overlays xvh+xvl
  float* gvb = db + 3 * EL;            // overlays Wrh+Wrl

  __hip_bfloat16* Wkh = (__hip_bfloat16*)alloc((size_t)CC * CC * 2);
  __hip_bfloat16* Wkl = (__hip_bfloat16*)alloc((size_t)CC * CC * 2);
  float* ybuf = (float*)Wkh;           // overlays Wkh+Wkl (dead after k-GEMM)

  __hip_bfloat16* Wvh = (__hip_bfloat16*)alloc((size_t)CC * CC * 2);
  __hip_bfloat16* Wvl = (__hip_bfloat16*)alloc((size_t)CC * CC * 2);
  __hip_bfloat16* Woh = (__hip_bfloat16*)alloc((size_t)CC * CC * 2);
  __hip_bfloat16* Wol = (__hip_bfloat16*)alloc((size_t)CC * CC * 2);
  __hip_bfloat16* xw  = (__hip_bfloat16*)alloc(EL * 2);
  __hip_bfloat16* xa  = (__hip_bfloat16*)alloc(EL * 2);
  __hip_bfloat16* xg  = (__hip_bfloat16*)alloc(EL * 2);
  __hip_bfloat16* w1t = (__hip_bfloat16*)alloc((size_t)64  * CC * 2);
  __hip_bfloat16* a1t = (__hip_bfloat16*)alloc((size_t)64  * CC * 2);
  __hip_bfloat16* v1t = (__hip_bfloat16*)alloc((size_t)64  * CC * 2);
  __hip_bfloat16* g1t = (__hip_bfloat16*)alloc((size_t)128 * CC * 2);
  float* rb  = (float*)alloc(EL * 4);
  float* kb  = (float*)alloc(EL * 4);  // raw k, then k_final in place
  float* vb  = (float*)alloc(EL * 4);  // raw v, then v_mix in place
  float* h1w = (float*)alloc((size_t)BT * 64  * 4);
  float* h1a = (float*)alloc((size_t)BT * 64  * 4);
  float* h1v = (float*)alloc((size_t)BT * 64  * 4);
  float* h1g = (float*)alloc((size_t)BT * 128 * 4);
  __hip_bfloat16* xoh = (__hip_bfloat16*)alloc(EL * 2);
  __hip_bfloat16* xol = (__hip_bfloat16*)alloc(EL * 2);
  float* bonb = (float*)alloc((size_t)BT * HH * 4);   // per-(token,head) bonus
  // total ~204.5 MiB (fits: 220 MiB known-OK, 268 MiB crashed)

  k_prepx<<<16384, 256, 0, stream>>>(hid, shift, xrc, xwc, xkc, xvc, xac, xgc,
                                     xrh, xrl, xw, xkh, xkl, xvh, xvl, xa, xg);
  k_cvt2<<<16384, 256, 0, stream>>>(Wr, Wrh, Wrl);
  k_cvt2<<<16384, 256, 0, stream>>>(Wk, Wkh, Wkl);
  k_cvt2<<<16384, 256, 0, stream>>>(Wv, Wvh, Wvl);
  k_cvt2<<<16384, 256, 0, stream>>>(Wo, Woh, Wol);
  k_tr<<<512, 256, 0, stream>>>(w1, w1t, 64);
  k_tr<<<512, 256, 0, stream>>>(a1, a1t, 64);
  k_tr<<<512, 256, 0, stream>>>(v1, v1t, 32);
  k_tr<<<1024, 256, 0, stream>>>(g1, g1t, 128);

  k_gemm_bt3<<<dim3(16, 32), 256, 0, stream>>>(xrh, xrl, Wrh, Wrl, rb, BT, CC, CC);
  k_gemm_bt3<<<dim3(16, 32), 256, 0, stream>>>(xkh, xkl, Wkh, Wkl, kb, BT, CC, CC);
  k_gemm_bt3<<<dim3(16, 32), 256, 0, stream>>>(xvh, xvl, Wvh, Wvl, vb, BT, CC, CC);
  k_gemm_bt<<<dim3(16, 1),  256, 0, stream>>>(xw,  w1t, h1w, BT, 64, CC);
  k_gemm_bt<<<dim3(16, 1),  256, 0, stream>>>(xa,  a1t, h1a, BT, 64, CC);
  k_gemm_bt<<<dim3(16, 1),  256, 0, stream>>>(xvh, v1t, h1v, BT, 64, CC);
  k_gemm_bt<<<dim3(16, 2),  256, 0, stream>>>(xg,  g1t, h1g, BT, 128, CC);

  k_act<<<1024, 256, 0, stream>>>(h1w, h1g);
  // from here: xrh..xvl / Wrh,Wrl dead (db/awb/bwb/gvb overlay);
  //            Wkh/Wkl dead (ybuf overlay)
  k_prep2<<<dim3(8, 256), 256, 0, stream>>>(h1w, h1a, h1v, h1g, w2, a2, v2, g2,
                                            w0, a0, v0, kkc, kac, kb, vb, vfirst,
                                            rb, rk, db, awb, bwb, gvb, bonb);
  k_scan<<<1024, 64, 0, stream>>>(rb, kb, db, awb, bwb, vb, st0, ybuf);
  k_post<<<16384, 256, 0, stream>>>(ybuf, vb, gvb, bonb, gnw, gnb, xoh, xol);
  k_gemm_bt3<<<dim3(16, 32), 256, 0, stream>>>(xoh, xol, Woh, Wol, out, BT, CC, CC);
}

// Round 5
// 1458.971 us; speedup vs baseline: 1.2696x; 1.1135x over previous
//
#include <hip/hip_runtime.h>
#include <hip/hip_bf16.h>

// Problem constants (RWKV-7 Tmix: B=2, T=1024, C=2048, H=32, N=64)
#define BB 2
#define TT 1024
#define CC 2048
#define HH 32
#define BT 2048          // BB*TT tokens
#define GN_EPS 6.4e-4f   // 1e-5 * 8^2

typedef __attribute__((ext_vector_type(8))) __bf16 bf16x8;
typedef __attribute__((ext_vector_type(4))) float f32x4;

__device__ __forceinline__ float sigf(float x) { return 1.0f / (1.0f + expf(-x)); }

__device__ __forceinline__ void split_bf16(float x, __hip_bfloat16& hi, __hip_bfloat16& lo) {
  __hip_bfloat16 h = __float2bfloat16(x);
  hi = h;
  lo = __float2bfloat16(x - __bfloat162float(h));
}

// Sum over each aligned 16-lane group, pure DPP (no LDS pipe on the chain).
__device__ __forceinline__ float red16(float x) {
  x += __int_as_float(__builtin_amdgcn_update_dpp(
      0, __float_as_int(x), 0xB1 /*quad_perm [1,0,3,2]*/, 0xF, 0xF, true));
  x += __int_as_float(__builtin_amdgcn_update_dpp(
      0, __float_as_int(x), 0x4E /*quad_perm [2,3,0,1]*/, 0xF, 0xF, true));
  x += __int_as_float(__builtin_amdgcn_update_dpp(
      0, __float_as_int(x), 0x141 /*row_half_mirror*/, 0xF, 0xF, true));
  x += __int_as_float(__builtin_amdgcn_update_dpp(
      0, __float_as_int(x), 0x140 /*row_mirror*/, 0xF, 0xF, true));
  return x;
}

// ---------------------------------------------------------------------------
// K1: token shift + six lerped projections. r/k/v hi+lo split; w/a/g bf16.
// ---------------------------------------------------------------------------
__global__ __launch_bounds__(256) void k_prepx(
    const float* __restrict__ hid, const float* __restrict__ shift,
    const float* __restrict__ xrc, const float* __restrict__ xwc,
    const float* __restrict__ xkc, const float* __restrict__ xvc,
    const float* __restrict__ xac, const float* __restrict__ xgc,
    __hip_bfloat16* __restrict__ xrh, __hip_bfloat16* __restrict__ xrl,
    __hip_bfloat16* __restrict__ xw,
    __hip_bfloat16* __restrict__ xkh, __hip_bfloat16* __restrict__ xkl,
    __hip_bfloat16* __restrict__ xvh, __hip_bfloat16* __restrict__ xvl,
    __hip_bfloat16* __restrict__ xa, __hip_bfloat16* __restrict__ xg) {
  int idx = blockIdx.x * 256 + threadIdx.x;   // < BT*CC
  int c  = idx & (CC - 1);
  int bt = idx >> 11;
  int t  = bt & (TT - 1);
  int b  = bt >> 10;
  float hcur  = hid[idx];
  float hprev = (t == 0) ? shift[b * CC + c] : hid[idx - CC];
  float xx = hprev - hcur;
  split_bf16(fmaf(xx, xrc[c], hcur), xrh[idx], xrl[idx]);
  split_bf16(fmaf(xx, xkc[c], hcur), xkh[idx], xkl[idx]);
  split_bf16(fmaf(xx, xvc[c], hcur), xvh[idx], xvl[idx]);
  xw[idx] = __float2bfloat16(fmaf(xx, xwc[c], hcur));
  xa[idx] = __float2bfloat16(fmaf(xx, xac[c], hcur));
  xg[idx] = __float2bfloat16(fmaf(xx, xgc[c], hcur));
}

// ---------------------------------------------------------------------------
// K2: f32 -> hi+lo bf16 split (for Wr/Wk/Wv/Wo)
// ---------------------------------------------------------------------------
__global__ __launch_bounds__(256) void k_cvt2(const float* __restrict__ in,
                                              __hip_bfloat16* __restrict__ oh,
                                              __hip_bfloat16* __restrict__ ol) {
  int i = blockIdx.x * 256 + threadIdx.x;
  split_bf16(in[i], oh[i], ol[i]);
}

// ---------------------------------------------------------------------------
// K3: transpose-convert small LoRA "up" weights: in [2048][N0] f32 ->
//     out [NP][2048] bf16 (rows >= N0 zero-padded).  (stage-1 B operands)
// ---------------------------------------------------------------------------
__global__ __launch_bounds__(256) void k_tr(const float* __restrict__ in,
                                            __hip_bfloat16* __restrict__ out,
                                            int N0) {
  int i = blockIdx.x * 256 + threadIdx.x;   // over NP*2048, grid exact
  int n = i >> 11;
  int k = i & 2047;
  float v = (n < N0) ? in[k * N0 + n] : 0.0f;
  out[i] = __float2bfloat16(v);
}

// ---------------------------------------------------------------------------
// K3b: transpose + hi/lo split of stage-2 "down" weights:
//   in [N0][CC] f32 -> out [CC][K0] bf16 hi+lo (K0 = 1<<lgK, rows>=N0 zero).
// ---------------------------------------------------------------------------
__global__ __launch_bounds__(256) void k_trs(const float* __restrict__ in,
                                             __hip_bfloat16* __restrict__ oh,
                                             __hip_bfloat16* __restrict__ ol,
                                             int N0, int lgK) {
  int i = blockIdx.x * 256 + threadIdx.x;   // over CC*K0, grid exact
  int n = i >> lgK;
  int k = i & ((1 << lgK) - 1);
  float v = (k < N0) ? in[k * CC + n] : 0.0f;
  split_bf16(v, oh[i], ol[i]);
}

// ---------------------------------------------------------------------------
// K4: plain bf16 MFMA GEMM, C[M,N] f32 = A[M,K] @ B[N,K]^T  (stage-1 LoRA)
// ---------------------------------------------------------------------------
__global__ __launch_bounds__(256) void k_gemm_bt(
    const __hip_bfloat16* __restrict__ A, const __hip_bfloat16* __restrict__ Bm,
    float* __restrict__ Cm, int M, int Nn, int K) {
  int tid  = threadIdx.x;
  int lane = tid & 63;
  int wv   = tid >> 6;
  int l15  = lane & 15;
  int quad = lane >> 4;
  int m0 = blockIdx.x * 128 + wv * 32;
  int n0 = blockIdx.y * 64;
  const __hip_bfloat16* ap0 = A + (m0 + l15) * K + quad * 8;
  const __hip_bfloat16* ap1 = ap0 + 16 * K;
  const __hip_bfloat16* bp  = Bm + (n0 + l15) * K + quad * 8;
  f32x4 z = {0.f, 0.f, 0.f, 0.f};
  f32x4 c00 = z, c01 = z, c02 = z, c03 = z;
  f32x4 c10 = z, c11 = z, c12 = z, c13 = z;
  for (int k0 = 0; k0 < K; k0 += 32) {
    bf16x8 a0v = *(const bf16x8*)(ap0 + k0);
    bf16x8 a1v = *(const bf16x8*)(ap1 + k0);
    bf16x8 b0v = *(const bf16x8*)(bp + k0);
    bf16x8 b1v = *(const bf16x8*)(bp + 16 * K + k0);
    bf16x8 b2v = *(const bf16x8*)(bp + 32 * K + k0);
    bf16x8 b3v = *(const bf16x8*)(bp + 48 * K + k0);
    c00 = __builtin_amdgcn_mfma_f32_16x16x32_bf16(a0v, b0v, c00, 0, 0, 0);
    c01 = __builtin_amdgcn_mfma_f32_16x16x32_bf16(a0v, b1v, c01, 0, 0, 0);
    c02 = __builtin_amdgcn_mfma_f32_16x16x32_bf16(a0v, b2v, c02, 0, 0, 0);
    c03 = __builtin_amdgcn_mfma_f32_16x16x32_bf16(a0v, b3v, c03, 0, 0, 0);
    c10 = __builtin_amdgcn_mfma_f32_16x16x32_bf16(a1v, b0v, c10, 0, 0, 0);
    c11 = __builtin_amdgcn_mfma_f32_16x16x32_bf16(a1v, b1v, c11, 0, 0, 0);
    c12 = __builtin_amdgcn_mfma_f32_16x16x32_bf16(a1v, b2v, c12, 0, 0, 0);
    c13 = __builtin_amdgcn_mfma_f32_16x16x32_bf16(a1v, b3v, c13, 0, 0, 0);
  }
  int colb = n0 + l15;
  int row0 = m0 + quad * 4;
#pragma unroll
  for (int r = 0; r < 4; ++r) {
    Cm[(row0 + r) * Nn + colb +  0] = c00[r];
    Cm[(row0 + r) * Nn + colb + 16] = c01[r];
    Cm[(row0 + r) * Nn + colb + 32] = c02[r];
    Cm[(row0 + r) * Nn + colb + 48] = c03[r];
    Cm[(row0 + 16 + r) * Nn + colb +  0] = c10[r];
    Cm[(row0 + 16 + r) * Nn + colb + 16] = c11[r];
    Cm[(row0 + 16 + r) * Nn + colb + 32] = c12[r];
    Cm[(row0 + 16 + r) * Nn + colb + 48] = c13[r];
  }
}

// ---------------------------------------------------------------------------
// K4b: split-precision GEMM: C = (Ah+Al)@(Bh+Bl)^T ~= Ah Bh + Ah Bl + Al Bh.
// ---------------------------------------------------------------------------
__global__ __launch_bounds__(256) void k_gemm_bt3(
    const __hip_bfloat16* __restrict__ Ah, const __hip_bfloat16* __restrict__ Al,
    const __hip_bfloat16* __restrict__ Bh, const __hip_bfloat16* __restrict__ Bl,
    float* __restrict__ Cm, int M, int Nn, int K) {
  int tid  = threadIdx.x;
  int lane = tid & 63;
  int wv   = tid >> 6;
  int l15  = lane & 15;
  int quad = lane >> 4;
  int m0 = blockIdx.x * 128 + wv * 32;
  int n0 = blockIdx.y * 64;
  size_t aoff0 = (size_t)(m0 + l15) * K + quad * 8;
  size_t aoff1 = aoff0 + (size_t)16 * K;
  size_t boff  = (size_t)(n0 + l15) * K + quad * 8;
  f32x4 z = {0.f, 0.f, 0.f, 0.f};
  f32x4 c00 = z, c01 = z, c02 = z, c03 = z;
  f32x4 c10 = z, c11 = z, c12 = z, c13 = z;
  for (int k0 = 0; k0 < K; k0 += 32) {
    bf16x8 a0h = *(const bf16x8*)(Ah + aoff0 + k0);
    bf16x8 a1h = *(const bf16x8*)(Ah + aoff1 + k0);
    bf16x8 a0l = *(const bf16x8*)(Al + aoff0 + k0);
    bf16x8 a1l = *(const bf16x8*)(Al + aoff1 + k0);
    bf16x8 bh0 = *(const bf16x8*)(Bh + boff + k0);
    bf16x8 bh1 = *(const bf16x8*)(Bh + boff + (size_t)16 * K + k0);
    bf16x8 bh2 = *(const bf16x8*)(Bh + boff + (size_t)32 * K + k0);
    bf16x8 bh3 = *(const bf16x8*)(Bh + boff + (size_t)48 * K + k0);
    bf16x8 bl0 = *(const bf16x8*)(Bl + boff + k0);
    bf16x8 bl1 = *(const bf16x8*)(Bl + boff + (size_t)16 * K + k0);
    bf16x8 bl2 = *(const bf16x8*)(Bl + boff + (size_t)32 * K + k0);
    bf16x8 bl3 = *(const bf16x8*)(Bl + boff + (size_t)48 * K + k0);
    c00 = __builtin_amdgcn_mfma_f32_16x16x32_bf16(a0h, bh0, c00, 0, 0, 0);
    c01 = __builtin_amdgcn_mfma_f32_16x16x32_bf16(a0h, bh1, c01, 0, 0, 0);
    c02 = __builtin_amdgcn_mfma_f32_16x16x32_bf16(a0h, bh2, c02, 0, 0, 0);
    c03 = __builtin_amdgcn_mfma_f32_16x16x32_bf16(a0h, bh3, c03, 0, 0, 0);
    c10 = __builtin_amdgcn_mfma_f32_16x16x32_bf16(a1h, bh0, c10, 0, 0, 0);
    c11 = __builtin_amdgcn_mfma_f32_16x16x32_bf16(a1h, bh1, c11, 0, 0, 0);
    c12 = __builtin_amdgcn_mfma_f32_16x16x32_bf16(a1h, bh2, c12, 0, 0, 0);
    c13 = __builtin_amdgcn_mfma_f32_16x16x32_bf16(a1h, bh3, c13, 0, 0, 0);
    c00 = __builtin_amdgcn_mfma_f32_16x16x32_bf16(a0h, bl0, c00, 0, 0, 0);
    c01 = __builtin_amdgcn_mfma_f32_16x16x32_bf16(a0h, bl1, c01, 0, 0, 0);
    c02 = __builtin_amdgcn_mfma_f32_16x16x32_bf16(a0h, bl2, c02, 0, 0, 0);
    c03 = __builtin_amdgcn_mfma_f32_16x16x32_bf16(a0h, bl3, c03, 0, 0, 0);
    c10 = __builtin_amdgcn_mfma_f32_16x16x32_bf16(a1h, bl0, c10, 0, 0, 0);
    c11 = __builtin_amdgcn_mfma_f32_16x16x32_bf16(a1h, bl1, c11, 0, 0, 0);
    c12 = __builtin_amdgcn_mfma_f32_16x16x32_bf16(a1h, bl2, c12, 0, 0, 0);
    c13 = __builtin_amdgcn_mfma_f32_16x16x32_bf16(a1h, bl3, c13, 0, 0, 0);
    c00 = __builtin_amdgcn_mfma_f32_16x16x32_bf16(a0l, bh0, c00, 0, 0, 0);
    c01 = __builtin_amdgcn_mfma_f32_16x16x32_bf16(a0l, bh1, c01, 0, 0, 0);
    c02 = __builtin_amdgcn_mfma_f32_16x16x32_bf16(a0l, bh2, c02, 0, 0, 0);
    c03 = __builtin_amdgcn_mfma_f32_16x16x32_bf16(a0l, bh3, c03, 0, 0, 0);
    c10 = __builtin_amdgcn_mfma_f32_16x16x32_bf16(a1l, bh0, c10, 0, 0, 0);
    c11 = __builtin_amdgcn_mfma_f32_16x16x32_bf16(a1l, bh1, c11, 0, 0, 0);
    c12 = __builtin_amdgcn_mfma_f32_16x16x32_bf16(a1l, bh2, c12, 0, 0, 0);
    c13 = __builtin_amdgcn_mfma_f32_16x16x32_bf16(a1l, bh3, c13, 0, 0, 0);
  }
  int colb = n0 + l15;
  int row0 = m0 + quad * 4;
#pragma unroll
  for (int r = 0; r < 4; ++r) {
    Cm[(row0 + r) * Nn + colb +  0] = c00[r];
    Cm[(row0 + r) * Nn + colb + 16] = c01[r];
    Cm[(row0 + r) * Nn + colb + 32] = c02[r];
    Cm[(row0 + r) * Nn + colb + 48] = c03[r];
    Cm[(row0 + 16 + r) * Nn + colb +  0] = c10[r];
    Cm[(row0 + 16 + r) * Nn + colb + 16] = c11[r];
    Cm[(row0 + 16 + r) * Nn + colb + 32] = c12[r];
    Cm[(row0 + 16 + r) * Nn + colb + 48] = c13[r];
  }
}

// ---------------------------------------------------------------------------
// K5: activations + hi/lo split of stage-1 LoRA outputs (MFMA stage-2 prep).
// h1w -> tanh -> split; h1a raw split; h1v raw split (cols 32..63 are zero
// from the padded stage-1 B); h1g -> sigmoid -> split.
// ---------------------------------------------------------------------------
__global__ __launch_bounds__(256) void k_act2(
    const float* __restrict__ h1w, const float* __restrict__ h1a,
    const float* __restrict__ h1v, const float* __restrict__ h1g,
    __hip_bfloat16* __restrict__ wh, __hip_bfloat16* __restrict__ wl,
    __hip_bfloat16* __restrict__ ah, __hip_bfloat16* __restrict__ al,
    __hip_bfloat16* __restrict__ vh, __hip_bfloat16* __restrict__ vl,
    __hip_bfloat16* __restrict__ gh, __hip_bfloat16* __restrict__ gl) {
  int i = blockIdx.x * 256 + threadIdx.x;   // grid covers BT*128 exactly
  if (i < BT * 64) {
    split_bf16(tanhf(h1w[i]), wh[i], wl[i]);
    split_bf16(h1a[i], ah[i], al[i]);
    split_bf16(h1v[i], vh[i], vl[i]);
  }
  split_bf16(sigf(h1g[i]), gh[i], gl[i]);
}

// ---------------------------------------------------------------------------
// K6: elementwise gates + kk-normalize + per-head bonus (ROUND-12: the old
// fused k_prep2 did the stage-2 dots as a serial 288-iter VALU loop —
// latency-bound at 284µs (VALUBusy 17%, 18x off FMA floor). Stage-2 dots
// now run on MFMA (split-precision, f32-class accuracy); this kernel is the
// remaining memory-bound elementwise pass. wave == one (token, head).
// g needs no gating here: k_post reads the stage-2 g output (h2g) directly.
// ---------------------------------------------------------------------------
__global__ __launch_bounds__(256) void k_gate(
    const float* __restrict__ h2w, const float* __restrict__ h2a,
    const float* __restrict__ h2v,
    const float* __restrict__ w0, const float* __restrict__ a0,
    const float* __restrict__ v0, const float* __restrict__ kkc,
    const float* __restrict__ kac, float* __restrict__ kbuf,
    float* __restrict__ vbuf, const float* __restrict__ vfirst,
    const float* __restrict__ rbuf, const float* __restrict__ rk,
    float* __restrict__ dec, float* __restrict__ aw,
    float* __restrict__ bw, float* __restrict__ bonb) {
  int idx = blockIdx.x * 256 + threadIdx.x;   // < BT*CC
  int c = idx & (CC - 1);
  float kv = kbuf[idx], vv = vbuf[idx], vf = vfirst[idx];
  float d_ = 0.60653065971f * sigf(w0[c] + h2w[idx]);   // sigmoid * e^-0.5
  float as = sigf(a0[c] + h2a[idx]);
  float vs = sigf(v0[c] + h2v[idx]);
  float vm = vv + (vf - vv) * vs;
  float kfv = kv * (1.0f + kac[c] * (as - 1.0f));
  float kku = kv * kkc[c];
  float s = kku * kku;     // per-head L2 over 64 lanes (wave == head)
  s += __shfl_xor(s, 1);  s += __shfl_xor(s, 2);  s += __shfl_xor(s, 4);
  s += __shfl_xor(s, 8);  s += __shfl_xor(s, 16); s += __shfl_xor(s, 32);
  float nrm = fmaxf(sqrtf(s), 1e-12f);
  float kkn = kku / nrm;
  float bon = rbuf[idx] * kfv * rk[c];
  bon += __shfl_xor(bon, 1);  bon += __shfl_xor(bon, 2);
  bon += __shfl_xor(bon, 4);  bon += __shfl_xor(bon, 8);
  bon += __shfl_xor(bon, 16); bon += __shfl_xor(bon, 32);
  if ((threadIdx.x & 63) == 0) bonb[(idx >> 11) * HH + (c >> 6)] = bon;
  dec[idx] = d_;
  aw[idx]  = -kkn; bw[idx] = kkn * as;
  kbuf[idx] = kfv; vbuf[idx] = vm;
}

// ---------------------------------------------------------------------------
// K7: WKV7 scan (round-11 winning version, unchanged).
// __launch_bounds__(64,1) unlocks the VGPR budget so the 8-deep C++ ring
// materializes; red16 = 4 pure-DPP ops; XCD-clustered heads for L2 locality.
// ---------------------------------------------------------------------------
__global__ __launch_bounds__(64, 1) void k_scan(
    const float* __restrict__ rbuf, const float* __restrict__ kf,
    const float* __restrict__ dec, const float* __restrict__ aw,
    const float* __restrict__ bw, const float* __restrict__ vbuf,
    const float* __restrict__ st0, float* __restrict__ ybuf) {
  int blk = blockIdx.x;                     // 0..1023
  int xcd = blk & 7;
  int q   = blk >> 3;                       // 0..127
  int bh  = xcd * 8 + (q & 7);              // all 16 rg-waves of a head share blk%8
  int rg  = q >> 3;                         // 0..15
  int b = bh >> 5, h = bh & 31;
  int lane = threadIdx.x;
  int row  = rg * 4 + (lane >> 4);
  int c0   = (lane & 15) * 4;
  size_t tokbase = (size_t)b * TT * CC + h * 64;

  float4 S = *(const float4*)(st0 + ((size_t)bh * 64 + row) * 64 + c0);

  bool writer = ((lane & 15) == 0);
  float* yout = ybuf + tokbase + row;

  const float* pr = rbuf + tokbase + c0;
  const float* pk = kf   + tokbase + c0;
  const float* pd = dec  + tokbase + c0;
  const float* pa = aw   + tokbase + c0;
  const float* pb = bw   + tokbase + c0;
  const float* pv = vbuf + tokbase + row;

  float4 Rr[8], Rk[8], Rd[8], Ra[8], Rb[8];
  float  Rv[8];

#define LOADT(SL, T)                                                         \
  { size_t oo = (size_t)(T) * CC;                                            \
    Rr[SL] = *(const float4*)(pr + oo);                                      \
    Rk[SL] = *(const float4*)(pk + oo);                                      \
    Rd[SL] = *(const float4*)(pd + oo);                                      \
    Ra[SL] = *(const float4*)(pa + oo);                                      \
    Rb[SL] = *(const float4*)(pb + oo);                                      \
    Rv[SL] = pv[oo]; }

#define STEP(SL, T)                                                          \
  { float sa = fmaf(S.w, Ra[SL].w, fmaf(S.z, Ra[SL].z,                       \
               fmaf(S.y, Ra[SL].y, S.x * Ra[SL].x)));                        \
    sa = red16(sa);                                                          \
    float vv = Rv[SL];                                                       \
    S.x = fmaf(S.x, Rd[SL].x, fmaf(sa, Rb[SL].x, vv * Rk[SL].x));            \
    S.y = fmaf(S.y, Rd[SL].y, fmaf(sa, Rb[SL].y, vv * Rk[SL].y));            \
    S.z = fmaf(S.z, Rd[SL].z, fmaf(sa, Rb[SL].z, vv * Rk[SL].z));            \
    S.w = fmaf(S.w, Rd[SL].w, fmaf(sa, Rb[SL].w, vv * Rk[SL].w));            \
    float y = fmaf(S.w, Rr[SL].w, fmaf(S.z, Rr[SL].z,                        \
              fmaf(S.y, Rr[SL].y, S.x * Rr[SL].x)));                         \
    y = red16(y);                                                            \
    if (writer) yout[(size_t)(T) * CC] = y; }

#pragma unroll
  for (int s = 0; s < 8; ++s) LOADT(s, s)
  for (int t = 0; t < TT; t += 8) {
#pragma unroll
    for (int s = 0; s < 8; ++s) {
      STEP(s, t + s)
      if (t + 8 + s < TT) LOADT(s, t + 8 + s)
      asm volatile("" ::: "memory");   // pin: reload issues here, 8 steps early
    }
  }
#undef LOADT
#undef STEP
}

// ---------------------------------------------------------------------------
// K8: post-scan epilogue: GroupNorm + bonus + g-gate, fully parallel.
// gvb = stage-2 g GEMM output (raw gacc, same values as before).
// ---------------------------------------------------------------------------
__global__ __launch_bounds__(256) void k_post(
    const float* __restrict__ ybuf, const float* __restrict__ vb,
    const float* __restrict__ gvb, const float* __restrict__ bonb,
    const float* __restrict__ gnw, const float* __restrict__ gnb,
    __hip_bfloat16* __restrict__ xoh, __hip_bfloat16* __restrict__ xol) {
  int tid = threadIdx.x, wv = tid >> 6, lane = tid & 63;
  int id = blockIdx.x * 4 + wv;        // 0..BT*HH-1
  int bt = id >> 5, h = id & 31;
  size_t base = (size_t)bt * CC + h * 64 + lane;
  float y = ybuf[base];
  float s1 = y, s2 = y * y;
#pragma unroll
  for (int off = 1; off < 64; off <<= 1) {
    s1 += __shfl_xor(s1, off);
    s2 += __shfl_xor(s2, off);
  }
  float mean = s1 * (1.0f / 64.0f);
  float var  = s2 * (1.0f / 64.0f) - mean * mean;
  float inv  = rsqrtf(var + GN_EPS);
  float x = fmaf((y - mean) * inv, gnw[h * 64 + lane], gnb[h * 64 + lane])
          + bonb[bt * HH + h] * vb[base];
  split_bf16(x * gvb[base], xoh[base], xol[base]);
}

// ---------------------------------------------------------------------------
extern "C" void kernel_launch(void* const* d_in, const int* in_sizes, int n_in,
                              void* d_out, int out_size, void* d_ws, size_t ws_size,
                              hipStream_t stream) {
  (void)in_sizes; (void)n_in; (void)out_size; (void)ws_size;
  const float* hid    = (const float*)d_in[0];
  const float* shift  = (const float*)d_in[1];
  const float* st0    = (const float*)d_in[2];
  const float* vfirst = (const float*)d_in[3];
  const float* xrc = (const float*)d_in[4];
  const float* xwc = (const float*)d_in[5];
  const float* xkc = (const float*)d_in[6];
  const float* xvc = (const float*)d_in[7];
  const float* xac = (const float*)d_in[8];
  const float* xgc = (const float*)d_in[9];
  const float* w0  = (const float*)d_in[10];
  const float* w1  = (const float*)d_in[11];
  const float* w2  = (const float*)d_in[12];
  const float* a0  = (const float*)d_in[13];
  const float* a1  = (const float*)d_in[14];
  const float* a2  = (const float*)d_in[15];
  const float* v0  = (const float*)d_in[16];
  const float* v1  = (const float*)d_in[17];
  const float* v2  = (const float*)d_in[18];
  const float* g1  = (const float*)d_in[19];
  const float* g2  = (const float*)d_in[20];
  const float* kkc = (const float*)d_in[21];
  const float* kac = (const float*)d_in[22];
  const float* rk  = (const float*)d_in[23];
  const float* Wr  = (const float*)d_in[24];
  const float* Wk  = (const float*)d_in[25];
  const float* Wv  = (const float*)d_in[26];
  const float* Wo  = (const float*)d_in[27];
  const float* gnw = (const float*)d_in[28];
  const float* gnb = (const float*)d_in[29];
  float* out = (float*)d_out;

  char* p = (char*)d_ws;
  auto alloc = [&](size_t n) { char* q = p; p += (n + 255) & ~(size_t)255; return q; };
  const size_t EL = (size_t)BT * CC;

  // --- alias pool: xrh..xvl + Wrh,Wrl dead by k_gate time; db/awb/bwb +
  //     h2g (the old gvb slot) overlay them.
  char* pool = p;
  __hip_bfloat16* xrh = (__hip_bfloat16*)alloc(EL * 2);
  __hip_bfloat16* xrl = (__hip_bfloat16*)alloc(EL * 2);
  __hip_bfloat16* xkh = (__hip_bfloat16*)alloc(EL * 2);
  __hip_bfloat16* xkl = (__hip_bfloat16*)alloc(EL * 2);
  __hip_bfloat16* xvh = (__hip_bfloat16*)alloc(EL * 2);
  __hip_bfloat16* xvl = (__hip_bfloat16*)alloc(EL * 2);
  __hip_bfloat16* Wrh = (__hip_bfloat16*)alloc((size_t)CC * CC * 2);
  __hip_bfloat16* Wrl = (__hip_bfloat16*)alloc((size_t)CC * CC * 2);
  float* db  = (float*)pool;           // overlays xrh+xrl
  float* awb = db + EL;                // overlays xkh+xkl
  float* bwb = db + 2 * EL;            // overlays xvh+xvl
  float* h2g = db + 3 * EL;            // overlays Wrh+Wrl (old gvb slot)

  __hip_bfloat16* Wkh = (__hip_bfloat16*)alloc((size_t)CC * CC * 2);
  __hip_bfloat16* Wkl = (__hip_bfloat16*)alloc((size_t)CC * CC * 2);
  float* ybuf = (float*)Wkh;           // overlays Wkh+Wkl (dead after k-GEMM)
  float* h2v  = (float*)Wkh;           // same region, read by k_gate BEFORE scan writes ybuf

  __hip_bfloat16* Wvh = (__hip_bfloat16*)alloc((size_t)CC * CC * 2);
  __hip_bfloat16* Wvl = (__hip_bfloat16*)alloc((size_t)CC * CC * 2);
  __hip_bfloat16* Woh = (__hip_bfloat16*)alloc((size_t)CC * CC * 2);
  __hip_bfloat16* Wol = (__hip_bfloat16*)alloc((size_t)CC * CC * 2);
  __hip_bfloat16* xw  = (__hip_bfloat16*)alloc(EL * 2);
  __hip_bfloat16* xa  = (__hip_bfloat16*)alloc(EL * 2);
  __hip_bfloat16* xg  = (__hip_bfloat16*)alloc(EL * 2);
  float* h2w = (float*)xw;             // overlays xw+xa (dead after stage-1 GEMMs)
  __hip_bfloat16* w1t = (__hip_bfloat16*)alloc((size_t)64  * CC * 2);
  __hip_bfloat16* a1t = (__hip_bfloat16*)alloc((size_t)64  * CC * 2);
  __hip_bfloat16* v1t = (__hip_bfloat16*)alloc((size_t)64  * CC * 2);
  __hip_bfloat16* g1t = (__hip_bfloat16*)alloc((size_t)128 * CC * 2);
  float* rb  = (float*)alloc(EL * 4);
  float* kb  = (float*)alloc(EL * 4);  // raw k, then k_final in place
  float* vb  = (float*)alloc(EL * 4);  // raw v, then v_mix in place
  float* h1w = (float*)alloc((size_t)BT * 64  * 4);
  float* h1a = (float*)alloc((size_t)BT * 64  * 4);
  float* h1v = (float*)alloc((size_t)BT * 64  * 4);
  float* h1g = (float*)alloc((size_t)BT * 128 * 4);
  __hip_bfloat16* xoh = (__hip_bfloat16*)alloc(EL * 2);
  __hip_bfloat16* xol = (__hip_bfloat16*)alloc(EL * 2);
  float* h2a = (float*)xoh;            // overlays xoh+xol (k_post writes them AFTER k_gate)
  float* bonb = (float*)alloc((size_t)BT * HH * 4);   // per-(token,head) bonus
  // stage-2 split operands (small, fresh):
  __hip_bfloat16* h1wh = (__hip_bfloat16*)alloc((size_t)BT * 64 * 2);
  __hip_bfloat16* h1wl = (__hip_bfloat16*)alloc((size_t)BT * 64 * 2);
  __hip_bfloat16* h1ah = (__hip_bfloat16*)alloc((size_t)BT * 64 * 2);
  __hip_bfloat16* h1al = (__hip_bfloat16*)alloc((size_t)BT * 64 * 2);
  __hip_bfloat16* h1vh = (__hip_bfloat16*)alloc((size_t)BT * 64 * 2);
  __hip_bfloat16* h1vl = (__hip_bfloat16*)alloc((size_t)BT * 64 * 2);
  __hip_bfloat16* h1gh = (__hip_bfloat16*)alloc((size_t)BT * 128 * 2);
  __hip_bfloat16* h1gl = (__hip_bfloat16*)alloc((size_t)BT * 128 * 2);
  __hip_bfloat16* w2th = (__hip_bfloat16*)alloc((size_t)CC * 64 * 2);
  __hip_bfloat16* w2tl = (__hip_bfloat16*)alloc((size_t)CC * 64 * 2);
  __hip_bfloat16* a2th = (__hip_bfloat16*)alloc((size_t)CC * 64 * 2);
  __hip_bfloat16* a2tl = (__hip_bfloat16*)alloc((size_t)CC * 64 * 2);
  __hip_bfloat16* v2th = (__hip_bfloat16*)alloc((size_t)CC * 64 * 2);
  __hip_bfloat16* v2tl = (__hip_bfloat16*)alloc((size_t)CC * 64 * 2);
  __hip_bfloat16* g2th = (__hip_bfloat16*)alloc((size_t)CC * 128 * 2);
  __hip_bfloat16* g2tl = (__hip_bfloat16*)alloc((size_t)CC * 128 * 2);
  // total ~210 MiB (known-OK envelope: 220 OK, 268 crashed)

  k_prepx<<<16384, 256, 0, stream>>>(hid, shift, xrc, xwc, xkc, xvc, xac, xgc,
                                     xrh, xrl, xw, xkh, xkl, xvh, xvl, xa, xg);
  k_cvt2<<<16384, 256, 0, stream>>>(Wr, Wrh, Wrl);
  k_cvt2<<<16384, 256, 0, stream>>>(Wk, Wkh, Wkl);
  k_cvt2<<<16384, 256, 0, stream>>>(Wv, Wvh, Wvl);
  k_cvt2<<<16384, 256, 0, stream>>>(Wo, Woh, Wol);
  k_tr<<<512, 256, 0, stream>>>(w1, w1t, 64);
  k_tr<<<512, 256, 0, stream>>>(a1, a1t, 64);
  k_tr<<<512, 256, 0, stream>>>(v1, v1t, 32);
  k_tr<<<1024, 256, 0, stream>>>(g1, g1t, 128);
  k_trs<<<512, 256, 0, stream>>>(w2, w2th, w2tl, 64, 6);
  k_trs<<<512, 256, 0, stream>>>(a2, a2th, a2tl, 64, 6);
  k_trs<<<512, 256, 0, stream>>>(v2, v2th, v2tl, 32, 6);   // padded K=64
  k_trs<<<1024, 256, 0, stream>>>(g2, g2th, g2tl, 128, 7);

  k_gemm_bt3<<<dim3(16, 32), 256, 0, stream>>>(xrh, xrl, Wrh, Wrl, rb, BT, CC, CC);
  k_gemm_bt3<<<dim3(16, 32), 256, 0, stream>>>(xkh, xkl, Wkh, Wkl, kb, BT, CC, CC);
  k_gemm_bt3<<<dim3(16, 32), 256, 0, stream>>>(xvh, xvl, Wvh, Wvl, vb, BT, CC, CC);
  k_gemm_bt<<<dim3(16, 1),  256, 0, stream>>>(xw,  w1t, h1w, BT, 64, CC);
  k_gemm_bt<<<dim3(16, 1),  256, 0, stream>>>(xa,  a1t, h1a, BT, 64, CC);
  k_gemm_bt<<<dim3(16, 1),  256, 0, stream>>>(xvh, v1t, h1v, BT, 64, CC);
  k_gemm_bt<<<dim3(16, 2),  256, 0, stream>>>(xg,  g1t, h1g, BT, 128, CC);

  k_act2<<<1024, 256, 0, stream>>>(h1w, h1a, h1v, h1g,
                                   h1wh, h1wl, h1ah, h1al,
                                   h1vh, h1vl, h1gh, h1gl);
  // stage-2 LoRA dots on MFMA (split precision). Overlays now live:
  //   h2w->xw+xa, h2a->xoh+xol, h2v->Wkh+Wkl, h2g->Wrh+Wrl.
  k_gemm_bt3<<<dim3(16, 32), 256, 0, stream>>>(h1wh, h1wl, w2th, w2tl, h2w, BT, CC, 64);
  k_gemm_bt3<<<dim3(16, 32), 256, 0, stream>>>(h1ah, h1al, a2th, a2tl, h2a, BT, CC, 64);
  k_gemm_bt3<<<dim3(16, 32), 256, 0, stream>>>(h1vh, h1vl, v2th, v2tl, h2v, BT, CC, 64);
  k_gemm_bt3<<<dim3(16, 32), 256, 0, stream>>>(h1gh, h1gl, g2th, g2tl, h2g, BT, CC, 128);

  k_gate<<<16384, 256, 0, stream>>>(h2w, h2a, h2v, w0, a0, v0, kkc, kac,
                                    kb, vb, vfirst, rb, rk, db, awb, bwb, bonb);
  k_scan<<<1024, 64, 0, stream>>>(rb, kb, db, awb, bwb, vb, st0, ybuf);
  k_post<<<16384, 256, 0, stream>>>(ybuf, vb, h2g, bonb, gnw, gnb, xoh, xol);
  k_gemm_bt3<<<dim3(16, 32), 256, 0, stream>>>(xoh, xol, Woh, Wol, out, BT, CC, CC);
}

// Round 6
// 1446.950 us; speedup vs baseline: 1.2801x; 1.0083x over previous
//
#include <hip/hip_runtime.h>
#include <hip/hip_bf16.h>

// Problem constants (RWKV-7 Tmix: B=2, T=1024, C=2048, H=32, N=64)
#define BB 2
#define TT 1024
#define CC 2048
#define HH 32
#define BT 2048          // BB*TT tokens
#define GN_EPS 6.4e-4f   // 1e-5 * 8^2

typedef __attribute__((ext_vector_type(8))) __bf16 bf16x8;
typedef __attribute__((ext_vector_type(4))) float f32x4;

__device__ __forceinline__ float sigf(float x) { return 1.0f / (1.0f + expf(-x)); }

__device__ __forceinline__ void split_bf16(float x, __hip_bfloat16& hi, __hip_bfloat16& lo) {
  __hip_bfloat16 h = __float2bfloat16(x);
  hi = h;
  lo = __float2bfloat16(x - __bfloat162float(h));
}

// Sum over each aligned 16-lane group, pure DPP (no LDS pipe on the chain).
__device__ __forceinline__ float red16(float x) {
  x += __int_as_float(__builtin_amdgcn_update_dpp(
      0, __float_as_int(x), 0xB1 /*quad_perm [1,0,3,2]*/, 0xF, 0xF, true));
  x += __int_as_float(__builtin_amdgcn_update_dpp(
      0, __float_as_int(x), 0x4E /*quad_perm [2,3,0,1]*/, 0xF, 0xF, true));
  x += __int_as_float(__builtin_amdgcn_update_dpp(
      0, __float_as_int(x), 0x141 /*row_half_mirror*/, 0xF, 0xF, true));
  x += __int_as_float(__builtin_amdgcn_update_dpp(
      0, __float_as_int(x), 0x140 /*row_mirror*/, 0xF, 0xF, true));
  return x;
}

// ---------------------------------------------------------------------------
// K1: token shift + six lerped projections. r/k/v hi+lo split; w/a/g bf16.
// ---------------------------------------------------------------------------
__global__ __launch_bounds__(256) void k_prepx(
    const float* __restrict__ hid, const float* __restrict__ shift,
    const float* __restrict__ xrc, const float* __restrict__ xwc,
    const float* __restrict__ xkc, const float* __restrict__ xvc,
    const float* __restrict__ xac, const float* __restrict__ xgc,
    __hip_bfloat16* __restrict__ xrh, __hip_bfloat16* __restrict__ xrl,
    __hip_bfloat16* __restrict__ xw,
    __hip_bfloat16* __restrict__ xkh, __hip_bfloat16* __restrict__ xkl,
    __hip_bfloat16* __restrict__ xvh, __hip_bfloat16* __restrict__ xvl,
    __hip_bfloat16* __restrict__ xa, __hip_bfloat16* __restrict__ xg) {
  int idx = blockIdx.x * 256 + threadIdx.x;   // < BT*CC
  int c  = idx & (CC - 1);
  int bt = idx >> 11;
  int t  = bt & (TT - 1);
  int b  = bt >> 10;
  float hcur  = hid[idx];
  float hprev = (t == 0) ? shift[b * CC + c] : hid[idx - CC];
  float xx = hprev - hcur;
  split_bf16(fmaf(xx, xrc[c], hcur), xrh[idx], xrl[idx]);
  split_bf16(fmaf(xx, xkc[c], hcur), xkh[idx], xkl[idx]);
  split_bf16(fmaf(xx, xvc[c], hcur), xvh[idx], xvl[idx]);
  xw[idx] = __float2bfloat16(fmaf(xx, xwc[c], hcur));
  xa[idx] = __float2bfloat16(fmaf(xx, xac[c], hcur));
  xg[idx] = __float2bfloat16(fmaf(xx, xgc[c], hcur));
}

// ---------------------------------------------------------------------------
// K2: f32 -> hi+lo bf16 split (for Wr/Wk/Wv/Wo)
// ---------------------------------------------------------------------------
__global__ __launch_bounds__(256) void k_cvt2(const float* __restrict__ in,
                                              __hip_bfloat16* __restrict__ oh,
                                              __hip_bfloat16* __restrict__ ol) {
  int i = blockIdx.x * 256 + threadIdx.x;
  split_bf16(in[i], oh[i], ol[i]);
}

// ---------------------------------------------------------------------------
// K3: transpose-convert small LoRA "up" weights: in [2048][N0] f32 ->
//     out [NP][2048] bf16 (rows >= N0 zero-padded).  (stage-1 B operands)
// ---------------------------------------------------------------------------
__global__ __launch_bounds__(256) void k_tr(const float* __restrict__ in,
                                            __hip_bfloat16* __restrict__ out,
                                            int N0) {
  int i = blockIdx.x * 256 + threadIdx.x;   // over NP*2048, grid exact
  int n = i >> 11;
  int k = i & 2047;
  float v = (n < N0) ? in[k * N0 + n] : 0.0f;
  out[i] = __float2bfloat16(v);
}

// ---------------------------------------------------------------------------
// K3b: transpose + hi/lo split of stage-2 "down" weights:
//   in [N0][CC] f32 -> out [CC][K0] bf16 hi+lo (K0 = 1<<lgK, rows>=N0 zero).
// ---------------------------------------------------------------------------
__global__ __launch_bounds__(256) void k_trs(const float* __restrict__ in,
                                             __hip_bfloat16* __restrict__ oh,
                                             __hip_bfloat16* __restrict__ ol,
                                             int N0, int lgK) {
  int i = blockIdx.x * 256 + threadIdx.x;   // over CC*K0, grid exact
  int n = i >> lgK;
  int k = i & ((1 << lgK) - 1);
  float v = (k < N0) ? in[k * CC + n] : 0.0f;
  split_bf16(v, oh[i], ol[i]);
}

// ---------------------------------------------------------------------------
// K4: plain bf16 MFMA GEMM, C[M,N] f32 = A[M,K] @ B[N,K]^T  (stage-1 LoRA)
// ---------------------------------------------------------------------------
__global__ __launch_bounds__(256) void k_gemm_bt(
    const __hip_bfloat16* __restrict__ A, const __hip_bfloat16* __restrict__ Bm,
    float* __restrict__ Cm, int M, int Nn, int K) {
  int tid  = threadIdx.x;
  int lane = tid & 63;
  int wv   = tid >> 6;
  int l15  = lane & 15;
  int quad = lane >> 4;
  int m0 = blockIdx.x * 128 + wv * 32;
  int n0 = blockIdx.y * 64;
  const __hip_bfloat16* ap0 = A + (m0 + l15) * K + quad * 8;
  const __hip_bfloat16* ap1 = ap0 + 16 * K;
  const __hip_bfloat16* bp  = Bm + (n0 + l15) * K + quad * 8;
  f32x4 z = {0.f, 0.f, 0.f, 0.f};
  f32x4 c00 = z, c01 = z, c02 = z, c03 = z;
  f32x4 c10 = z, c11 = z, c12 = z, c13 = z;
  for (int k0 = 0; k0 < K; k0 += 32) {
    bf16x8 a0v = *(const bf16x8*)(ap0 + k0);
    bf16x8 a1v = *(const bf16x8*)(ap1 + k0);
    bf16x8 b0v = *(const bf16x8*)(bp + k0);
    bf16x8 b1v = *(const bf16x8*)(bp + 16 * K + k0);
    bf16x8 b2v = *(const bf16x8*)(bp + 32 * K + k0);
    bf16x8 b3v = *(const bf16x8*)(bp + 48 * K + k0);
    c00 = __builtin_amdgcn_mfma_f32_16x16x32_bf16(a0v, b0v, c00, 0, 0, 0);
    c01 = __builtin_amdgcn_mfma_f32_16x16x32_bf16(a0v, b1v, c01, 0, 0, 0);
    c02 = __builtin_amdgcn_mfma_f32_16x16x32_bf16(a0v, b2v, c02, 0, 0, 0);
    c03 = __builtin_amdgcn_mfma_f32_16x16x32_bf16(a0v, b3v, c03, 0, 0, 0);
    c10 = __builtin_amdgcn_mfma_f32_16x16x32_bf16(a1v, b0v, c10, 0, 0, 0);
    c11 = __builtin_amdgcn_mfma_f32_16x16x32_bf16(a1v, b1v, c11, 0, 0, 0);
    c12 = __builtin_amdgcn_mfma_f32_16x16x32_bf16(a1v, b2v, c12, 0, 0, 0);
    c13 = __builtin_amdgcn_mfma_f32_16x16x32_bf16(a1v, b3v, c13, 0, 0, 0);
  }
  int colb = n0 + l15;
  int row0 = m0 + quad * 4;
#pragma unroll
  for (int r = 0; r < 4; ++r) {
    Cm[(row0 + r) * Nn + colb +  0] = c00[r];
    Cm[(row0 + r) * Nn + colb + 16] = c01[r];
    Cm[(row0 + r) * Nn + colb + 32] = c02[r];
    Cm[(row0 + r) * Nn + colb + 48] = c03[r];
    Cm[(row0 + 16 + r) * Nn + colb +  0] = c10[r];
    Cm[(row0 + 16 + r) * Nn + colb + 16] = c11[r];
    Cm[(row0 + 16 + r) * Nn + colb + 32] = c12[r];
    Cm[(row0 + 16 + r) * Nn + colb + 48] = c13[r];
  }
}

// ---------------------------------------------------------------------------
// K4b: split-precision GEMM: C = (Ah+Al)@(Bh+Bl)^T ~= Ah Bh + Ah Bl + Al Bh.
// ---------------------------------------------------------------------------
__global__ __launch_bounds__(256) void k_gemm_bt3(
    const __hip_bfloat16* __restrict__ Ah, const __hip_bfloat16* __restrict__ Al,
    const __hip_bfloat16* __restrict__ Bh, const __hip_bfloat16* __restrict__ Bl,
    float* __restrict__ Cm, int M, int Nn, int K) {
  int tid  = threadIdx.x;
  int lane = tid & 63;
  int wv   = tid >> 6;
  int l15  = lane & 15;
  int quad = lane >> 4;
  int m0 = blockIdx.x * 128 + wv * 32;
  int n0 = blockIdx.y * 64;
  size_t aoff0 = (size_t)(m0 + l15) * K + quad * 8;
  size_t aoff1 = aoff0 + (size_t)16 * K;
  size_t boff  = (size_t)(n0 + l15) * K + quad * 8;
  f32x4 z = {0.f, 0.f, 0.f, 0.f};
  f32x4 c00 = z, c01 = z, c02 = z, c03 = z;
  f32x4 c10 = z, c11 = z, c12 = z, c13 = z;
  for (int k0 = 0; k0 < K; k0 += 32) {
    bf16x8 a0h = *(const bf16x8*)(Ah + aoff0 + k0);
    bf16x8 a1h = *(const bf16x8*)(Ah + aoff1 + k0);
    bf16x8 a0l = *(const bf16x8*)(Al + aoff0 + k0);
    bf16x8 a1l = *(const bf16x8*)(Al + aoff1 + k0);
    bf16x8 bh0 = *(const bf16x8*)(Bh + boff + k0);
    bf16x8 bh1 = *(const bf16x8*)(Bh + boff + (size_t)16 * K + k0);
    bf16x8 bh2 = *(const bf16x8*)(Bh + boff + (size_t)32 * K + k0);
    bf16x8 bh3 = *(const bf16x8*)(Bh + boff + (size_t)48 * K + k0);
    bf16x8 bl0 = *(const bf16x8*)(Bl + boff + k0);
    bf16x8 bl1 = *(const bf16x8*)(Bl + boff + (size_t)16 * K + k0);
    bf16x8 bl2 = *(const bf16x8*)(Bl + boff + (size_t)32 * K + k0);
    bf16x8 bl3 = *(const bf16x8*)(Bl + boff + (size_t)48 * K + k0);
    c00 = __builtin_amdgcn_mfma_f32_16x16x32_bf16(a0h, bh0, c00, 0, 0, 0);
    c01 = __builtin_amdgcn_mfma_f32_16x16x32_bf16(a0h, bh1, c01, 0, 0, 0);
    c02 = __builtin_amdgcn_mfma_f32_16x16x32_bf16(a0h, bh2, c02, 0, 0, 0);
    c03 = __builtin_amdgcn_mfma_f32_16x16x32_bf16(a0h, bh3, c03, 0, 0, 0);
    c10 = __builtin_amdgcn_mfma_f32_16x16x32_bf16(a1h, bh0, c10, 0, 0, 0);
    c11 = __builtin_amdgcn_mfma_f32_16x16x32_bf16(a1h, bh1, c11, 0, 0, 0);
    c12 = __builtin_amdgcn_mfma_f32_16x16x32_bf16(a1h, bh2, c12, 0, 0, 0);
    c13 = __builtin_amdgcn_mfma_f32_16x16x32_bf16(a1h, bh3, c13, 0, 0, 0);
    c00 = __builtin_amdgcn_mfma_f32_16x16x32_bf16(a0h, bl0, c00, 0, 0, 0);
    c01 = __builtin_amdgcn_mfma_f32_16x16x32_bf16(a0h, bl1, c01, 0, 0, 0);
    c02 = __builtin_amdgcn_mfma_f32_16x16x32_bf16(a0h, bl2, c02, 0, 0, 0);
    c03 = __builtin_amdgcn_mfma_f32_16x16x32_bf16(a0h, bl3, c03, 0, 0, 0);
    c10 = __builtin_amdgcn_mfma_f32_16x16x32_bf16(a1h, bl0, c10, 0, 0, 0);
    c11 = __builtin_amdgcn_mfma_f32_16x16x32_bf16(a1h, bl1, c11, 0, 0, 0);
    c12 = __builtin_amdgcn_mfma_f32_16x16x32_bf16(a1h, bl2, c12, 0, 0, 0);
    c13 = __builtin_amdgcn_mfma_f32_16x16x32_bf16(a1h, bl3, c13, 0, 0, 0);
    c00 = __builtin_amdgcn_mfma_f32_16x16x32_bf16(a0l, bh0, c00, 0, 0, 0);
    c01 = __builtin_amdgcn_mfma_f32_16x16x32_bf16(a0l, bh1, c01, 0, 0, 0);
    c02 = __builtin_amdgcn_mfma_f32_16x16x32_bf16(a0l, bh2, c02, 0, 0, 0);
    c03 = __builtin_amdgcn_mfma_f32_16x16x32_bf16(a0l, bh3, c03, 0, 0, 0);
    c10 = __builtin_amdgcn_mfma_f32_16x16x32_bf16(a1l, bh0, c10, 0, 0, 0);
    c11 = __builtin_amdgcn_mfma_f32_16x16x32_bf16(a1l, bh1, c11, 0, 0, 0);
    c12 = __builtin_amdgcn_mfma_f32_16x16x32_bf16(a1l, bh2, c12, 0, 0, 0);
    c13 = __builtin_amdgcn_mfma_f32_16x16x32_bf16(a1l, bh3, c13, 0, 0, 0);
  }
  int colb = n0 + l15;
  int row0 = m0 + quad * 4;
#pragma unroll
  for (int r = 0; r < 4; ++r) {
    Cm[(row0 + r) * Nn + colb +  0] = c00[r];
    Cm[(row0 + r) * Nn + colb + 16] = c01[r];
    Cm[(row0 + r) * Nn + colb + 32] = c02[r];
    Cm[(row0 + r) * Nn + colb + 48] = c03[r];
    Cm[(row0 + 16 + r) * Nn + colb +  0] = c10[r];
    Cm[(row0 + 16 + r) * Nn + colb + 16] = c11[r];
    Cm[(row0 + 16 + r) * Nn + colb + 32] = c12[r];
    Cm[(row0 + 16 + r) * Nn + colb + 48] = c13[r];
  }
}

// ---------------------------------------------------------------------------
// K5: activations + hi/lo split of stage-1 LoRA outputs (MFMA stage-2 prep).
// ---------------------------------------------------------------------------
__global__ __launch_bounds__(256) void k_act2(
    const float* __restrict__ h1w, const float* __restrict__ h1a,
    const float* __restrict__ h1v, const float* __restrict__ h1g,
    __hip_bfloat16* __restrict__ wh, __hip_bfloat16* __restrict__ wl,
    __hip_bfloat16* __restrict__ ah, __hip_bfloat16* __restrict__ al,
    __hip_bfloat16* __restrict__ vh, __hip_bfloat16* __restrict__ vl,
    __hip_bfloat16* __restrict__ gh, __hip_bfloat16* __restrict__ gl) {
  int i = blockIdx.x * 256 + threadIdx.x;   // grid covers BT*128 exactly
  if (i < BT * 64) {
    split_bf16(tanhf(h1w[i]), wh[i], wl[i]);
    split_bf16(h1a[i], ah[i], al[i]);
    split_bf16(h1v[i], vh[i], vl[i]);
  }
  split_bf16(sigf(h1g[i]), gh[i], gl[i]);
}

// ---------------------------------------------------------------------------
// K6: elementwise gates + kk-normalize + per-head bonus. wave == head.
// ---------------------------------------------------------------------------
__global__ __launch_bounds__(256) void k_gate(
    const float* __restrict__ h2w, const float* __restrict__ h2a,
    const float* __restrict__ h2v,
    const float* __restrict__ w0, const float* __restrict__ a0,
    const float* __restrict__ v0, const float* __restrict__ kkc,
    const float* __restrict__ kac, float* __restrict__ kbuf,
    float* __restrict__ vbuf, const float* __restrict__ vfirst,
    const float* __restrict__ rbuf, const float* __restrict__ rk,
    float* __restrict__ dec, float* __restrict__ aw,
    float* __restrict__ bw, float* __restrict__ bonb) {
  int idx = blockIdx.x * 256 + threadIdx.x;   // < BT*CC
  int c = idx & (CC - 1);
  float kv = kbuf[idx], vv = vbuf[idx], vf = vfirst[idx];
  float d_ = 0.60653065971f * sigf(w0[c] + h2w[idx]);   // sigmoid * e^-0.5
  float as = sigf(a0[c] + h2a[idx]);
  float vs = sigf(v0[c] + h2v[idx]);
  float vm = vv + (vf - vv) * vs;
  float kfv = kv * (1.0f + kac[c] * (as - 1.0f));
  float kku = kv * kkc[c];
  float s = kku * kku;     // per-head L2 over 64 lanes (wave == head)
  s += __shfl_xor(s, 1);  s += __shfl_xor(s, 2);  s += __shfl_xor(s, 4);
  s += __shfl_xor(s, 8);  s += __shfl_xor(s, 16); s += __shfl_xor(s, 32);
  float nrm = fmaxf(sqrtf(s), 1e-12f);
  float kkn = kku / nrm;
  float bon = rbuf[idx] * kfv * rk[c];
  bon += __shfl_xor(bon, 1);  bon += __shfl_xor(bon, 2);
  bon += __shfl_xor(bon, 4);  bon += __shfl_xor(bon, 8);
  bon += __shfl_xor(bon, 16); bon += __shfl_xor(bon, 32);
  if ((threadIdx.x & 63) == 0) bonb[(idx >> 11) * HH + (c >> 6)] = bon;
  dec[idx] = d_;
  aw[idx]  = -kkn; bw[idx] = kkn * as;
  kbuf[idx] = kfv; vbuf[idx] = vm;
}

// ---------------------------------------------------------------------------
// K7: WKV7 scan — ROUND-13.
// ROOT CAUSE of the collapsed rings (VGPR 104 even with (64,1)): the
// asm volatile("" ::: "memory") fences. A memory-clobber asm may READ
// memory, so the backend drains vmem (s_waitcnt vmcnt(0)) before each
// fence -> every iteration waited for the loads it had just issued ->
// prefetch distance = 0 at runtime -> compiler rightly shrank the ring.
// FIX: __builtin_amdgcn_sched_barrier(0) — pure scheduling fence, no
// memory semantics, no forced waitcnt. Loads stay 8 steps in flight;
// compiler emits counted s_waitcnt before each slot's first use.
// Everything else identical to round-11/12 (red16 pure-DPP, XCD-clustered
// heads, (64,1) VGPR budget, 8-deep C++ float4 ring).
// ---------------------------------------------------------------------------
__global__ __launch_bounds__(64, 1) void k_scan(
    const float* __restrict__ rbuf, const float* __restrict__ kf,
    const float* __restrict__ dec, const float* __restrict__ aw,
    const float* __restrict__ bw, const float* __restrict__ vbuf,
    const float* __restrict__ st0, float* __restrict__ ybuf) {
  int blk = blockIdx.x;                     // 0..1023
  int xcd = blk & 7;
  int q   = blk >> 3;                       // 0..127
  int bh  = xcd * 8 + (q & 7);              // all 16 rg-waves of a head share blk%8
  int rg  = q >> 3;                         // 0..15
  int b = bh >> 5, h = bh & 31;
  int lane = threadIdx.x;
  int row  = rg * 4 + (lane >> 4);
  int c0   = (lane & 15) * 4;
  size_t tokbase = (size_t)b * TT * CC + h * 64;

  float4 S = *(const float4*)(st0 + ((size_t)bh * 64 + row) * 64 + c0);

  bool writer = ((lane & 15) == 0);
  float* yout = ybuf + tokbase + row;

  const float* pr = rbuf + tokbase + c0;
  const float* pk = kf   + tokbase + c0;
  const float* pd = dec  + tokbase + c0;
  const float* pa = aw   + tokbase + c0;
  const float* pb = bw   + tokbase + c0;
  const float* pv = vbuf + tokbase + row;

  float4 Rr[8], Rk[8], Rd[8], Ra[8], Rb[8];
  float  Rv[8];

#define LOADT(SL, T)                                                         \
  { size_t oo = (size_t)(T) * CC;                                            \
    Rr[SL] = *(const float4*)(pr + oo);                                      \
    Rk[SL] = *(const float4*)(pk + oo);                                      \
    Rd[SL] = *(const float4*)(pd + oo);                                      \
    Ra[SL] = *(const float4*)(pa + oo);                                      \
    Rb[SL] = *(const float4*)(pb + oo);                                      \
    Rv[SL] = pv[oo]; }

#define STEP(SL, T)                                                          \
  { float sa = fmaf(S.w, Ra[SL].w, fmaf(S.z, Ra[SL].z,                       \
               fmaf(S.y, Ra[SL].y, S.x * Ra[SL].x)));                        \
    sa = red16(sa);                                                          \
    float vv = Rv[SL];                                                       \
    S.x = fmaf(S.x, Rd[SL].x, fmaf(sa, Rb[SL].x, vv * Rk[SL].x));            \
    S.y = fmaf(S.y, Rd[SL].y, fmaf(sa, Rb[SL].y, vv * Rk[SL].y));            \
    S.z = fmaf(S.z, Rd[SL].z, fmaf(sa, Rb[SL].z, vv * Rk[SL].z));            \
    S.w = fmaf(S.w, Rd[SL].w, fmaf(sa, Rb[SL].w, vv * Rk[SL].w));            \
    float y = fmaf(S.w, Rr[SL].w, fmaf(S.z, Rr[SL].z,                        \
              fmaf(S.y, Rr[SL].y, S.x * Rr[SL].x)));                         \
    y = red16(y);                                                            \
    if (writer) yout[(size_t)(T) * CC] = y; }

#pragma unroll
  for (int s = 0; s < 8; ++s) LOADT(s, s)
  for (int t = 0; t < TT; t += 8) {
#pragma unroll
    for (int s = 0; s < 8; ++s) {
      STEP(s, t + s)
      if (t + 8 + s < TT) LOADT(s, t + 8 + s)
      __builtin_amdgcn_sched_barrier(0);   // scheduler-only fence: pins the
      // reload 8 steps early WITHOUT the vmcnt(0) drain a "memory" clobber
      // asm forces (round-13 root cause).
    }
  }
#undef LOADT
#undef STEP
}

// ---------------------------------------------------------------------------
// K8: post-scan epilogue: GroupNorm + bonus + g-gate, fully parallel.
// ---------------------------------------------------------------------------
__global__ __launch_bounds__(256) void k_post(
    const float* __restrict__ ybuf, const float* __restrict__ vb,
    const float* __restrict__ gvb, const float* __restrict__ bonb,
    const float* __restrict__ gnw, const float* __restrict__ gnb,
    __hip_bfloat16* __restrict__ xoh, __hip_bfloat16* __restrict__ xol) {
  int tid = threadIdx.x, wv = tid >> 6, lane = tid & 63;
  int id = blockIdx.x * 4 + wv;        // 0..BT*HH-1
  int bt = id >> 5, h = id & 31;
  size_t base = (size_t)bt * CC + h * 64 + lane;
  float y = ybuf[base];
  float s1 = y, s2 = y * y;
#pragma unroll
  for (int off = 1; off < 64; off <<= 1) {
    s1 += __shfl_xor(s1, off);
    s2 += __shfl_xor(s2, off);
  }
  float mean = s1 * (1.0f / 64.0f);
  float var  = s2 * (1.0f / 64.0f) - mean * mean;
  float inv  = rsqrtf(var + GN_EPS);
  float x = fmaf((y - mean) * inv, gnw[h * 64 + lane], gnb[h * 64 + lane])
          + bonb[bt * HH + h] * vb[base];
  split_bf16(x * gvb[base], xoh[base], xol[base]);
}

// ---------------------------------------------------------------------------
extern "C" void kernel_launch(void* const* d_in, const int* in_sizes, int n_in,
                              void* d_out, int out_size, void* d_ws, size_t ws_size,
                              hipStream_t stream) {
  (void)in_sizes; (void)n_in; (void)out_size; (void)ws_size;
  const float* hid    = (const float*)d_in[0];
  const float* shift  = (const float*)d_in[1];
  const float* st0    = (const float*)d_in[2];
  const float* vfirst = (const float*)d_in[3];
  const float* xrc = (const float*)d_in[4];
  const float* xwc = (const float*)d_in[5];
  const float* xkc = (const float*)d_in[6];
  const float* xvc = (const float*)d_in[7];
  const float* xac = (const float*)d_in[8];
  const float* xgc = (const float*)d_in[9];
  const float* w0  = (const float*)d_in[10];
  const float* w1  = (const float*)d_in[11];
  const float* w2  = (const float*)d_in[12];
  const float* a0  = (const float*)d_in[13];
  const float* a1  = (const float*)d_in[14];
  const float* a2  = (const float*)d_in[15];
  const float* v0  = (const float*)d_in[16];
  const float* v1  = (const float*)d_in[17];
  const float* v2  = (const float*)d_in[18];
  const float* g1  = (const float*)d_in[19];
  const float* g2  = (const float*)d_in[20];
  const float* kkc = (const float*)d_in[21];
  const float* kac = (const float*)d_in[22];
  const float* rk  = (const float*)d_in[23];
  const float* Wr  = (const float*)d_in[24];
  const float* Wk  = (const float*)d_in[25];
  const float* Wv  = (const float*)d_in[26];
  const float* Wo  = (const float*)d_in[27];
  const float* gnw = (const float*)d_in[28];
  const float* gnb = (const float*)d_in[29];
  float* out = (float*)d_out;

  char* p = (char*)d_ws;
  auto alloc = [&](size_t n) { char* q = p; p += (n + 255) & ~(size_t)255; return q; };
  const size_t EL = (size_t)BT * CC;

  // --- alias pool: xrh..xvl + Wrh,Wrl dead by k_gate time; db/awb/bwb +
  //     h2g (the old gvb slot) overlay them.
  char* pool = p;
  __hip_bfloat16* xrh = (__hip_bfloat16*)alloc(EL * 2);
  __hip_bfloat16* xrl = (__hip_bfloat16*)alloc(EL * 2);
  __hip_bfloat16* xkh = (__hip_bfloat16*)alloc(EL * 2);
  __hip_bfloat16* xkl = (__hip_bfloat16*)alloc(EL * 2);
  __hip_bfloat16* xvh = (__hip_bfloat16*)alloc(EL * 2);
  __hip_bfloat16* xvl = (__hip_bfloat16*)alloc(EL * 2);
  __hip_bfloat16* Wrh = (__hip_bfloat16*)alloc((size_t)CC * CC * 2);
  __hip_bfloat16* Wrl = (__hip_bfloat16*)alloc((size_t)CC * CC * 2);
  float* db  = (float*)pool;           // overlays xrh+xrl
  float* awb = db + EL;                // overlays xkh+xkl
  float* bwb = db + 2 * EL;            // overlays xvh+xvl
  float* h2g = db + 3 * EL;            // overlays Wrh+Wrl (old gvb slot)

  __hip_bfloat16* Wkh = (__hip_bfloat16*)alloc((size_t)CC * CC * 2);
  __hip_bfloat16* Wkl = (__hip_bfloat16*)alloc((size_t)CC * CC * 2);
  float* ybuf = (float*)Wkh;           // overlays Wkh+Wkl (dead after k-GEMM)
  float* h2v  = (float*)Wkh;           // same region, read by k_gate BEFORE scan writes ybuf

  __hip_bfloat16* Wvh = (__hip_bfloat16*)alloc((size_t)CC * CC * 2);
  __hip_bfloat16* Wvl = (__hip_bfloat16*)alloc((size_t)CC * CC * 2);
  __hip_bfloat16* Woh = (__hip_bfloat16*)alloc((size_t)CC * CC * 2);
  __hip_bfloat16* Wol = (__hip_bfloat16*)alloc((size_t)CC * CC * 2);
  __hip_bfloat16* xw  = (__hip_bfloat16*)alloc(EL * 2);
  __hip_bfloat16* xa  = (__hip_bfloat16*)alloc(EL * 2);
  __hip_bfloat16* xg  = (__hip_bfloat16*)alloc(EL * 2);
  float* h2w = (float*)xw;             // overlays xw+xa (dead after stage-1 GEMMs)
  __hip_bfloat16* w1t = (__hip_bfloat16*)alloc((size_t)64  * CC * 2);
  __hip_bfloat16* a1t = (__hip_bfloat16*)alloc((size_t)64  * CC * 2);
  __hip_bfloat16* v1t = (__hip_bfloat16*)alloc((size_t)64  * CC * 2);
  __hip_bfloat16* g1t = (__hip_bfloat16*)alloc((size_t)128 * CC * 2);
  float* rb  = (float*)alloc(EL * 4);
  float* kb  = (float*)alloc(EL * 4);  // raw k, then k_final in place
  float* vb  = (float*)alloc(EL * 4);  // raw v, then v_mix in place
  float* h1w = (float*)alloc((size_t)BT * 64  * 4);
  float* h1a = (float*)alloc((size_t)BT * 64  * 4);
  float* h1v = (float*)alloc((size_t)BT * 64  * 4);
  float* h1g = (float*)alloc((size_t)BT * 128 * 4);
  __hip_bfloat16* xoh = (__hip_bfloat16*)alloc(EL * 2);
  __hip_bfloat16* xol = (__hip_bfloat16*)alloc(EL * 2);
  float* h2a = (float*)xoh;            // overlays xoh+xol (k_post writes them AFTER k_gate)
  float* bonb = (float*)alloc((size_t)BT * HH * 4);   // per-(token,head) bonus
  // stage-2 split operands (small, fresh):
  __hip_bfloat16* h1wh = (__hip_bfloat16*)alloc((size_t)BT * 64 * 2);
  __hip_bfloat16* h1wl = (__hip_bfloat16*)alloc((size_t)BT * 64 * 2);
  __hip_bfloat16* h1ah = (__hip_bfloat16*)alloc((size_t)BT * 64 * 2);
  __hip_bfloat16* h1al = (__hip_bfloat16*)alloc((size_t)BT * 64 * 2);
  __hip_bfloat16* h1vh = (__hip_bfloat16*)alloc((size_t)BT * 64 * 2);
  __hip_bfloat16* h1vl = (__hip_bfloat16*)alloc((size_t)BT * 64 * 2);
  __hip_bfloat16* h1gh = (__hip_bfloat16*)alloc((size_t)BT * 128 * 2);
  __hip_bfloat16* h1gl = (__hip_bfloat16*)alloc((size_t)BT * 128 * 2);
  __hip_bfloat16* w2th = (__hip_bfloat16*)alloc((size_t)CC * 64 * 2);
  __hip_bfloat16* w2tl = (__hip_bfloat16*)alloc((size_t)CC * 64 * 2);
  __hip_bfloat16* a2th = (__hip_bfloat16*)alloc((size_t)CC * 64 * 2);
  __hip_bfloat16* a2tl = (__hip_bfloat16*)alloc((size_t)CC * 64 * 2);
  __hip_bfloat16* v2th = (__hip_bfloat16*)alloc((size_t)CC * 64 * 2);
  __hip_bfloat16* v2tl = (__hip_bfloat16*)alloc((size_t)CC * 64 * 2);
  __hip_bfloat16* g2th = (__hip_bfloat16*)alloc((size_t)CC * 128 * 2);
  __hip_bfloat16* g2tl = (__hip_bfloat16*)alloc((size_t)CC * 128 * 2);
  // total ~210 MiB (known-OK envelope: 220 OK, 268 crashed)

  k_prepx<<<16384, 256, 0, stream>>>(hid, shift, xrc, xwc, xkc, xvc, xac, xgc,
                                     xrh, xrl, xw, xkh, xkl, xvh, xvl, xa, xg);
  k_cvt2<<<16384, 256, 0, stream>>>(Wr, Wrh, Wrl);
  k_cvt2<<<16384, 256, 0, stream>>>(Wk, Wkh, Wkl);
  k_cvt2<<<16384, 256, 0, stream>>>(Wv, Wvh, Wvl);
  k_cvt2<<<16384, 256, 0, stream>>>(Wo, Woh, Wol);
  k_tr<<<512, 256, 0, stream>>>(w1, w1t, 64);
  k_tr<<<512, 256, 0, stream>>>(a1, a1t, 64);
  k_tr<<<512, 256, 0, stream>>>(v1, v1t, 32);
  k_tr<<<1024, 256, 0, stream>>>(g1, g1t, 128);
  k_trs<<<512, 256, 0, stream>>>(w2, w2th, w2tl, 64, 6);
  k_trs<<<512, 256, 0, stream>>>(a2, a2th, a2tl, 64, 6);
  k_trs<<<512, 256, 0, stream>>>(v2, v2th, v2tl, 32, 6);   // padded K=64
  k_trs<<<1024, 256, 0, stream>>>(g2, g2th, g2tl, 128, 7);

  k_gemm_bt3<<<dim3(16, 32), 256, 0, stream>>>(xrh, xrl, Wrh, Wrl, rb, BT, CC, CC);
  k_gemm_bt3<<<dim3(16, 32), 256, 0, stream>>>(xkh, xkl, Wkh, Wkl, kb, BT, CC, CC);
  k_gemm_bt3<<<dim3(16, 32), 256, 0, stream>>>(xvh, xvl, Wvh, Wvl, vb, BT, CC, CC);
  k_gemm_bt<<<dim3(16, 1),  256, 0, stream>>>(xw,  w1t, h1w, BT, 64, CC);
  k_gemm_bt<<<dim3(16, 1),  256, 0, stream>>>(xa,  a1t, h1a, BT, 64, CC);
  k_gemm_bt<<<dim3(16, 1),  256, 0, stream>>>(xvh, v1t, h1v, BT, 64, CC);
  k_gemm_bt<<<dim3(16, 2),  256, 0, stream>>>(xg,  g1t, h1g, BT, 128, CC);

  k_act2<<<1024, 256, 0, stream>>>(h1w, h1a, h1v, h1g,
                                   h1wh, h1wl, h1ah, h1al,
                                   h1vh, h1vl, h1gh, h1gl);
  // stage-2 LoRA dots on MFMA (split precision). Overlays now live:
  //   h2w->xw+xa, h2a->xoh+xol, h2v->Wkh+Wkl, h2g->Wrh+Wrl.
  k_gemm_bt3<<<dim3(16, 32), 256, 0, stream>>>(h1wh, h1wl, w2th, w2tl, h2w, BT, CC, 64);
  k_gemm_bt3<<<dim3(16, 32), 256, 0, stream>>>(h1ah, h1al, a2th, a2tl, h2a, BT, CC, 64);
  k_gemm_bt3<<<dim3(16, 32), 256, 0, stream>>>(h1vh, h1vl, v2th, v2tl, h2v, BT, CC, 64);
  k_gemm_bt3<<<dim3(16, 32), 256, 0, stream>>>(h1gh, h1gl, g2th, g2tl, h2g, BT, CC, 128);

  k_gate<<<16384, 256, 0, stream>>>(h2w, h2a, h2v, w0, a0, v0, kkc, kac,
                                    kb, vb, vfirst, rb, rk, db, awb, bwb, bonb);
  k_scan<<<1024, 64, 0, stream>>>(rb, kb, db, awb, bwb, vb, st0, ybuf);
  k_post<<<16384, 256, 0, stream>>>(ybuf, vb, h2g, bonb, gnw, gnb, xoh, xol);
  k_gemm_bt3<<<dim3(16, 32), 256, 0, stream>>>(xoh, xol, Woh, Wol, out, BT, CC, CC);
}

// Round 7
// 1395.162 us; speedup vs baseline: 1.3276x; 1.0371x over previous
//
#include <hip/hip_runtime.h>
#include <hip/hip_bf16.h>

// Problem constants (RWKV-7 Tmix: B=2, T=1024, C=2048, H=32, N=64)
#define BB 2
#define TT 1024
#define CC 2048
#define HH 32
#define BT 2048          // BB*TT tokens
#define GN_EPS 6.4e-4f   // 1e-5 * 8^2

typedef __attribute__((ext_vector_type(8))) __bf16 bf16x8;
typedef __attribute__((ext_vector_type(4))) float f32x4;

__device__ __forceinline__ float sigf(float x) { return 1.0f / (1.0f + expf(-x)); }

__device__ __forceinline__ void split_bf16(float x, __hip_bfloat16& hi, __hip_bfloat16& lo) {
  __hip_bfloat16 h = __float2bfloat16(x);
  hi = h;
  lo = __float2bfloat16(x - __bfloat162float(h));
}

// Sum over each aligned 16-lane group, pure DPP (no LDS pipe on the chain).
__device__ __forceinline__ float red16(float x) {
  x += __int_as_float(__builtin_amdgcn_update_dpp(
      0, __float_as_int(x), 0xB1 /*quad_perm [1,0,3,2]*/, 0xF, 0xF, true));
  x += __int_as_float(__builtin_amdgcn_update_dpp(
      0, __float_as_int(x), 0x4E /*quad_perm [2,3,0,1]*/, 0xF, 0xF, true));
  x += __int_as_float(__builtin_amdgcn_update_dpp(
      0, __float_as_int(x), 0x141 /*row_half_mirror*/, 0xF, 0xF, true));
  x += __int_as_float(__builtin_amdgcn_update_dpp(
      0, __float_as_int(x), 0x140 /*row_mirror*/, 0xF, 0xF, true));
  return x;
}

// ---------------------------------------------------------------------------
// K1: token shift + six lerped projections. r/k/v hi+lo split; w/a/g bf16.
// ---------------------------------------------------------------------------
__global__ __launch_bounds__(256) void k_prepx(
    const float* __restrict__ hid, const float* __restrict__ shift,
    const float* __restrict__ xrc, const float* __restrict__ xwc,
    const float* __restrict__ xkc, const float* __restrict__ xvc,
    const float* __restrict__ xac, const float* __restrict__ xgc,
    __hip_bfloat16* __restrict__ xrh, __hip_bfloat16* __restrict__ xrl,
    __hip_bfloat16* __restrict__ xw,
    __hip_bfloat16* __restrict__ xkh, __hip_bfloat16* __restrict__ xkl,
    __hip_bfloat16* __restrict__ xvh, __hip_bfloat16* __restrict__ xvl,
    __hip_bfloat16* __restrict__ xa, __hip_bfloat16* __restrict__ xg) {
  int idx = blockIdx.x * 256 + threadIdx.x;   // < BT*CC
  int c  = idx & (CC - 1);
  int bt = idx >> 11;
  int t  = bt & (TT - 1);
  int b  = bt >> 10;
  float hcur  = hid[idx];
  float hprev = (t == 0) ? shift[b * CC + c] : hid[idx - CC];
  float xx = hprev - hcur;
  split_bf16(fmaf(xx, xrc[c], hcur), xrh[idx], xrl[idx]);
  split_bf16(fmaf(xx, xkc[c], hcur), xkh[idx], xkl[idx]);
  split_bf16(fmaf(xx, xvc[c], hcur), xvh[idx], xvl[idx]);
  xw[idx] = __float2bfloat16(fmaf(xx, xwc[c], hcur));
  xa[idx] = __float2bfloat16(fmaf(xx, xac[c], hcur));
  xg[idx] = __float2bfloat16(fmaf(xx, xgc[c], hcur));
}

// ---------------------------------------------------------------------------
// K2: f32 -> hi+lo bf16 split (for Wr/Wk/Wv/Wo)
// ---------------------------------------------------------------------------
__global__ __launch_bounds__(256) void k_cvt2(const float* __restrict__ in,
                                              __hip_bfloat16* __restrict__ oh,
                                              __hip_bfloat16* __restrict__ ol) {
  int i = blockIdx.x * 256 + threadIdx.x;
  split_bf16(in[i], oh[i], ol[i]);
}

// ---------------------------------------------------------------------------
// K3: transpose-convert small LoRA "up" weights: in [2048][N0] f32 ->
//     out [NP][2048] bf16 (rows >= N0 zero-padded).  (stage-1 B operands)
// ---------------------------------------------------------------------------
__global__ __launch_bounds__(256) void k_tr(const float* __restrict__ in,
                                            __hip_bfloat16* __restrict__ out,
                                            int N0) {
  int i = blockIdx.x * 256 + threadIdx.x;   // over NP*2048, grid exact
  int n = i >> 11;
  int k = i & 2047;
  float v = (n < N0) ? in[k * N0 + n] : 0.0f;
  out[i] = __float2bfloat16(v);
}

// ---------------------------------------------------------------------------
// K3b: transpose + hi/lo split of stage-2 "down" weights:
//   in [N0][CC] f32 -> out [CC][K0] bf16 hi+lo (K0 = 1<<lgK, rows>=N0 zero).
// ---------------------------------------------------------------------------
__global__ __launch_bounds__(256) void k_trs(const float* __restrict__ in,
                                             __hip_bfloat16* __restrict__ oh,
                                             __hip_bfloat16* __restrict__ ol,
                                             int N0, int lgK) {
  int i = blockIdx.x * 256 + threadIdx.x;   // over CC*K0, grid exact
  int n = i >> lgK;
  int k = i & ((1 << lgK) - 1);
  float v = (k < N0) ? in[k * CC + n] : 0.0f;
  split_bf16(v, oh[i], ol[i]);
}

// ---------------------------------------------------------------------------
// K4: plain bf16 MFMA GEMM, C[M,N] f32 = A[M,K] @ B[N,K]^T  (stage-1 LoRA)
// ---------------------------------------------------------------------------
__global__ __launch_bounds__(256) void k_gemm_bt(
    const __hip_bfloat16* __restrict__ A, const __hip_bfloat16* __restrict__ Bm,
    float* __restrict__ Cm, int M, int Nn, int K) {
  int tid  = threadIdx.x;
  int lane = tid & 63;
  int wv   = tid >> 6;
  int l15  = lane & 15;
  int quad = lane >> 4;
  int m0 = blockIdx.x * 128 + wv * 32;
  int n0 = blockIdx.y * 64;
  const __hip_bfloat16* ap0 = A + (m0 + l15) * K + quad * 8;
  const __hip_bfloat16* ap1 = ap0 + 16 * K;
  const __hip_bfloat16* bp  = Bm + (n0 + l15) * K + quad * 8;
  f32x4 z = {0.f, 0.f, 0.f, 0.f};
  f32x4 c00 = z, c01 = z, c02 = z, c03 = z;
  f32x4 c10 = z, c11 = z, c12 = z, c13 = z;
  for (int k0 = 0; k0 < K; k0 += 32) {
    bf16x8 a0v = *(const bf16x8*)(ap0 + k0);
    bf16x8 a1v = *(const bf16x8*)(ap1 + k0);
    bf16x8 b0v = *(const bf16x8*)(bp + k0);
    bf16x8 b1v = *(const bf16x8*)(bp + 16 * K + k0);
    bf16x8 b2v = *(const bf16x8*)(bp + 32 * K + k0);
    bf16x8 b3v = *(const bf16x8*)(bp + 48 * K + k0);
    c00 = __builtin_amdgcn_mfma_f32_16x16x32_bf16(a0v, b0v, c00, 0, 0, 0);
    c01 = __builtin_amdgcn_mfma_f32_16x16x32_bf16(a0v, b1v, c01, 0, 0, 0);
    c02 = __builtin_amdgcn_mfma_f32_16x16x32_bf16(a0v, b2v, c02, 0, 0, 0);
    c03 = __builtin_amdgcn_mfma_f32_16x16x32_bf16(a0v, b3v, c03, 0, 0, 0);
    c10 = __builtin_amdgcn_mfma_f32_16x16x32_bf16(a1v, b0v, c10, 0, 0, 0);
    c11 = __builtin_amdgcn_mfma_f32_16x16x32_bf16(a1v, b1v, c11, 0, 0, 0);
    c12 = __builtin_amdgcn_mfma_f32_16x16x32_bf16(a1v, b2v, c12, 0, 0, 0);
    c13 = __builtin_amdgcn_mfma_f32_16x16x32_bf16(a1v, b3v, c13, 0, 0, 0);
  }
  int colb = n0 + l15;
  int row0 = m0 + quad * 4;
#pragma unroll
  for (int r = 0; r < 4; ++r) {
    Cm[(row0 + r) * Nn + colb +  0] = c00[r];
    Cm[(row0 + r) * Nn + colb + 16] = c01[r];
    Cm[(row0 + r) * Nn + colb + 32] = c02[r];
    Cm[(row0 + r) * Nn + colb + 48] = c03[r];
    Cm[(row0 + 16 + r) * Nn + colb +  0] = c10[r];
    Cm[(row0 + 16 + r) * Nn + colb + 16] = c11[r];
    Cm[(row0 + 16 + r) * Nn + colb + 32] = c12[r];
    Cm[(row0 + 16 + r) * Nn + colb + 48] = c13[r];
  }
}

// ---------------------------------------------------------------------------
// K4b: split-precision GEMM: C = (Ah+Al)@(Bh+Bl)^T ~= Ah Bh + Ah Bl + Al Bh.
// ---------------------------------------------------------------------------
__global__ __launch_bounds__(256) void k_gemm_bt3(
    const __hip_bfloat16* __restrict__ Ah, const __hip_bfloat16* __restrict__ Al,
    const __hip_bfloat16* __restrict__ Bh, const __hip_bfloat16* __restrict__ Bl,
    float* __restrict__ Cm, int M, int Nn, int K) {
  int tid  = threadIdx.x;
  int lane = tid & 63;
  int wv   = tid >> 6;
  int l15  = lane & 15;
  int quad = lane >> 4;
  int m0 = blockIdx.x * 128 + wv * 32;
  int n0 = blockIdx.y * 64;
  size_t aoff0 = (size_t)(m0 + l15) * K + quad * 8;
  size_t aoff1 = aoff0 + (size_t)16 * K;
  size_t boff  = (size_t)(n0 + l15) * K + quad * 8;
  f32x4 z = {0.f, 0.f, 0.f, 0.f};
  f32x4 c00 = z, c01 = z, c02 = z, c03 = z;
  f32x4 c10 = z, c11 = z, c12 = z, c13 = z;
  for (int k0 = 0; k0 < K; k0 += 32) {
    bf16x8 a0h = *(const bf16x8*)(Ah + aoff0 + k0);
    bf16x8 a1h = *(const bf16x8*)(Ah + aoff1 + k0);
    bf16x8 a0l = *(const bf16x8*)(Al + aoff0 + k0);
    bf16x8 a1l = *(const bf16x8*)(Al + aoff1 + k0);
    bf16x8 bh0 = *(const bf16x8*)(Bh + boff + k0);
    bf16x8 bh1 = *(const bf16x8*)(Bh + boff + (size_t)16 * K + k0);
    bf16x8 bh2 = *(const bf16x8*)(Bh + boff + (size_t)32 * K + k0);
    bf16x8 bh3 = *(const bf16x8*)(Bh + boff + (size_t)48 * K + k0);
    bf16x8 bl0 = *(const bf16x8*)(Bl + boff + k0);
    bf16x8 bl1 = *(const bf16x8*)(Bl + boff + (size_t)16 * K + k0);
    bf16x8 bl2 = *(const bf16x8*)(Bl + boff + (size_t)32 * K + k0);
    bf16x8 bl3 = *(const bf16x8*)(Bl + boff + (size_t)48 * K + k0);
    c00 = __builtin_amdgcn_mfma_f32_16x16x32_bf16(a0h, bh0, c00, 0, 0, 0);
    c01 = __builtin_amdgcn_mfma_f32_16x16x32_bf16(a0h, bh1, c01, 0, 0, 0);
    c02 = __builtin_amdgcn_mfma_f32_16x16x32_bf16(a0h, bh2, c02, 0, 0, 0);
    c03 = __builtin_amdgcn_mfma_f32_16x16x32_bf16(a0h, bh3, c03, 0, 0, 0);
    c10 = __builtin_amdgcn_mfma_f32_16x16x32_bf16(a1h, bh0, c10, 0, 0, 0);
    c11 = __builtin_amdgcn_mfma_f32_16x16x32_bf16(a1h, bh1, c11, 0, 0, 0);
    c12 = __builtin_amdgcn_mfma_f32_16x16x32_bf16(a1h, bh2, c12, 0, 0, 0);
    c13 = __builtin_amdgcn_mfma_f32_16x16x32_bf16(a1h, bh3, c13, 0, 0, 0);
    c00 = __builtin_amdgcn_mfma_f32_16x16x32_bf16(a0h, bl0, c00, 0, 0, 0);
    c01 = __builtin_amdgcn_mfma_f32_16x16x32_bf16(a0h, bl1, c01, 0, 0, 0);
    c02 = __builtin_amdgcn_mfma_f32_16x16x32_bf16(a0h, bl2, c02, 0, 0, 0);
    c03 = __builtin_amdgcn_mfma_f32_16x16x32_bf16(a0h, bl3, c03, 0, 0, 0);
    c10 = __builtin_amdgcn_mfma_f32_16x16x32_bf16(a1h, bl0, c10, 0, 0, 0);
    c11 = __builtin_amdgcn_mfma_f32_16x16x32_bf16(a1h, bl1, c11, 0, 0, 0);
    c12 = __builtin_amdgcn_mfma_f32_16x16x32_bf16(a1h, bl2, c12, 0, 0, 0);
    c13 = __builtin_amdgcn_mfma_f32_16x16x32_bf16(a1h, bl3, c13, 0, 0, 0);
    c00 = __builtin_amdgcn_mfma_f32_16x16x32_bf16(a0l, bh0, c00, 0, 0, 0);
    c01 = __builtin_amdgcn_mfma_f32_16x16x32_bf16(a0l, bh1, c01, 0, 0, 0);
    c02 = __builtin_amdgcn_mfma_f32_16x16x32_bf16(a0l, bh2, c02, 0, 0, 0);
    c03 = __builtin_amdgcn_mfma_f32_16x16x32_bf16(a0l, bh3, c03, 0, 0, 0);
    c10 = __builtin_amdgcn_mfma_f32_16x16x32_bf16(a1l, bh0, c10, 0, 0, 0);
    c11 = __builtin_amdgcn_mfma_f32_16x16x32_bf16(a1l, bh1, c11, 0, 0, 0);
    c12 = __builtin_amdgcn_mfma_f32_16x16x32_bf16(a1l, bh2, c12, 0, 0, 0);
    c13 = __builtin_amdgcn_mfma_f32_16x16x32_bf16(a1l, bh3, c13, 0, 0, 0);
  }
  int colb = n0 + l15;
  int row0 = m0 + quad * 4;
#pragma unroll
  for (int r = 0; r < 4; ++r) {
    Cm[(row0 + r) * Nn + colb +  0] = c00[r];
    Cm[(row0 + r) * Nn + colb + 16] = c01[r];
    Cm[(row0 + r) * Nn + colb + 32] = c02[r];
    Cm[(row0 + r) * Nn + colb + 48] = c03[r];
    Cm[(row0 + 16 + r) * Nn + colb +  0] = c10[r];
    Cm[(row0 + 16 + r) * Nn + colb + 16] = c11[r];
    Cm[(row0 + 16 + r) * Nn + colb + 32] = c12[r];
    Cm[(row0 + 16 + r) * Nn + colb + 48] = c13[r];
  }
}

// ---------------------------------------------------------------------------
// K5: activations + hi/lo split of stage-1 LoRA outputs (MFMA stage-2 prep).
// ---------------------------------------------------------------------------
__global__ __launch_bounds__(256) void k_act2(
    const float* __restrict__ h1w, const float* __restrict__ h1a,
    const float* __restrict__ h1v, const float* __restrict__ h1g,
    __hip_bfloat16* __restrict__ wh, __hip_bfloat16* __restrict__ wl,
    __hip_bfloat16* __restrict__ ah, __hip_bfloat16* __restrict__ al,
    __hip_bfloat16* __restrict__ vh, __hip_bfloat16* __restrict__ vl,
    __hip_bfloat16* __restrict__ gh, __hip_bfloat16* __restrict__ gl) {
  int i = blockIdx.x * 256 + threadIdx.x;   // grid covers BT*128 exactly
  if (i < BT * 64) {
    split_bf16(tanhf(h1w[i]), wh[i], wl[i]);
    split_bf16(h1a[i], ah[i], al[i]);
    split_bf16(h1v[i], vh[i], vl[i]);
  }
  split_bf16(sigf(h1g[i]), gh[i], gl[i]);
}

// ---------------------------------------------------------------------------
// K6: elementwise gates + kk-normalize + per-head bonus. wave == head.
// ---------------------------------------------------------------------------
__global__ __launch_bounds__(256) void k_gate(
    const float* __restrict__ h2w, const float* __restrict__ h2a,
    const float* __restrict__ h2v,
    const float* __restrict__ w0, const float* __restrict__ a0,
    const float* __restrict__ v0, const float* __restrict__ kkc,
    const float* __restrict__ kac, float* __restrict__ kbuf,
    float* __restrict__ vbuf, const float* __restrict__ vfirst,
    const float* __restrict__ rbuf, const float* __restrict__ rk,
    float* __restrict__ dec, float* __restrict__ aw,
    float* __restrict__ bw, float* __restrict__ bonb) {
  int idx = blockIdx.x * 256 + threadIdx.x;   // < BT*CC
  int c = idx & (CC - 1);
  float kv = kbuf[idx], vv = vbuf[idx], vf = vfirst[idx];
  float d_ = 0.60653065971f * sigf(w0[c] + h2w[idx]);   // sigmoid * e^-0.5
  float as = sigf(a0[c] + h2a[idx]);
  float vs = sigf(v0[c] + h2v[idx]);
  float vm = vv + (vf - vv) * vs;
  float kfv = kv * (1.0f + kac[c] * (as - 1.0f));
  float kku = kv * kkc[c];
  float s = kku * kku;     // per-head L2 over 64 lanes (wave == head)
  s += __shfl_xor(s, 1);  s += __shfl_xor(s, 2);  s += __shfl_xor(s, 4);
  s += __shfl_xor(s, 8);  s += __shfl_xor(s, 16); s += __shfl_xor(s, 32);
  float nrm = fmaxf(sqrtf(s), 1e-12f);
  float kkn = kku / nrm;
  float bon = rbuf[idx] * kfv * rk[c];
  bon += __shfl_xor(bon, 1);  bon += __shfl_xor(bon, 2);
  bon += __shfl_xor(bon, 4);  bon += __shfl_xor(bon, 8);
  bon += __shfl_xor(bon, 16); bon += __shfl_xor(bon, 32);
  if ((threadIdx.x & 63) == 0) bonb[(idx >> 11) * HH + (c >> 6)] = bon;
  dec[idx] = d_;
  aw[idx]  = -kkn; bw[idx] = kkn * as;
  kbuf[idx] = kfv; vbuf[idx] = vm;
}

// ---------------------------------------------------------------------------
// K7: WKV7 scan — ROUND-14: LDS-ring prefetch via global_load_lds DMA.
// Three C++ register-ring attempts all collapsed to VGPR=104 (compiler
// serializes load->use regardless of fences/launch_bounds). This version
// moves the prefetch state to LDS where the compiler cannot touch it:
//  - 16-token LDS ring, 2KB/slot (32KB). Per token 2 DMA instructions:
//    instr1 gathers r/k/d/a (lanes 0-15/16-31/32-47/48-63 -> LDS
//    base+lane*16); instr2 gathers b (lanes 0-15) + v rows (lanes 16-63
//    redundantly into slot padding — branchless; LDS dest is wave-uniform
//    base + lane*16, global src is per-lane [m104/m173]).
//  - counted waits: steady vmcnt(40) (exact budget 45 = 3 vmem/step x 15
//    steps in flight, 5 slack), warm-up vmcnt(24), vmcnt(0)+waitless tail.
//  - consumption via opaque asm ds_read (rule-18: + lgkmcnt(0) +
//    sched_barrier(0)) so the waitcnt legalizer can't insert drains;
//    LDS->reg double-buffered one token ahead (latency hides under VALU).
// Math identical to round-13 (red16 pure-DPP, same fma order).
// ---------------------------------------------------------------------------
__global__ __launch_bounds__(64, 1) void k_scan(
    const float* __restrict__ rbuf, const float* __restrict__ kf,
    const float* __restrict__ dec, const float* __restrict__ aw,
    const float* __restrict__ bw, const float* __restrict__ vbuf,
    const float* __restrict__ st0, float* __restrict__ ybuf) {
  __shared__ __align__(16) char ldsbuf[16 * 2048];
  int blk = blockIdx.x;                     // 0..1023
  int xcd = blk & 7;
  int q   = blk >> 3;                       // 0..127
  int bh  = xcd * 8 + (q & 7);              // 16 rg-waves of a head share blk%8
  int rg  = q >> 3;                         // 0..15
  int b = bh >> 5, h = bh & 31;
  int lane = threadIdx.x;
  int l15  = lane & 15;
  int row  = rg * 4 + (lane >> 4);
  size_t tokbase = (size_t)b * TT * CC + h * 64;

  f32x4 S = *(const f32x4*)(st0 + ((size_t)bh * 64 + row) * 64 + l15 * 4);
  bool writer = (l15 == 0);
  float* yout = ybuf + tokbase + row;

  // per-lane DMA source pointers (advance +CC per token, all lanes uniform)
  const float* g1 = (lane < 16 ? rbuf : lane < 32 ? kf : lane < 48 ? dec : aw)
                  + tokbase + l15 * 4;
  const float* g2 = (lane < 16) ? (bw + tokbase + l15 * 4)
                                : (vbuf + tokbase + rg * 4);  // lanes>=16: v rows (16 real, rest pad)

  // LDS byte offsets (relative to workgroup LDS base)
  unsigned lbase = (unsigned)(uintptr_t)(__attribute__((address_space(3))) char*)ldsbuf;
  unsigned larr = lbase + (unsigned)(l15 * 16);          // +slot: arrays at 0/256/512/768/1024
  unsigned lvad = lbase + 1280u + (unsigned)((lane >> 4) * 4);  // +slot: v word

#define DMAQ(T)                                                              \
  { char* sb_ = ldsbuf + (((T) & 15) << 11);                                 \
    __builtin_amdgcn_global_load_lds(                                        \
        (const __attribute__((address_space(1))) void*)g1,                   \
        (__attribute__((address_space(3))) void*)sb_, 16, 0, 0);             \
    __builtin_amdgcn_global_load_lds(                                        \
        (const __attribute__((address_space(1))) void*)g2,                   \
        (__attribute__((address_space(3))) void*)(sb_ + 1024), 16, 0, 0);    \
    g1 += CC; g2 += CC; }

#define DSRD(RR, RK, RD, RA, RB, RV, T)                                      \
  { unsigned a_ = larr + (unsigned)(((T) & 15) << 11);                       \
    unsigned v_ = lvad + (unsigned)(((T) & 15) << 11);                       \
    asm volatile("ds_read_b128 %0, %1"             : "=v"(RR) : "v"(a_));    \
    asm volatile("ds_read_b128 %0, %1 offset:256"  : "=v"(RK) : "v"(a_));    \
    asm volatile("ds_read_b128 %0, %1 offset:512"  : "=v"(RD) : "v"(a_));    \
    asm volatile("ds_read_b128 %0, %1 offset:768"  : "=v"(RA) : "v"(a_));    \
    asm volatile("ds_read_b128 %0, %1 offset:1024" : "=v"(RB) : "v"(a_));    \
    asm volatile("ds_read_b32 %0, %1"              : "=v"(RV) : "v"(v_)); }

#define WVM(N) { asm volatile("s_waitcnt vmcnt(" #N ")" ::: "memory");       \
                 __builtin_amdgcn_sched_barrier(0); }
#define WLG    { asm volatile("s_waitcnt lgkmcnt(0)" ::: "memory");          \
                 __builtin_amdgcn_sched_barrier(0); }

#define STEPR(RR, RK, RD, RA, RB, RV, T)                                     \
  { float sa = fmaf(S.w, RA.w, fmaf(S.z, RA.z,                               \
               fmaf(S.y, RA.y, S.x * RA.x)));                                \
    sa = red16(sa);                                                          \
    float vv = RV;                                                           \
    S.x = fmaf(S.x, RD.x, fmaf(sa, RB.x, vv * RK.x));                        \
    S.y = fmaf(S.y, RD.y, fmaf(sa, RB.y, vv * RK.y));                        \
    S.z = fmaf(S.z, RD.z, fmaf(sa, RB.z, vv * RK.z));                        \
    S.w = fmaf(S.w, RD.w, fmaf(sa, RB.w, vv * RK.w));                        \
    float y = fmaf(S.w, RR.w, fmaf(S.z, RR.z,                                \
              fmaf(S.y, RR.y, S.x * RR.x)));                                 \
    y = red16(y);                                                            \
    if (writer) yout[(size_t)(T) * CC] = y; }

  // prologue: DMA tokens 0..15 (32 vmem ops in flight)
  for (int tt = 0; tt < 16; ++tt) DMAQ(tt)

  f32x4 Ar, Ak, Ad, Aa, Ab; float Av;
  f32x4 Br, Bk, Bd, Ba, Bb; float Bv;

  WVM(24)                      // token 0 landed (30 ops after it; 6 slack)
  DSRD(Ar, Ak, Ad, Aa, Ab, Av, 0)
  WLG

  int t = 0;
  // warm-up pairs: t = 0..15 (prologue-issued tokens; exact budget 30+t)
  for (; t < 16; t += 2) {
    DMAQ(t + 16)
    WVM(24)
    DSRD(Br, Bk, Bd, Ba, Bb, Bv, t + 1)
    STEPR(Ar, Ak, Ad, Aa, Ab, Av, t)
    WLG
    DMAQ(t + 17)
    WVM(24)
    DSRD(Ar, Ak, Ad, Aa, Ab, Av, t + 2)
    STEPR(Br, Bk, Bd, Ba, Bb, Bv, t + 1)
    WLG
  }
  // steady pairs: t = 16..1006 (budget 45; 5 slack)
  for (; t < TT - 16; t += 2) {
    DMAQ(t + 16)
    WVM(40)
    DSRD(Br, Bk, Bd, Ba, Bb, Bv, t + 1)
    STEPR(Ar, Ak, Ad, Aa, Ab, Av, t)
    WLG
    DMAQ(t + 17)
    WVM(40)
    DSRD(Ar, Ak, Ad, Aa, Ab, Av, t + 2)
    STEPR(Br, Bk, Bd, Ba, Bb, Bv, t + 1)
    WLG
  }
  // drain, then waitless tail: t = 1008..1023 (all data resident in LDS)
  asm volatile("s_waitcnt vmcnt(0)" ::: "memory");
  __builtin_amdgcn_sched_barrier(0);
  for (; t < TT; t += 2) {
    DSRD(Br, Bk, Bd, Ba, Bb, Bv, t + 1)
    STEPR(Ar, Ak, Ad, Aa, Ab, Av, t)
    WLG
    if (t + 2 < TT) DSRD(Ar, Ak, Ad, Aa, Ab, Av, t + 2)
    STEPR(Br, Bk, Bd, Ba, Bb, Bv, t + 1)
    WLG
  }
#undef DMAQ
#undef DSRD
#undef WVM
#undef WLG
#undef STEPR
}

// ---------------------------------------------------------------------------
// K8: post-scan epilogue: GroupNorm + bonus + g-gate, fully parallel.
// ---------------------------------------------------------------------------
__global__ __launch_bounds__(256) void k_post(
    const float* __restrict__ ybuf, const float* __restrict__ vb,
    const float* __restrict__ gvb, const float* __restrict__ bonb,
    const float* __restrict__ gnw, const float* __restrict__ gnb,
    __hip_bfloat16* __restrict__ xoh, __hip_bfloat16* __restrict__ xol) {
  int tid = threadIdx.x, wv = tid >> 6, lane = tid & 63;
  int id = blockIdx.x * 4 + wv;        // 0..BT*HH-1
  int bt = id >> 5, h = id & 31;
  size_t base = (size_t)bt * CC + h * 64 + lane;
  float y = ybuf[base];
  float s1 = y, s2 = y * y;
#pragma unroll
  for (int off = 1; off < 64; off <<= 1) {
    s1 += __shfl_xor(s1, off);
    s2 += __shfl_xor(s2, off);
  }
  float mean = s1 * (1.0f / 64.0f);
  float var  = s2 * (1.0f / 64.0f) - mean * mean;
  float inv  = rsqrtf(var + GN_EPS);
  float x = fmaf((y - mean) * inv, gnw[h * 64 + lane], gnb[h * 64 + lane])
          + bonb[bt * HH + h] * vb[base];
  split_bf16(x * gvb[base], xoh[base], xol[base]);
}

// ---------------------------------------------------------------------------
extern "C" void kernel_launch(void* const* d_in, const int* in_sizes, int n_in,
                              void* d_out, int out_size, void* d_ws, size_t ws_size,
                              hipStream_t stream) {
  (void)in_sizes; (void)n_in; (void)out_size; (void)ws_size;
  const float* hid    = (const float*)d_in[0];
  const float* shift  = (const float*)d_in[1];
  const float* st0    = (const float*)d_in[2];
  const float* vfirst = (const float*)d_in[3];
  const float* xrc = (const float*)d_in[4];
  const float* xwc = (const float*)d_in[5];
  const float* xkc = (const float*)d_in[6];
  const float* xvc = (const float*)d_in[7];
  const float* xac = (const float*)d_in[8];
  const float* xgc = (const float*)d_in[9];
  const float* w0  = (const float*)d_in[10];
  const float* w1  = (const float*)d_in[11];
  const float* w2  = (const float*)d_in[12];
  const float* a0  = (const float*)d_in[13];
  const float* a1  = (const float*)d_in[14];
  const float* a2  = (const float*)d_in[15];
  const float* v0  = (const float*)d_in[16];
  const float* v1  = (const float*)d_in[17];
  const float* v2  = (const float*)d_in[18];
  const float* g1  = (const float*)d_in[19];
  const float* g2  = (const float*)d_in[20];
  const float* kkc = (const float*)d_in[21];
  const float* kac = (const float*)d_in[22];
  const float* rk  = (const float*)d_in[23];
  const float* Wr  = (const float*)d_in[24];
  const float* Wk  = (const float*)d_in[25];
  const float* Wv  = (const float*)d_in[26];
  const float* Wo  = (const float*)d_in[27];
  const float* gnw = (const float*)d_in[28];
  const float* gnb = (const float*)d_in[29];
  float* out = (float*)d_out;

  char* p = (char*)d_ws;
  auto alloc = [&](size_t n) { char* q = p; p += (n + 255) & ~(size_t)255; return q; };
  const size_t EL = (size_t)BT * CC;

  // --- alias pool: xrh..xvl + Wrh,Wrl dead by k_gate time; db/awb/bwb +
  //     h2g (the old gvb slot) overlay them.
  char* pool = p;
  __hip_bfloat16* xrh = (__hip_bfloat16*)alloc(EL * 2);
  __hip_bfloat16* xrl = (__hip_bfloat16*)alloc(EL * 2);
  __hip_bfloat16* xkh = (__hip_bfloat16*)alloc(EL * 2);
  __hip_bfloat16* xkl = (__hip_bfloat16*)alloc(EL * 2);
  __hip_bfloat16* xvh = (__hip_bfloat16*)alloc(EL * 2);
  __hip_bfloat16* xvl = (__hip_bfloat16*)alloc(EL * 2);
  __hip_bfloat16* Wrh = (__hip_bfloat16*)alloc((size_t)CC * CC * 2);
  __hip_bfloat16* Wrl = (__hip_bfloat16*)alloc((size_t)CC * CC * 2);
  float* db  = (float*)pool;           // overlays xrh+xrl
  float* awb = db + EL;                // overlays xkh+xkl
  float* bwb = db + 2 * EL;            // overlays xvh+xvl
  float* h2g = db + 3 * EL;            // overlays Wrh+Wrl (old gvb slot)

  __hip_bfloat16* Wkh = (__hip_bfloat16*)alloc((size_t)CC * CC * 2);
  __hip_bfloat16* Wkl = (__hip_bfloat16*)alloc((size_t)CC * CC * 2);
  float* ybuf = (float*)Wkh;           // overlays Wkh+Wkl (dead after k-GEMM)
  float* h2v  = (float*)Wkh;           // same region, read by k_gate BEFORE scan writes ybuf

  __hip_bfloat16* Wvh = (__hip_bfloat16*)alloc((size_t)CC * CC * 2);
  __hip_bfloat16* Wvl = (__hip_bfloat16*)alloc((size_t)CC * CC * 2);
  __hip_bfloat16* Woh = (__hip_bfloat16*)alloc((size_t)CC * CC * 2);
  __hip_bfloat16* Wol = (__hip_bfloat16*)alloc((size_t)CC * CC * 2);
  __hip_bfloat16* xw  = (__hip_bfloat16*)alloc(EL * 2);
  __hip_bfloat16* xa  = (__hip_bfloat16*)alloc(EL * 2);
  __hip_bfloat16* xg  = (__hip_bfloat16*)alloc(EL * 2);
  float* h2w = (float*)xw;             // overlays xw+xa (dead after stage-1 GEMMs)
  __hip_bfloat16* w1t = (__hip_bfloat16*)alloc((size_t)64  * CC * 2);
  __hip_bfloat16* a1t = (__hip_bfloat16*)alloc((size_t)64  * CC * 2);
  __hip_bfloat16* v1t = (__hip_bfloat16*)alloc((size_t)64  * CC * 2);
  __hip_bfloat16* g1t = (__hip_bfloat16*)alloc((size_t)128 * CC * 2);
  float* rb  = (float*)alloc(EL * 4);
  float* kb  = (float*)alloc(EL * 4);  // raw k, then k_final in place
  float* vb  = (float*)alloc(EL * 4);  // raw v, then v_mix in place
  float* h1w = (float*)alloc((size_t)BT * 64  * 4);
  float* h1a = (float*)alloc((size_t)BT * 64  * 4);
  float* h1v = (float*)alloc((size_t)BT * 64  * 4);
  float* h1g = (float*)alloc((size_t)BT * 128 * 4);
  __hip_bfloat16* xoh = (__hip_bfloat16*)alloc(EL * 2);
  __hip_bfloat16* xol = (__hip_bfloat16*)alloc(EL * 2);
  float* h2a = (float*)xoh;            // overlays xoh+xol (k_post writes them AFTER k_gate)
  float* bonb = (float*)alloc((size_t)BT * HH * 4);   // per-(token,head) bonus
  // stage-2 split operands (small, fresh):
  __hip_bfloat16* h1wh = (__hip_bfloat16*)alloc((size_t)BT * 64 * 2);
  __hip_bfloat16* h1wl = (__hip_bfloat16*)alloc((size_t)BT * 64 * 2);
  __hip_bfloat16* h1ah = (__hip_bfloat16*)alloc((size_t)BT * 64 * 2);
  __hip_bfloat16* h1al = (__hip_bfloat16*)alloc((size_t)BT * 64 * 2);
  __hip_bfloat16* h1vh = (__hip_bfloat16*)alloc((size_t)BT * 64 * 2);
  __hip_bfloat16* h1vl = (__hip_bfloat16*)alloc((size_t)BT * 64 * 2);
  __hip_bfloat16* h1gh = (__hip_bfloat16*)alloc((size_t)BT * 128 * 2);
  __hip_bfloat16* h1gl = (__hip_bfloat16*)alloc((size_t)BT * 128 * 2);
  __hip_bfloat16* w2th = (__hip_bfloat16*)alloc((size_t)CC * 64 * 2);
  __hip_bfloat16* w2tl = (__hip_bfloat16*)alloc((size_t)CC * 64 * 2);
  __hip_bfloat16* a2th = (__hip_bfloat16*)alloc((size_t)CC * 64 * 2);
  __hip_bfloat16* a2tl = (__hip_bfloat16*)alloc((size_t)CC * 64 * 2);
  __hip_bfloat16* v2th = (__hip_bfloat16*)alloc((size_t)CC * 64 * 2);
  __hip_bfloat16* v2tl = (__hip_bfloat16*)alloc((size_t)CC * 64 * 2);
  __hip_bfloat16* g2th = (__hip_bfloat16*)alloc((size_t)CC * 128 * 2);
  __hip_bfloat16* g2tl = (__hip_bfloat16*)alloc((size_t)CC * 128 * 2);
  // total ~210 MiB (known-OK envelope: 220 OK, 268 crashed)

  k_prepx<<<16384, 256, 0, stream>>>(hid, shift, xrc, xwc, xkc, xvc, xac, xgc,
                                     xrh, xrl, xw, xkh, xkl, xvh, xvl, xa, xg);
  k_cvt2<<<16384, 256, 0, stream>>>(Wr, Wrh, Wrl);
  k_cvt2<<<16384, 256, 0, stream>>>(Wk, Wkh, Wkl);
  k_cvt2<<<16384, 256, 0, stream>>>(Wv, Wvh, Wvl);
  k_cvt2<<<16384, 256, 0, stream>>>(Wo, Woh, Wol);
  k_tr<<<512, 256, 0, stream>>>(w1, w1t, 64);
  k_tr<<<512, 256, 0, stream>>>(a1, a1t, 64);
  k_tr<<<512, 256, 0, stream>>>(v1, v1t, 32);
  k_tr<<<1024, 256, 0, stream>>>(g1, g1t, 128);
  k_trs<<<512, 256, 0, stream>>>(w2, w2th, w2tl, 64, 6);
  k_trs<<<512, 256, 0, stream>>>(a2, a2th, a2tl, 64, 6);
  k_trs<<<512, 256, 0, stream>>>(v2, v2th, v2tl, 32, 6);   // padded K=64
  k_trs<<<1024, 256, 0, stream>>>(g2, g2th, g2tl, 128, 7);

  k_gemm_bt3<<<dim3(16, 32), 256, 0, stream>>>(xrh, xrl, Wrh, Wrl, rb, BT, CC, CC);
  k_gemm_bt3<<<dim3(16, 32), 256, 0, stream>>>(xkh, xkl, Wkh, Wkl, kb, BT, CC, CC);
  k_gemm_bt3<<<dim3(16, 32), 256, 0, stream>>>(xvh, xvl, Wvh, Wvl, vb, BT, CC, CC);
  k_gemm_bt<<<dim3(16, 1),  256, 0, stream>>>(xw,  w1t, h1w, BT, 64, CC);
  k_gemm_bt<<<dim3(16, 1),  256, 0, stream>>>(xa,  a1t, h1a, BT, 64, CC);
  k_gemm_bt<<<dim3(16, 1),  256, 0, stream>>>(xvh, v1t, h1v, BT, 64, CC);
  k_gemm_bt<<<dim3(16, 2),  256, 0, stream>>>(xg,  g1t, h1g, BT, 128, CC);

  k_act2<<<1024, 256, 0, stream>>>(h1w, h1a, h1v, h1g,
                                   h1wh, h1wl, h1ah, h1al,
                                   h1vh, h1vl, h1gh, h1gl);
  // stage-2 LoRA dots on MFMA (split precision). Overlays now live:
  //   h2w->xw+xa, h2a->xoh+xol, h2v->Wkh+Wkl, h2g->Wrh+Wrl.
  k_gemm_bt3<<<dim3(16, 32), 256, 0, stream>>>(h1wh, h1wl, w2th, w2tl, h2w, BT, CC, 64);
  k_gemm_bt3<<<dim3(16, 32), 256, 0, stream>>>(h1ah, h1al, a2th, a2tl, h2a, BT, CC, 64);
  k_gemm_bt3<<<dim3(16, 32), 256, 0, stream>>>(h1vh, h1vl, v2th, v2tl, h2v, BT, CC, 64);
  k_gemm_bt3<<<dim3(16, 32), 256, 0, stream>>>(h1gh, h1gl, g2th, g2tl, h2g, BT, CC, 128);

  k_gate<<<16384, 256, 0, stream>>>(h2w, h2a, h2v, w0, a0, v0, kkc, kac,
                                    kb, vb, vfirst, rb, rk, db, awb, bwb, bonb);
  k_scan<<<1024, 64, 0, stream>>>(rb, kb, db, awb, bwb, vb, st0, ybuf);
  k_post<<<16384, 256, 0, stream>>>(ybuf, vb, h2g, bonb, gnw, gnb, xoh, xol);
  k_gemm_bt3<<<dim3(16, 32), 256, 0, stream>>>(xoh, xol, Woh, Wol, out, BT, CC, CC);
}